// Round 16
// baseline (2306.622 us; speedup 1.0000x reference)
//
#include <hip/hip_runtime.h>
#include <math.h>

#define H 256
#define NROWS 10000
#define LTREE 8
#define TSEQ 16
#define FDIM 128
#define NE 160000
#define HTILE 65536      // 128 rows * 256 cols * 2 halves (u16)
#define XTILE 32768      // 128 rows * 128 cols * 2
#define HZS 5242880      // 80 tiles * HTILE
#define XZS 2621440      // 80 tiles * XTILE

typedef __attribute__((ext_vector_type(8))) short short8;
typedef __attribute__((ext_vector_type(4))) float f32x4;
typedef unsigned short u16;

__device__ __forceinline__ u16 f2bf(float x) {
    unsigned int u = __float_as_uint(x);
    return (u16)((u + 0x7fffu + ((u >> 16) & 1u)) >> 16);
}
__device__ __forceinline__ float bf2f(u16 s) { return __uint_as_float(((unsigned int)s) << 16); }
__device__ __forceinline__ short8 ldf(const u16* __restrict__ p) { return *(const short8*)(p); }
__device__ __forceinline__ float fexp_(float x) { return __expf(fminf(x, 80.f)); }
__device__ __forceinline__ float fsig_(float x) { return 1.f / (1.f + fexp_(-x)); }
__device__ __forceinline__ float ftanh_(float x) {
    float e = fexp_(fmaxf(2.f * x, -80.f));
    return (e - 1.f) / (e + 1.f);
}
#define MFMA(A, B, C) C = __builtin_amdgcn_mfma_f32_16x16x32_bf16(A, B, C, 0, 0, 0)
#define MF2(AH, AL, BH, C) do { MFMA(AH, BH, C); MFMA(AL, BH, C); } while (0)

__device__ __forceinline__ void async16(u16* l, const u16* g) {
    __builtin_amdgcn_global_load_lds((__attribute__((address_space(1))) const void*)g,
                                     (__attribute__((address_space(3))) void*)l, 16, 0, 0);
}

// XCD-aware remap, bijective when nwg%8==0.
__device__ __forceinline__ void xcd_swz(int& cbi, int& yy, int& zz) {
    const int gx = gridDim.x, gy = gridDim.y;
    int nwg8 = (gx * gy * gridDim.z) >> 3;
    int bid = blockIdx.x + gx * (blockIdx.y + gy * blockIdx.z);
    int wgid = (bid & 7) * nwg8 + (bid >> 3);
    cbi = wgid % gx;
    int rem = wgid / gx;
    yy = rem % gy;
    zz = rem / gy;
}

// tiled-layout u16 offset helpers
__device__ __forceinline__ size_t tpo128(int row, int g, int half) {
    return (size_t)(row >> 7) * XTILE + (size_t)(g >> 2) * 8192 +
           (size_t)((((g & 3) << 1) | half)) * 1024 + (size_t)(row & 127) * 8;
}

// Stage one 16KB chunk (pre-tiled source == LDS image), 128-row tiles. 4 loads/wave.
__device__ __forceinline__ void stageT(u16* ldsbuf, const u16* __restrict__ chunkbase,
                                       int w, int lane) {
#pragma unroll
    for (int cc = 0; cc < 4; cc++) {
        int eb = (w * 4 + cc) * 64;
        async16(ldsbuf + (size_t)eb * 8, chunkbase + (size_t)(eb + lane) * 8);
    }
}
// Stage an 8KB half-tile chunk (64 rows). 2 loads/wave.
__device__ __forceinline__ void stage64T(u16* ldsbuf, const u16* __restrict__ chunkbase,
                                         int w, int lane) {
#pragma unroll
    for (int cc = 0; cc < 2; cc++) {
        int p = w * 2 + cc;
        async16(ldsbuf + (size_t)p * 512, chunkbase + (size_t)p * 1024 + (size_t)lane * 8);
    }
}
// old-layout 64-row variant (tree kernel), with row clamp
__device__ __forceinline__ void stage_chunk64(u16* ldsbuf, const u16* __restrict__ src,
                                              int stride_u16, int kb_u16, int m0,
                                              int w, int lane) {
#pragma unroll
    for (int c = 0; c < 4; c++) {
        int e_base = (w * 4 + c) * 64;
        int e = e_base + lane;
        int p = e >> 6, rs = e & 63;
        int row = m0 + rs;
        if (row > NROWS - 1) row = NROWS - 1;
        const u16* g = src + (size_t)row * stride_u16 + kb_u16 + (p >> 1) * 16 + (p & 1) * 8;
        async16(ldsbuf + (size_t)e_base * 8, g);
    }
}

// ---------------- split helpers ----------------
__device__ __forceinline__ void emit8t(u16* __restrict__ hi_p, u16* __restrict__ lo_p,
                                       const float* v8) {
    short8 h, l;
#pragma unroll
    for (int j = 0; j < 8; j++) {
        u16 hh = f2bf(v8[j]);
        h[j] = (short)hh;
        l[j] = (short)f2bf(v8[j] - bf2f(hh));
    }
    *(short8*)hi_p = h;
    *(short8*)(lo_p) = l;
}
__device__ __forceinline__ void emit8(u16* __restrict__ dst, const float* v8) {
    emit8t(dst, dst + 8, v8);
}
__global__ void k_splitWb(const float* __restrict__ src, u16* __restrict__ dst, int ngroups) {
    int g = blockIdx.x * 256 + threadIdx.x;
    if (g < ngroups) {
        float v[8];
        *(float4*)v = *(const float4*)(src + (size_t)g * 8);
        *(float4*)(v + 4) = *(const float4*)(src + (size_t)g * 8 + 4);
        short8 h;
#pragma unroll
        for (int j = 0; j < 8; j++) h[j] = (short)f2bf(v[j]);
        *(short8*)(dst + (size_t)g * 8) = h;
    }
}
__global__ void k_split_xseq(const float* __restrict__ s2, const float* __restrict__ s3,
                             const float* __restrict__ s4, const float* __restrict__ s5,
                             int t, u16* __restrict__ dst) {
    int bid = blockIdx.x;
    int xcd = bid & 7, chunk = bid >> 3;
    int z = xcd >> 1, half = xcd & 1;
    int g = chunk * 256 + threadIdx.x;
    int row = half * 5120 + (g >> 4);
    if (row >= NROWS) return;
    int gg = g & 15;
    const float* s = (z == 0) ? s2 : (z == 1) ? s3 : (z == 2) ? s4 : s5;
    const float* p = s + (size_t)row * (TSEQ * FDIM) + t * FDIM + gg * 8;
    float v[8];
    *(float4*)v = *(const float4*)p;
    *(float4*)(v + 4) = *(const float4*)(p + 4);
    u16* d = dst + (size_t)z * XZS;
    emit8t(d + tpo128(row, gg, 0), d + tpo128(row, gg, 1), v);
}
__global__ void k_split_xtree(const float* __restrict__ tree, int t, u16* __restrict__ dst) {
    int bid = blockIdx.x;
    int xcd = bid & 7, chunk = bid >> 3;
    int g = chunk * 256 + threadIdx.x;
    int row = xcd * 1280 + (g >> 4);
    if (row >= NROWS) return;
    int col = (g & 15) * 8;
    const float* p = tree + (size_t)row * (LTREE * FDIM) + t * FDIM + col;
    float v[8];
    *(float4*)v = *(const float4*)p;
    *(float4*)(v + 4) = *(const float4*)(p + 4);
    emit8(dst + (size_t)row * 256 + (size_t)(g & 15) * 16, v);
}
// (fvF + fvB) f32 -> old paired (GCN conv input)
__global__ void k_splitNH2(const float* __restrict__ a, const float* __restrict__ b,
                           u16* __restrict__ dst) {
    int g = blockIdx.x * 256 + threadIdx.x;
    if (g < NROWS * 32) {
        float v[8];
        float4 x0 = *(const float4*)(a + (size_t)g * 8);
        float4 x1 = *(const float4*)(a + (size_t)g * 8 + 4);
        float4 y0 = *(const float4*)(b + (size_t)g * 8);
        float4 y1 = *(const float4*)(b + (size_t)g * 8 + 4);
        v[0] = x0.x + y0.x; v[1] = x0.y + y0.y; v[2] = x0.z + y0.z; v[3] = x0.w + y0.w;
        v[4] = x1.x + y1.x; v[5] = x1.y + y1.y; v[6] = x1.z + y1.z; v[7] = x1.w + y1.w;
        emit8(dst + (size_t)g * 16, v);
    }
}

// ---------------------------------------------------------------------------
// GRU step: 128-row A-tile, RF=8, tiled staging; 4-buffer 2-deep prefetch
// with counted vmcnt (T3/T4): stage loads stay in flight across barriers.
// ---------------------------------------------------------------------------
template <int KX>
__global__ __launch_bounds__(256, 2) void k_rnn_step(
    const float* __restrict__ q0, const float* __restrict__ q1,
    const float* __restrict__ q2, const float* __restrict__ q3,
    int qoff4, u16* __restrict__ xnext,
    const u16* __restrict__ xp, long long xzs, long long xo0, long long xo1,
    const u16* __restrict__ Wih, long long wz,
    const u16* __restrict__ Whh, long long wzh,
    const float* __restrict__ bihB, const float* __restrict__ bhhB,
    const u16* __restrict__ hp, long long hz,
    u16* __restrict__ op, long long ozs) {
    __shared__ u16 lds[4][8192];
    const int tid = threadIdx.x, lane = tid & 63, w = tid >> 6;
    const int lx = lane & 15, lg = lane >> 4;
    int cbi, yy, z;
    xcd_swz(cbi, yy, z);
    const int colw = cbi * 64 + w * 16;
    const int m0 = yy * 128;
    const u16* xb = xp + (size_t)z * xzs + (size_t)((z == 1) ? xo1 : xo0) +
                    (size_t)yy * (KX * 256);
    const u16* hb = hp + (size_t)z * hz;
    const u16* hbt = hb + (size_t)yy * HTILE;
    const float* bih = bihB + z * 768;
    const float* bhh = bhhB + z * 768;
    constexpr int NCX = KX / 32;
    constexpr int NC = NCX + 8;

    const u16* bx0 = Wih + (size_t)z * wz + (size_t)(colw + lx) * KX + lg * 8;
    const u16* bx1 = bx0 + (size_t)256 * KX;
    const u16* bx2 = bx0 + (size_t)512 * KX;
    const u16* bh0 = Whh + (size_t)z * wzh + (size_t)(colw + lx) * 256 + lg * 8;
    const u16* bh1 = bh0 + 65536;
    const u16* bh2 = bh0 + 131072;

    const f32x4 zf = {0.f, 0.f, 0.f, 0.f};
    f32x4 aR[8], aZ[8], aNX[8], aNH[8];
#pragma unroll
    for (int rf = 0; rf < 8; rf++) { aR[rf] = zf; aZ[rf] = zf; aNX[rf] = zf; aNH[rf] = zf; }

    // ---- fused next-timestep x split FIRST (older than all stage loads) ----
    if (xnext) {
        const float* qs = (z == 0) ? q0 : (z == 1) ? q1 : (z == 2) ? q2 : q3;
        int row = m0 + (tid >> 1);
        if (row < NROWS) {
            int g0 = (cbi * 32 + (tid & 1) * 16) >> 3;
            const float* p = qs + (size_t)row * (TSEQ * FDIM) + qoff4 + g0 * 8;
            u16* d = xnext + (size_t)z * XZS;
            float v[8];
            *(float4*)v = *(const float4*)p;
            *(float4*)(v + 4) = *(const float4*)(p + 4);
            emit8t(d + tpo128(row, g0, 0), d + tpo128(row, g0, 1), v);
            *(float4*)v = *(const float4*)(p + 8);
            *(float4*)(v + 4) = *(const float4*)(p + 12);
            emit8t(d + tpo128(row, g0 + 1, 0), d + tpo128(row, g0 + 1, 1), v);
        }
    }

    auto chunksrc = [&](int c) -> const u16* {
        return (c < NCX) ? xb + (size_t)c * 8192 : hbt + (size_t)(c - NCX) * 8192;
    };
    stageT(lds[0], chunksrc(0), w, lane);
    stageT(lds[1], chunksrc(1), w, lane);

    for (int c = 0; c < NC; c++) {
        if (c + 2 < NC) {
            stageT(lds[(c + 2) & 3], chunksrc(c + 2), w, lane);
            __builtin_amdgcn_sched_barrier(0);
            asm volatile("s_waitcnt vmcnt(8)");
        } else if (c + 1 < NC) {
            __builtin_amdgcn_sched_barrier(0);
            asm volatile("s_waitcnt vmcnt(4)");
        } else {
            __builtin_amdgcn_sched_barrier(0);
            asm volatile("s_waitcnt vmcnt(0)");
        }
        __builtin_amdgcn_s_barrier();
        __builtin_amdgcn_sched_barrier(0);
        const u16* lb = lds[c & 3];
        const bool isX = (c < NCX);
        const int cl = isX ? c : c - NCX;
        short8 axh[8], axl[8];
        const u16* ph = lb + (size_t)(2 * lg) * 1024 + lx * 8;
#pragma unroll
        for (int rf = 0; rf < 8; rf++) {
            axh[rf] = ldf(ph + rf * 128);
            axl[rf] = ldf(ph + 1024 + rf * 128);
        }
        const int ko = cl * 32;
        if (isX) {
            {
                short8 bh_ = ldf(bx0 + ko);
#pragma unroll
                for (int rf = 0; rf < 8; rf++) MF2(axh[rf], axl[rf], bh_, aR[rf]);
            }
            {
                short8 bh_ = ldf(bx1 + ko);
#pragma unroll
                for (int rf = 0; rf < 8; rf++) MF2(axh[rf], axl[rf], bh_, aZ[rf]);
            }
            {
                short8 bh_ = ldf(bx2 + ko);
#pragma unroll
                for (int rf = 0; rf < 8; rf++) MF2(axh[rf], axl[rf], bh_, aNX[rf]);
            }
        } else {
            {
                short8 bh_ = ldf(bh0 + ko);
#pragma unroll
                for (int rf = 0; rf < 8; rf++) MF2(axh[rf], axl[rf], bh_, aR[rf]);
            }
            {
                short8 bh_ = ldf(bh1 + ko);
#pragma unroll
                for (int rf = 0; rf < 8; rf++) MF2(axh[rf], axl[rf], bh_, aZ[rf]);
            }
            {
                short8 bh_ = ldf(bh2 + ko);
#pragma unroll
                for (int rf = 0; rf < 8; rf++) MF2(axh[rf], axl[rf], bh_, aNH[rf]);
            }
        }
    }
    const int col = colw + lx;
    const float b_r = bih[col] + bhh[col];
    const float b_z = bih[256 + col] + bhh[256 + col];
    const float bx_n = bih[512 + col], bh_n = bhh[512 + col];
    const int g = col >> 3;
    const size_t colpart = (size_t)(g >> 2) * 8192 + (size_t)((g & 3) << 1) * 1024 + (col & 7);
    u16* ob = op + (size_t)z * ozs;
#pragma unroll
    for (int rf = 0; rf < 8; rf++) {
#pragma unroll
        for (int rr = 0; rr < 4; rr++) {
            int row = m0 + rf * 16 + lg * 4 + rr;
            if (row < NROWS) {
                float rg = fsig_(aR[rf][rr] + b_r);
                float zg = fsig_(aZ[rf][rr] + b_z);
                float ng = ftanh_(aNX[rf][rr] + bx_n + rg * (aNH[rf][rr] + bh_n));
                size_t addr = (size_t)(row >> 7) * HTILE + (size_t)(row & 127) * 8 + colpart;
                float hold = bf2f(hb[addr]) + bf2f(hb[addr + 1024]);
                float hnew = (1.f - zg) * ng + zg * hold;
                u16 hh = f2bf(hnew);
                ob[addr] = hh;
                ob[addr + 1024] = f2bf(hnew - bf2f(hh));
            }
        }
    }
}

// ---------------------------------------------------------------------------
// comb GRU step: 64-row tile, RF=4, 3 waves/SIMD, K=256. grid (4,160,2).
// 4-buffer 2-deep prefetch + counted vmcnt (2 loads/wave/chunk).
// ---------------------------------------------------------------------------
__global__ __launch_bounds__(256, 3) void k_rnn_step64(
    const u16* __restrict__ xp, long long xo0, long long xo1,
    const u16* __restrict__ Wih, long long wz,
    const u16* __restrict__ Whh, long long wzh,
    const float* __restrict__ bihB, const float* __restrict__ bhhB,
    const u16* __restrict__ hp, long long hz,
    u16* __restrict__ op, long long ozs) {
    __shared__ u16 lds[4][4096];
    const int tid = threadIdx.x, lane = tid & 63, w = tid >> 6;
    const int lx = lane & 15, lg = lane >> 4;
    int cbi, yy, z;
    xcd_swz(cbi, yy, z);
    const int colw = cbi * 64 + w * 16;
    const int m0 = yy * 64;
    const int tile = yy >> 1, rh = yy & 1;
    const u16* xb = xp + (size_t)((z == 1) ? xo1 : xo0) + (size_t)tile * HTILE + rh * 512;
    const u16* hb = hp + (size_t)z * hz;
    const u16* hbt = hb + (size_t)tile * HTILE + rh * 512;
    const float* bih = bihB + z * 768;
    const float* bhh = bhhB + z * 768;
    constexpr int NCX = 8, NC = 16;

    const u16* bx0 = Wih + (size_t)z * wz + (size_t)(colw + lx) * 256 + lg * 8;
    const u16* bx1 = bx0 + 65536;
    const u16* bx2 = bx0 + 131072;
    const u16* bh0 = Whh + (size_t)z * wzh + (size_t)(colw + lx) * 256 + lg * 8;
    const u16* bh1 = bh0 + 65536;
    const u16* bh2 = bh0 + 131072;

    const f32x4 zf = {0.f, 0.f, 0.f, 0.f};
    f32x4 aR[4], aZ[4], aNX[4], aNH[4];
#pragma unroll
    for (int rf = 0; rf < 4; rf++) { aR[rf] = zf; aZ[rf] = zf; aNX[rf] = zf; aNH[rf] = zf; }

    auto chunksrc = [&](int c) -> const u16* {
        return (c < NCX) ? xb + (size_t)c * 8192 : hbt + (size_t)(c - NCX) * 8192;
    };
    stage64T(lds[0], chunksrc(0), w, lane);
    stage64T(lds[1], chunksrc(1), w, lane);

    for (int c = 0; c < NC; c++) {
        if (c + 2 < NC) {
            stage64T(lds[(c + 2) & 3], chunksrc(c + 2), w, lane);
            __builtin_amdgcn_sched_barrier(0);
            asm volatile("s_waitcnt vmcnt(4)");
        } else if (c + 1 < NC) {
            __builtin_amdgcn_sched_barrier(0);
            asm volatile("s_waitcnt vmcnt(2)");
        } else {
            __builtin_amdgcn_sched_barrier(0);
            asm volatile("s_waitcnt vmcnt(0)");
        }
        __builtin_amdgcn_s_barrier();
        __builtin_amdgcn_sched_barrier(0);
        const u16* lb = lds[c & 3];
        const bool isX = (c < NCX);
        const int cl = isX ? c : c - NCX;
        short8 axh[4], axl[4];
        const u16* ph = lb + (size_t)(2 * lg) * 512 + lx * 8;
#pragma unroll
        for (int rf = 0; rf < 4; rf++) {
            axh[rf] = ldf(ph + rf * 128);
            axl[rf] = ldf(ph + 512 + rf * 128);
        }
        const int ko = cl * 32;
        if (isX) {
            {
                short8 bh_ = ldf(bx0 + ko);
#pragma unroll
                for (int rf = 0; rf < 4; rf++) MF2(axh[rf], axl[rf], bh_, aR[rf]);
            }
            {
                short8 bh_ = ldf(bx1 + ko);
#pragma unroll
                for (int rf = 0; rf < 4; rf++) MF2(axh[rf], axl[rf], bh_, aZ[rf]);
            }
            {
                short8 bh_ = ldf(bx2 + ko);
#pragma unroll
                for (int rf = 0; rf < 4; rf++) MF2(axh[rf], axl[rf], bh_, aNX[rf]);
            }
        } else {
            {
                short8 bh_ = ldf(bh0 + ko);
#pragma unroll
                for (int rf = 0; rf < 4; rf++) MF2(axh[rf], axl[rf], bh_, aR[rf]);
            }
            {
                short8 bh_ = ldf(bh1 + ko);
#pragma unroll
                for (int rf = 0; rf < 4; rf++) MF2(axh[rf], axl[rf], bh_, aZ[rf]);
            }
            {
                short8 bh_ = ldf(bh2 + ko);
#pragma unroll
                for (int rf = 0; rf < 4; rf++) MF2(axh[rf], axl[rf], bh_, aNH[rf]);
            }
        }
    }
    const int col = colw + lx;
    const float b_r = bih[col] + bhh[col];
    const float b_z = bih[256 + col] + bhh[256 + col];
    const float bx_n = bih[512 + col], bh_n = bhh[512 + col];
    const int g = col >> 3;
    const size_t colpart = (size_t)(g >> 2) * 8192 + (size_t)((g & 3) << 1) * 1024 + (col & 7);
    u16* ob = op + (size_t)z * ozs;
#pragma unroll
    for (int rf = 0; rf < 4; rf++) {
#pragma unroll
        for (int rr = 0; rr < 4; rr++) {
            int row = m0 + rf * 16 + lg * 4 + rr;
            if (row < NROWS) {
                float rg = fsig_(aR[rf][rr] + b_r);
                float zg = fsig_(aZ[rf][rr] + b_z);
                float ng = ftanh_(aNX[rf][rr] + bx_n + rg * (aNH[rf][rr] + bh_n));
                size_t addr = (size_t)(row >> 7) * HTILE + (size_t)(row & 127) * 8 + colpart;
                float hold = bf2f(hb[addr]) + bf2f(hb[addr + 1024]);
                float hnew = (1.f - zg) * ng + zg * hold;
                u16 hh = f2bf(hnew);
                ob[addr] = hh;
                ob[addr + 1024] = f2bf(hnew - bf2f(hh));
            }
        }
    }
}

// ---------------------------------------------------------------------------
// TreeLSTM step (unchanged from r15).
// ---------------------------------------------------------------------------
__global__ __launch_bounds__(256, 3) void k_tree_step_mf(
    const float* __restrict__ treenext, u16* __restrict__ xtnext,
    const u16* __restrict__ txp,
    const u16* __restrict__ Wx, const u16* __restrict__ Wh,
    const u16* __restrict__ Wfx, const u16* __restrict__ Wfh,
    const float* __restrict__ bioux, const float* __restrict__ biouh,
    const float* __restrict__ bfx, const float* __restrict__ bfh,
    const u16* __restrict__ hp, float* __restrict__ cst,
    u16* __restrict__ op, int tiledOut) {
    __shared__ u16 lds[2][8192];
    const int tid = threadIdx.x, lane = tid & 63, w = tid >> 6;
    const int lx = lane & 15, lg = lane >> 4;
    int cbi, yy, zz;
    xcd_swz(cbi, yy, zz);
    const int colw = cbi * 64 + w * 16;
    const int m0 = yy * 64;
    constexpr int NCX = 2, NC = 6;

    const u16* bx0 = Wx + (size_t)(colw + lx) * 128 + lg * 8;
    const u16* bx1 = bx0 + 32768;
    const u16* bx2 = bx0 + 65536;
    const u16* bxf = Wfx + (size_t)(colw + lx) * 128 + lg * 8;
    const u16* bh0 = Wh + (size_t)(colw + lx) * 256 + lg * 8;
    const u16* bh1 = bh0 + 65536;
    const u16* bh2 = bh0 + 131072;
    const u16* bhf = Wfh + (size_t)(colw + lx) * 256 + lg * 8;

    const f32x4 zf = {0.f, 0.f, 0.f, 0.f};
    f32x4 aI[4], aO[4], aU[4], aF[4];
#pragma unroll
    for (int rf = 0; rf < 4; rf++) { aI[rf] = zf; aO[rf] = zf; aU[rf] = zf; aF[rf] = zf; }

    stage_chunk64(lds[0], txp, 256, 0, m0, w, lane);

    if (xtnext) {
        int row = m0 + (tid >> 2);
        if (row < NROWS) {
            int c0 = cbi * 32 + (tid & 3) * 8;
            const float* p = treenext + (size_t)row * (LTREE * FDIM) + c0;
            float v[8];
            *(float4*)v = *(const float4*)p;
            *(float4*)(v + 4) = *(const float4*)(p + 4);
            emit8(xtnext + (size_t)row * 256 + (size_t)(c0 >> 3) * 16, v);
        }
    }

    for (int c = 0; c < NC; c++) {
        __syncthreads();
        if (c + 1 < NC) {
            u16* nb = lds[(c + 1) & 1];
            if (c + 1 < NCX) stage_chunk64(nb, txp, 256, (c + 1) * 128, m0, w, lane);
            else stage_chunk64(nb, hp, 512, (c + 1 - NCX) * 128, m0, w, lane);
        }
        const u16* lb = lds[c & 1];
        const bool isX = (c < NCX);
        const int cl = isX ? c : c - NCX;
#pragma unroll
        for (int s = 0; s < 2; s++) {
            short8 axh[4], axl[4];
            const u16* ph = lb + (size_t)(2 * (s * 4 + lg)) * 512 + lx * 8;
#pragma unroll
            for (int rf = 0; rf < 4; rf++) {
                axh[rf] = ldf(ph + rf * 128);
                axl[rf] = ldf(ph + 512 + rf * 128);
            }
            const int ko = cl * 64 + s * 32;
            const u16* p0 = isX ? bx0 : bh0;
            const u16* p1 = isX ? bx1 : bh1;
            const u16* p2 = isX ? bx2 : bh2;
            const u16* p3 = isX ? bxf : bhf;
            {
                short8 bh_ = ldf(p0 + ko);
#pragma unroll
                for (int rf = 0; rf < 4; rf++) MF2(axh[rf], axl[rf], bh_, aI[rf]);
            }
            {
                short8 bh_ = ldf(p1 + ko);
#pragma unroll
                for (int rf = 0; rf < 4; rf++) MF2(axh[rf], axl[rf], bh_, aO[rf]);
            }
            {
                short8 bh_ = ldf(p2 + ko);
#pragma unroll
                for (int rf = 0; rf < 4; rf++) MF2(axh[rf], axl[rf], bh_, aU[rf]);
            }
            {
                short8 bh_ = ldf(p3 + ko);
#pragma unroll
                for (int rf = 0; rf < 4; rf++) MF2(axh[rf], axl[rf], bh_, aF[rf]);
            }
        }
    }
    const int col = colw + lx;
    const float b_i = bioux[col] + biouh[col];
    const float b_o = bioux[256 + col] + biouh[256 + col];
    const float b_u = bioux[512 + col] + biouh[512 + col];
    const float b_f = bfx[col] + bfh[col];
    const int cpo = ((col >> 3) << 4) + (col & 7);
    const int gcol = col >> 3;
    const size_t colpart = (size_t)(gcol >> 2) * 8192 + (size_t)((gcol & 3) << 1) * 1024 + (col & 7);
#pragma unroll
    for (int rf = 0; rf < 4; rf++) {
#pragma unroll
        for (int rr = 0; rr < 4; rr++) {
            int row = m0 + rf * 16 + lg * 4 + rr;
            if (row < NROWS) {
                float ig = fsig_(aI[rf][rr] + b_i);
                float og = fsig_(aO[rf][rr] + b_o);
                float ug = ftanh_(aU[rf][rr] + b_u);
                float fg = fsig_(aF[rf][rr] + b_f);
                size_t ci = (size_t)row * H + col;
                float cnew = ig * ug + fg * cst[ci];
                cst[ci] = cnew;
                float hnew = og * ftanh_(cnew);
                u16 hh = f2bf(hnew);
                if (tiledOut) {
                    size_t addr = (size_t)(row >> 7) * HTILE + (size_t)(row & 127) * 8 + colpart;
                    op[addr] = hh;
                    op[addr + 1024] = f2bf(hnew - bf2f(hh));
                } else {
                    size_t oi = (size_t)row * 512 + cpo;
                    op[oi] = hh;
                    op[oi + 8] = f2bf(hnew - bf2f(hh));
                }
            }
        }
    }
}

// fv_z += h_z @ Wc-slice^T ; z=0 forward (fvF), z=1 backward (fvB). grid (4,79,2).
__global__ __launch_bounds__(256) void k_fv_acc_mf(
    float* __restrict__ fvbase, const u16* __restrict__ hq,
    const u16* __restrict__ Wc, int off_f, int off_b) {
    const int tid = threadIdx.x, lane = tid & 63, w = tid >> 6;
    const int lx = lane & 15, kl8 = (lane >> 4);
    int cbi, yy, z;
    xcd_swz(cbi, yy, z);
    const int wr = w >> 1, wc = w & 1;
    const int cb = cbi * 64 + wc * 32;
    const int m0 = yy * 128 + wr * 64;
    int arow[4];
#pragma unroll
    for (int rf = 0; rf < 4; rf++) {
        int r = m0 + rf * 16 + lx;
        arow[rf] = (r < NROWS) ? r : NROWS - 1;
    }
    const f32x4 zf = {0.f, 0.f, 0.f, 0.f};
    f32x4 acc[4][2] = {{zf, zf}, {zf, zf}, {zf, zf}, {zf, zf}};
    const u16* aB = hq + (size_t)z * HZS;
    const int off = z ? off_b : off_f;
    const u16* a[4];
#pragma unroll
    for (int rf = 0; rf < 4; rf++) {
        a[rf] = aB + (size_t)(arow[rf] >> 7) * HTILE + (size_t)(arow[rf] & 127) * 8 +
                (size_t)kl8 * 2048;
    }
    const u16* bp0 = Wc + (size_t)(cb + lx) * 2560 + off + kl8 * 8;
    const u16* bp1 = bp0 + 16 * 2560;
#pragma unroll
    for (int it = 0; it < 8; it++) {
        short8 axh[4], axl[4];
#pragma unroll
        for (int rf = 0; rf < 4; rf++) {
            axh[rf] = ldf(a[rf]);
            axl[rf] = ldf(a[rf] + 1024);
            a[rf] += 8192;
        }
        const int kb = it * 32;
        {
            short8 bh = ldf(bp0 + kb);
#pragma unroll
            for (int rf = 0; rf < 4; rf++) MF2(axh[rf], axl[rf], bh, acc[rf][0]);
        }
        {
            short8 bh = ldf(bp1 + kb);
#pragma unroll
            for (int rf = 0; rf < 4; rf++) MF2(axh[rf], axl[rf], bh, acc[rf][1]);
        }
    }
    float* fv = fvbase + (size_t)z * (NROWS * H);
#pragma unroll
    for (int rf = 0; rf < 4; rf++) {
#pragma unroll
        for (int cf = 0; cf < 2; cf++) {
            int col = cb + cf * 16 + lx;
#pragma unroll
            for (int rr = 0; rr < 4; rr++) {
                int row = m0 + rf * 16 + (lane >> 4) * 4 + rr;
                if (row < NROWS) fv[(size_t)row * H + col] += acc[rf][cf][rr];
            }
        }
    }
}

// out = A @ W^T; RF=2, 128-row blocks, grid (4,80).
__global__ __launch_bounds__(256) void k_gcn_gemm(
    float* __restrict__ out, const u16* __restrict__ ap_, const u16* __restrict__ W) {
    const int tid = threadIdx.x, lane = tid & 63, w = tid >> 6;
    const int lx = lane & 15, kl = (lane >> 4) * 8;
    int cbi, yy, zz;
    xcd_swz(cbi, yy, zz);
    const int cb = cbi * 64, m0 = yy * 128 + w * 32;
    int arow[2];
#pragma unroll
    for (int rf = 0; rf < 2; rf++) {
        int r = m0 + rf * 16 + lx;
        arow[rf] = (r < NROWS) ? r : NROWS - 1;
    }
    const f32x4 zf = {0.f, 0.f, 0.f, 0.f};
    f32x4 acc[2][4] = {{zf, zf, zf, zf}, {zf, zf, zf, zf}};
    const u16* a0 = ap_ + (size_t)arow[0] * 512 + kl * 2;
    const u16* a1 = ap_ + (size_t)arow[1] * 512 + kl * 2;
    const u16* bp0 = W + (size_t)(cb + lx) * 256 + kl;
    const u16* bp1 = bp0 + 16 * 256;
    const u16* bp2 = bp0 + 32 * 256;
    const u16* bp3 = bp0 + 48 * 256;
#pragma unroll
    for (int kb = 0; kb < 256; kb += 32) {
        short8 axh[2], axl[2];
        axh[0] = ldf(a0 + kb * 2); axl[0] = ldf(a0 + kb * 2 + 8);
        axh[1] = ldf(a1 + kb * 2); axl[1] = ldf(a1 + kb * 2 + 8);
        {
            short8 bh = ldf(bp0 + kb);
#pragma unroll
            for (int rf = 0; rf < 2; rf++) MF2(axh[rf], axl[rf], bh, acc[rf][0]);
        }
        {
            short8 bh = ldf(bp1 + kb);
#pragma unroll
            for (int rf = 0; rf < 2; rf++) MF2(axh[rf], axl[rf], bh, acc[rf][1]);
        }
        {
            short8 bh = ldf(bp2 + kb);
#pragma unroll
            for (int rf = 0; rf < 2; rf++) MF2(axh[rf], axl[rf], bh, acc[rf][2]);
        }
        {
            short8 bh = ldf(bp3 + kb);
#pragma unroll
            for (int rf = 0; rf < 2; rf++) MF2(axh[rf], axl[rf], bh, acc[rf][3]);
        }
    }
#pragma unroll
    for (int rf = 0; rf < 2; rf++) {
#pragma unroll
        for (int cf = 0; cf < 4; cf++) {
            int col = cb + cf * 16 + lx;
#pragma unroll
            for (int rr = 0; rr < 4; rr++) {
                int row = m0 + rf * 16 + (lane >> 4) * 4 + rr;
                if (row < NROWS) out[(size_t)row * H + col] = acc[rf][cf][rr];
            }
        }
    }
}

// ---------------------------- GCN small kernels -----------------------------
__global__ void k_fv_init(float* fv, const float* __restrict__ b) {
    int idx = blockIdx.x * 256 + threadIdx.x;
    if (idx < NROWS * H) fv[idx] = b[idx & (H - 1)];
}
__global__ void k_cnt(int* __restrict__ cnt, const int* __restrict__ dst) {
    int i = blockIdx.x * 256 + threadIdx.x;
    if (i < NE) atomicAdd(&cnt[dst[i]], 1);
}
__global__ void k_scan(const int* __restrict__ cnt, int* __restrict__ rowptr) {
    __shared__ int part[256];
    int tid = threadIdx.x;
    int st = tid * 40, en = (st + 40 > NROWS) ? NROWS : st + 40;
    int s = 0;
    for (int i = st; i < en; i++) s += cnt[i];
    part[tid] = s;
    __syncthreads();
    if (tid == 0) {
        int run = 0;
        for (int i = 0; i < 256; i++) { int t = part[i]; part[i] = run; run += t; }
        rowptr[NROWS] = run;
    }
    __syncthreads();
    int run = part[tid];
    for (int i = st; i < en; i++) { rowptr[i] = run; run += cnt[i]; }
}
__global__ void k_dinv(float* __restrict__ dinv, const int* __restrict__ cnt) {
    int i = blockIdx.x * 256 + threadIdx.x;
    if (i < NROWS) dinv[i] = rsqrtf(1.0f + (float)cnt[i]);
}
__global__ void k_fill(int* __restrict__ csr, int* __restrict__ cursor,
                       const int* __restrict__ rowptr, const int* __restrict__ ei) {
    int e = blockIdx.x * 256 + threadIdx.x;
    if (e < NE) {
        int d = ei[NE + e];
        int p = atomicAdd(&cursor[d], 1);
        csr[rowptr[d] + p] = ei[e];
    }
}
__global__ __launch_bounds__(256) void k_gather(
    float* __restrict__ out, u16* __restrict__ xcp,
    const float* __restrict__ xw, const float* __restrict__ dinv,
    const int* __restrict__ rowptr, const int* __restrict__ csr, const float* __restrict__ b) {
    int node = blockIdx.x * 4 + (threadIdx.x >> 6);
    if (node >= NROWS) return;
    int lane = threadIdx.x & 63;
    float dn = dinv[node];
    float4 acc = *(const float4*)(xw + (size_t)node * H + lane * 4);
    float dn2 = dn * dn;
    acc.x *= dn2; acc.y *= dn2; acc.z *= dn2; acc.w *= dn2;
    int e0 = rowptr[node], e1 = rowptr[node + 1];
    for (int i = e0; i < e1; i++) {
        int s = csr[i];
        float wgt = dn * dinv[s];
        const float4 v = *(const float4*)(xw + (size_t)s * H + lane * 4);
        acc.x += v.x * wgt; acc.y += v.y * wgt; acc.z += v.z * wgt; acc.w += v.w * wgt;
    }
    const float4 bv = *(const float4*)(b + lane * 4);
    float o[4];
    o[0] = fmaxf(acc.x + bv.x, 0.f);
    o[1] = fmaxf(acc.y + bv.y, 0.f);
    o[2] = fmaxf(acc.z + bv.z, 0.f);
    o[3] = fmaxf(acc.w + bv.w, 0.f);
    *(float4*)(out + (size_t)node * H + lane * 4) = *(const float4*)o;
    u16 hs[4], ls[4];
#pragma unroll
    for (int j = 0; j < 4; j++) {
        hs[j] = f2bf(o[j]);
        ls[j] = f2bf(o[j] - bf2f(hs[j]));
    }
    size_t bidx = (size_t)node * 512 + (size_t)(lane >> 1) * 16 + (lane & 1) * 4;
    *(short4*)(xcp + bidx) = *(const short4*)hs;
    *(short4*)(xcp + bidx + 8) = *(const short4*)ls;
}
__global__ void k_colmax(float* __restrict__ out, const float* __restrict__ x) {
    int j = threadIdx.x;
    float m = 0.0f;
    for (int r = blockIdx.x; r < NROWS; r += gridDim.x)
        m = fmaxf(m, x[(size_t)r * H + j]);
    atomicMax((int*)&out[j], __float_as_int(m));
}

// ---------------------------------------------------------------------------
extern "C" void kernel_launch(void* const* d_in, const int* in_sizes, int n_in,
                              void* d_out, int out_size, void* d_ws, size_t ws_size,
                              hipStream_t stream) {
    const float* tree = (const float*)d_in[0];
    const float* s2 = (const float*)d_in[1];
    const float* s3 = (const float*)d_in[2];
    const float* s4 = (const float*)d_in[3];
    const float* s5 = (const float*)d_in[4];
    const int* edge = (const int*)d_in[5];
    const float* tl_Wioux = (const float*)d_in[6];
    const float* tl_bioux = (const float*)d_in[7];
    const float* tl_Wiouh = (const float*)d_in[8];
    const float* tl_biouh = (const float*)d_in[9];
    const float* tl_Wfx = (const float*)d_in[10];
    const float* tl_bfx = (const float*)d_in[11];
    const float* tl_Wfh = (const float*)d_in[12];
    const float* tl_bfh = (const float*)d_in[13];
    const float* gru_Wih = (const float*)d_in[14];
    const float* gru_Whh = (const float*)d_in[15];
    const float* gru_bih = (const float*)d_in[16];
    const float* gru_bhh = (const float*)d_in[17];
    const float* comb_Wih = (const float*)d_in[18];
    const float* comb_Whh = (const float*)d_in[19];
    const float* comb_bih = (const float*)d_in[20];
    const float* comb_bhh = (const float*)d_in[21];
    const float* connect_W = (const float*)d_in[22];
    const float* connect_b = (const float*)d_in[23];
    const float* gcn_W = (const float*)d_in[24];
    const float* gcn_b = (const float*)d_in[25];

    char* base = (char*)d_ws;
    size_t off = 0;
    auto aus = [&](size_t nu16) { u16* p = (u16*)(base + off); off += nu16 * sizeof(u16); return p; };
    u16* tx = aus(98304);
    u16* th = aus(196608);
    u16* tfx = aus(32768);
    u16* tfh = aus(65536);
    u16* gWih = aus(393216);
    u16* gWhh = aus(786432);
    u16* cWih = aus(393216);
    u16* cWhh = aus(393216);
    u16* cn = aus(655360);
    u16* gc = aus(196608);
    u16* feats = aus((size_t)5 * HZS);
    u16* hA = aus((size_t)4 * HZS);
    u16* hB = aus((size_t)4 * HZS);
    u16* SA = aus((size_t)4 * XZS);
    u16* SB = aus((size_t)4 * XZS);

    const dim3 blk(256);

    hipMemsetAsync(d_out, 0, H * sizeof(float), stream);

    auto SPW = [&](const float* s, u16* d, int n) {
        k_splitWb<<<(n / 8 + 255) / 256, blk, 0, stream>>>(s, d, n / 8);
    };
    SPW(tl_Wioux, tx, 98304);
    SPW(tl_Wiouh, th, 196608);
    SPW(tl_Wfx, tfx, 32768);
    SPW(tl_Wfh, tfh, 65536);
    SPW(gru_Wih, gWih, 393216);
    SPW(gru_Whh, gWhh, 786432);
    SPW(comb_Wih, cWih, 393216);
    SPW(comb_Whh, cWhh, 393216);
    SPW(connect_W, cn, 655360);
    SPW(gcn_W, gc, 196608);

    // -------- TreeLSTM (8 steps) --------
    float* cbuf = (float*)SA;
    u16* xtA = SA + 5120000;
    u16* xtB = SA + 7680000;
    hipMemsetAsync(hA, 0, (size_t)NROWS * 512 * 2, stream);
    hipMemsetAsync(cbuf, 0, (size_t)NROWS * H * 4, stream);
    k_split_xtree<<<640, blk, 0, stream>>>(tree, 0, xtA);
    {
        u16 *p = hA, *q = hB;
        for (int t = 0; t < LTREE; ++t) {
            bool last = (t == LTREE - 1);
            u16* xin = (t & 1) ? xtB : xtA;
            u16* xnx = last ? (u16*)0 : ((t & 1) ? xtA : xtB);
            k_tree_step_mf<<<dim3(4, 160, 1), blk, 0, stream>>>(
                tree + (t + 1) * FDIM, xnx,
                xin, tx, th, tfx, tfh, tl_bioux, tl_biouh, tl_bfx, tl_bfh,
                p, cbuf, last ? feats : q, last ? 1 : 0);
            u16* tmp = p; p = q; q = tmp;
        }
    }

    // -------- 4 GRUs (16 steps, z=4) --------
    u16* xsA = SA;
    u16* xsB = SB;
    hipMemsetAsync(hA, 0, (size_t)4 * HZS * 2, stream);
    k_split_xseq<<<2560, blk, 0, stream>>>(s2, s3, s4, s5, 0, xsA);
    {
        u16 *p = hA, *q = hB;
        for (int t = 0; t < TSEQ; ++t) {
            bool last = (t == TSEQ - 1);
            u16* xin = (t & 1) ? xsB : xsA;
            u16* xnx = last ? (u16*)0 : ((t & 1) ? xsA : xsB);
            k_rnn_step<128><<<dim3(4, 80, 4), blk, 0, stream>>>(
                s2, s3, s4, s5, (t + 1) * FDIM, xnx,
                xin, (long long)XZS, 0LL, 0LL,
                gWih, 98304LL, gWhh, 196608LL, gru_bih, gru_bhh,
                p, (long long)HZS,
                last ? feats + HZS : q, (long long)HZS);
            u16* tmp = p; p = q; q = tmp;
        }
    }

    // -------- combine bi-GRU (5 steps, z=2) + fused connect --------
    float* fvF = (float*)SA;
    float* fvB = fvF + (size_t)NROWS * H;
    hipMemsetAsync(hA, 0, (size_t)2 * HZS * 2, stream);
    k_fv_init<<<(NROWS * H + 255) / 256, blk, 0, stream>>>(fvF, connect_b);
    hipMemsetAsync(fvB, 0, (size_t)NROWS * H * 4, stream);
    {
        u16 *p = hA, *q = hB;
        for (int s = 0; s < 5; ++s) {
            k_rnn_step64<<<dim3(4, 160, 2), blk, 0, stream>>>(
                feats, (long long)s * HZS, (long long)(4 - s) * HZS,
                cWih, 196608LL, cWhh, 196608LL, comb_bih, comb_bhh,
                p, (long long)HZS,
                q, (long long)HZS);
            k_fv_acc_mf<<<dim3(4, 79, 2), blk, 0, stream>>>(
                fvF, q, cn, s * 512, (4 - s) * 512 + 256);
            u16* tmp = p; p = q; q = tmp;
        }
    }

    // -------- CSR build --------
    int* cnt = (int*)(hB + 12000000);
    int* rowptr = cnt + 10016;
    int* cursor = rowptr + 10016;
    int* csr = cursor + 10016;
    float* dinv = (float*)(csr + NE);
    hipMemsetAsync(cnt, 0, NROWS * sizeof(int), stream);
    hipMemsetAsync(cursor, 0, NROWS * sizeof(int), stream);
    k_cnt<<<(NE + 255) / 256, blk, 0, stream>>>(cnt, edge + NE);
    k_scan<<<1, blk, 0, stream>>>(cnt, rowptr);
    k_dinv<<<(NROWS + 255) / 256, blk, 0, stream>>>(dinv, cnt);
    k_fill<<<(NE + 255) / 256, blk, 0, stream>>>(csr, cursor, rowptr, edge);

    // -------- 4 conv applications (last two share W2,b2) --------
    {
        u16* xc = hB;
        float* xw = (float*)SB;
        float* cur = fvF;
        float* nxt = (float*)hA;
        k_splitNH2<<<1250, blk, 0, stream>>>(fvF, fvB, xc);
        for (int i = 0; i < 4; ++i) {
            int wi = (i < 3) ? i : 2;
            k_gcn_gemm<<<dim3(4, 80, 1), blk, 0, stream>>>(xw, xc, gc + (size_t)wi * 65536);
            k_gather<<<(NROWS + 3) / 4, blk, 0, stream>>>(nxt, xc, xw, dinv, rowptr, csr,
                                                          gcn_b + wi * H);
            float* tmp = cur; cur = nxt; nxt = tmp;
        }
        k_colmax<<<256, blk, 0, stream>>>((float*)d_out, cur);
    }
}

// Round 17
// 1932.399 us; speedup vs baseline: 1.1937x; 1.1937x over previous
//
#include <hip/hip_runtime.h>
#include <math.h>

#define H 256
#define NROWS 10000
#define LTREE 8
#define TSEQ 16
#define FDIM 128
#define NE 160000
#define HTILE2 32768     // 128 rows * 256 cols hi-only (u16)
#define XTILE 32768      // 128 rows * 128 cols * 2 halves (u16)
#define H2 2621440       // 80 tiles * HTILE2 (u16)
#define XZS 2621440      // 80 tiles * XTILE

typedef __attribute__((ext_vector_type(8))) short short8;
typedef __attribute__((ext_vector_type(4))) float f32x4;
typedef unsigned short u16;

__device__ __forceinline__ u16 f2bf(float x) {
    unsigned int u = __float_as_uint(x);
    return (u16)((u + 0x7fffu + ((u >> 16) & 1u)) >> 16);
}
__device__ __forceinline__ float bf2f(u16 s) { return __uint_as_float(((unsigned int)s) << 16); }
__device__ __forceinline__ short8 ldf(const u16* __restrict__ p) { return *(const short8*)(p); }
__device__ __forceinline__ float fexp_(float x) { return __expf(fminf(x, 80.f)); }
__device__ __forceinline__ float fsig_(float x) { return 1.f / (1.f + fexp_(-x)); }
__device__ __forceinline__ float ftanh_(float x) {
    float e = fexp_(fmaxf(2.f * x, -80.f));
    return (e - 1.f) / (e + 1.f);
}
#define MFMA(A, B, C) C = __builtin_amdgcn_mfma_f32_16x16x32_bf16(A, B, C, 0, 0, 0)
#define MF2(AH, AL, BH, C) do { MFMA(AH, BH, C); MFMA(AL, BH, C); } while (0)

__device__ __forceinline__ void async16(u16* l, const u16* g) {
    __builtin_amdgcn_global_load_lds((__attribute__((address_space(1))) const void*)g,
                                     (__attribute__((address_space(3))) void*)l, 16, 0, 0);
}

// XCD-aware remap, bijective when nwg%8==0.
__device__ __forceinline__ void xcd_swz(int& cbi, int& yy, int& zz) {
    const int gx = gridDim.x, gy = gridDim.y;
    int nwg8 = (gx * gy * gridDim.z) >> 3;
    int bid = blockIdx.x + gx * (blockIdx.y + gy * blockIdx.z);
    int wgid = (bid & 7) * nwg8 + (bid >> 3);
    cbi = wgid % gx;
    int rem = wgid / gx;
    yy = rem % gy;
    zz = rem / gy;
}

// paired-x tiled offset (row, k-group g, half)
__device__ __forceinline__ size_t tpo128(int row, int g, int half) {
    return (size_t)(row >> 7) * XTILE + (size_t)(g >> 2) * 8192 +
           (size_t)((((g & 3) << 1) | half)) * 1024 + (size_t)(row & 127) * 8;
}
// hi-only tiled offset: [tile][kgroup g][row][8]
__device__ __forceinline__ size_t hpo(int row, int g) {
    return (size_t)(row >> 7) * HTILE2 + (size_t)g * 1024 + (size_t)(row & 127) * 8;
}

// Stage one 16KB chunk (pre-tiled source == LDS image), 128-row tiles. 4 loads/wave.
__device__ __forceinline__ void stageT(u16* ldsbuf, const u16* __restrict__ chunkbase,
                                       int w, int lane) {
#pragma unroll
    for (int cc = 0; cc < 4; cc++) {
        int eb = (w * 4 + cc) * 64;
        async16(ldsbuf + (size_t)eb * 8, chunkbase + (size_t)(eb + lane) * 8);
    }
}
// Stage an 8KB half-tile chunk (64 rows of a 128-row tile). 2 loads/wave.
__device__ __forceinline__ void stage64T(u16* ldsbuf, const u16* __restrict__ chunkbase,
                                         int w, int lane) {
#pragma unroll
    for (int cc = 0; cc < 2; cc++) {
        int p = w * 2 + cc;
        async16(ldsbuf + (size_t)p * 512, chunkbase + (size_t)p * 1024 + (size_t)lane * 8);
    }
}
// old-layout 64-row variant (tree kernel), with row clamp
__device__ __forceinline__ void stage_chunk64(u16* ldsbuf, const u16* __restrict__ src,
                                              int stride_u16, int kb_u16, int m0,
                                              int w, int lane) {
#pragma unroll
    for (int c = 0; c < 4; c++) {
        int e_base = (w * 4 + c) * 64;
        int e = e_base + lane;
        int p = e >> 6, rs = e & 63;
        int row = m0 + rs;
        if (row > NROWS - 1) row = NROWS - 1;
        const u16* g = src + (size_t)row * stride_u16 + kb_u16 + (p >> 1) * 16 + (p & 1) * 8;
        async16(ldsbuf + (size_t)e_base * 8, g);
    }
}

// ---------------- split helpers ----------------
__device__ __forceinline__ void emit8t(u16* __restrict__ hi_p, u16* __restrict__ lo_p,
                                       const float* v8) {
    short8 h, l;
#pragma unroll
    for (int j = 0; j < 8; j++) {
        u16 hh = f2bf(v8[j]);
        h[j] = (short)hh;
        l[j] = (short)f2bf(v8[j] - bf2f(hh));
    }
    *(short8*)hi_p = h;
    *(short8*)(lo_p) = l;
}
__device__ __forceinline__ void emit8(u16* __restrict__ dst, const float* v8) {
    emit8t(dst, dst + 8, v8);
}
__global__ void k_splitWb(const float* __restrict__ src, u16* __restrict__ dst, int ngroups) {
    int g = blockIdx.x * 256 + threadIdx.x;
    if (g < ngroups) {
        float v[8];
        *(float4*)v = *(const float4*)(src + (size_t)g * 8);
        *(float4*)(v + 4) = *(const float4*)(src + (size_t)g * 8 + 4);
        short8 h;
#pragma unroll
        for (int j = 0; j < 8; j++) h[j] = (short)f2bf(v[j]);
        *(short8*)(dst + (size_t)g * 8) = h;
    }
}
__global__ void k_split_xseq(const float* __restrict__ s2, const float* __restrict__ s3,
                             const float* __restrict__ s4, const float* __restrict__ s5,
                             int t, u16* __restrict__ dst) {
    int bid = blockIdx.x;
    int xcd = bid & 7, chunk = bid >> 3;
    int z = xcd >> 1, half = xcd & 1;
    int g = chunk * 256 + threadIdx.x;
    int row = half * 5120 + (g >> 4);
    if (row >= NROWS) return;
    int gg = g & 15;
    const float* s = (z == 0) ? s2 : (z == 1) ? s3 : (z == 2) ? s4 : s5;
    const float* p = s + (size_t)row * (TSEQ * FDIM) + t * FDIM + gg * 8;
    float v[8];
    *(float4*)v = *(const float4*)p;
    *(float4*)(v + 4) = *(const float4*)(p + 4);
    u16* d = dst + (size_t)z * XZS;
    emit8t(d + tpo128(row, gg, 0), d + tpo128(row, gg, 1), v);
}
__global__ void k_split_xtree(const float* __restrict__ tree, int t, u16* __restrict__ dst) {
    int bid = blockIdx.x;
    int xcd = bid & 7, chunk = bid >> 3;
    int g = chunk * 256 + threadIdx.x;
    int row = xcd * 1280 + (g >> 4);
    if (row >= NROWS) return;
    int col = (g & 15) * 8;
    const float* p = tree + (size_t)row * (LTREE * FDIM) + t * FDIM + col;
    float v[8];
    *(float4*)v = *(const float4*)p;
    *(float4*)(v + 4) = *(const float4*)(p + 4);
    emit8(dst + (size_t)row * 256 + (size_t)(g & 15) * 16, v);
}
// (fvF + fvB) f32 -> old paired (GCN conv input)
__global__ void k_splitNH2(const float* __restrict__ a, const float* __restrict__ b,
                           u16* __restrict__ dst) {
    int g = blockIdx.x * 256 + threadIdx.x;
    if (g < NROWS * 32) {
        float v[8];
        float4 x0 = *(const float4*)(a + (size_t)g * 8);
        float4 x1 = *(const float4*)(a + (size_t)g * 8 + 4);
        float4 y0 = *(const float4*)(b + (size_t)g * 8);
        float4 y1 = *(const float4*)(b + (size_t)g * 8 + 4);
        v[0] = x0.x + y0.x; v[1] = x0.y + y0.y; v[2] = x0.z + y0.z; v[3] = x0.w + y0.w;
        v[4] = x1.x + y1.x; v[5] = x1.y + y1.y; v[6] = x1.z + y1.z; v[7] = x1.w + y1.w;
        emit8(dst + (size_t)g * 16, v);
    }
}

// ---------------------------------------------------------------------------
// GRU step: 128-row A-tile, RF=8. x paired (MF2), h hi-only (single MFMA).
// NC = KX/32 (x chunks, 32k paired) + 4 (h chunks, 64k hi-only).
// ---------------------------------------------------------------------------
template <int KX>
__global__ __launch_bounds__(256, 2) void k_rnn_step(
    const float* __restrict__ q0, const float* __restrict__ q1,
    const float* __restrict__ q2, const float* __restrict__ q3,
    int qoff4, u16* __restrict__ xnext,
    const u16* __restrict__ xp,
    const u16* __restrict__ Wih, long long wz,
    const u16* __restrict__ Whh, long long wzh,
    const float* __restrict__ bihB, const float* __restrict__ bhhB,
    const u16* __restrict__ hp,
    u16* __restrict__ op) {
    __shared__ u16 lds[2][8192];
    const int tid = threadIdx.x, lane = tid & 63, w = tid >> 6;
    const int lx = lane & 15, lg = lane >> 4;
    int cbi, yy, z;
    xcd_swz(cbi, yy, z);
    const int colw = cbi * 64 + w * 16;
    const int m0 = yy * 128;
    const u16* xb = xp + (size_t)z * XZS + (size_t)yy * XTILE;
    const u16* hb = hp + (size_t)z * H2;
    const u16* hbt = hb + (size_t)yy * HTILE2;
    const float* bih = bihB + z * 768;
    const float* bhh = bhhB + z * 768;
    constexpr int NCX = KX / 32;
    constexpr int NC = NCX + 4;

    const u16* bx0 = Wih + (size_t)z * wz + (size_t)(colw + lx) * KX + lg * 8;
    const u16* bx1 = bx0 + (size_t)256 * KX;
    const u16* bx2 = bx0 + (size_t)512 * KX;
    const u16* bh0 = Whh + (size_t)z * wzh + (size_t)(colw + lx) * 256 + lg * 8;
    const u16* bh1 = bh0 + 65536;
    const u16* bh2 = bh0 + 131072;

    const f32x4 zf = {0.f, 0.f, 0.f, 0.f};
    f32x4 aR[8], aZ[8], aNX[8], aNH[8];
#pragma unroll
    for (int rf = 0; rf < 8; rf++) { aR[rf] = zf; aZ[rf] = zf; aNX[rf] = zf; aNH[rf] = zf; }

    auto chunksrc = [&](int c) -> const u16* {
        return (c < NCX) ? xb + (size_t)c * 8192 : hbt + (size_t)(c - NCX) * 8192;
    };
    stageT(lds[0], chunksrc(0), w, lane);

    // fused next-timestep x split (paired tiled stores)
    if (xnext) {
        const float* qs = (z == 0) ? q0 : (z == 1) ? q1 : (z == 2) ? q2 : q3;
        int row = m0 + (tid >> 1);
        if (row < NROWS) {
            int g0 = (cbi * 32 + (tid & 1) * 16) >> 3;
            const float* p = qs + (size_t)row * (TSEQ * FDIM) + qoff4 + g0 * 8;
            u16* d = xnext + (size_t)z * XZS;
            float v[8];
            *(float4*)v = *(const float4*)p;
            *(float4*)(v + 4) = *(const float4*)(p + 4);
            emit8t(d + tpo128(row, g0, 0), d + tpo128(row, g0, 1), v);
            *(float4*)v = *(const float4*)(p + 8);
            *(float4*)(v + 4) = *(const float4*)(p + 12);
            emit8t(d + tpo128(row, g0 + 1, 0), d + tpo128(row, g0 + 1, 1), v);
        }
    }

    for (int c = 0; c < NC; c++) {
        __syncthreads();  // drains DMA for lds[c&1]
        if (c + 1 < NC) stageT(lds[(c + 1) & 1], chunksrc(c + 1), w, lane);
        const u16* lb = lds[c & 1];
        if (c < NCX) {
            // paired x chunk: 32 k, MF2
            short8 axh[8], axl[8];
            const u16* ph = lb + (size_t)(2 * lg) * 1024 + lx * 8;
#pragma unroll
            for (int rf = 0; rf < 8; rf++) {
                axh[rf] = ldf(ph + rf * 128);
                axl[rf] = ldf(ph + 1024 + rf * 128);
            }
            const int ko = c * 32;
            {
                short8 bh_ = ldf(bx0 + ko);
#pragma unroll
                for (int rf = 0; rf < 8; rf++) MF2(axh[rf], axl[rf], bh_, aR[rf]);
            }
            {
                short8 bh_ = ldf(bx1 + ko);
#pragma unroll
                for (int rf = 0; rf < 8; rf++) MF2(axh[rf], axl[rf], bh_, aZ[rf]);
            }
            {
                short8 bh_ = ldf(bx2 + ko);
#pragma unroll
                for (int rf = 0; rf < 8; rf++) MF2(axh[rf], axl[rf], bh_, aNX[rf]);
            }
        } else {
            // hi-only h chunk: 64 k, 2 sub-steps, single MFMA
            const int cl = c - NCX;
#pragma unroll
            for (int s = 0; s < 2; s++) {
                short8 axh[8];
                const u16* ph = lb + (size_t)(s * 4 + lg) * 1024 + lx * 8;
#pragma unroll
                for (int rf = 0; rf < 8; rf++) axh[rf] = ldf(ph + rf * 128);
                const int ko = cl * 64 + s * 32;
                {
                    short8 bh_ = ldf(bh0 + ko);
#pragma unroll
                    for (int rf = 0; rf < 8; rf++) MFMA(axh[rf], bh_, aR[rf]);
                }
                {
                    short8 bh_ = ldf(bh1 + ko);
#pragma unroll
                    for (int rf = 0; rf < 8; rf++) MFMA(axh[rf], bh_, aZ[rf]);
                }
                {
                    short8 bh_ = ldf(bh2 + ko);
#pragma unroll
                    for (int rf = 0; rf < 8; rf++) MFMA(axh[rf], bh_, aNH[rf]);
                }
            }
        }
    }
    const int col = colw + lx;
    const float b_r = bih[col] + bhh[col];
    const float b_z = bih[256 + col] + bhh[256 + col];
    const float bx_n = bih[512 + col], bh_n = bhh[512 + col];
    const size_t colpart = (size_t)(col >> 3) * 1024 + (col & 7);
    u16* ob = op + (size_t)z * H2;
#pragma unroll
    for (int rf = 0; rf < 8; rf++) {
#pragma unroll
        for (int rr = 0; rr < 4; rr++) {
            int row = m0 + rf * 16 + lg * 4 + rr;
            if (row < NROWS) {
                float rg = fsig_(aR[rf][rr] + b_r);
                float zg = fsig_(aZ[rf][rr] + b_z);
                float ng = ftanh_(aNX[rf][rr] + bx_n + rg * (aNH[rf][rr] + bh_n));
                size_t addr = (size_t)(row >> 7) * HTILE2 + (size_t)(row & 127) * 8 + colpart;
                float hold = bf2f(hb[addr]);
                float hnew = (1.f - zg) * ng + zg * hold;
                ob[addr] = f2bf(hnew);
            }
        }
    }
}

// ---------------------------------------------------------------------------
// comb GRU step: 64-row tile, RF=4, 3 waves/SIMD; x (feats) and h both
// hi-only. NC = 4 + 4 chunks of 64k each (8KB half-tile). grid (4,160,2).
// ---------------------------------------------------------------------------
__global__ __launch_bounds__(256, 3) void k_rnn_step64(
    const u16* __restrict__ xp, long long xo0, long long xo1,
    const u16* __restrict__ Wih, long long wz,
    const u16* __restrict__ Whh, long long wzh,
    const float* __restrict__ bihB, const float* __restrict__ bhhB,
    const u16* __restrict__ hp,
    u16* __restrict__ op) {
    __shared__ u16 lds[2][4096];
    const int tid = threadIdx.x, lane = tid & 63, w = tid >> 6;
    const int lx = lane & 15, lg = lane >> 4;
    int cbi, yy, z;
    xcd_swz(cbi, yy, z);
    const int colw = cbi * 64 + w * 16;
    const int m0 = yy * 64;
    const int tile = yy >> 1, rh = yy & 1;
    const u16* xb = xp + (size_t)((z == 1) ? xo1 : xo0) + (size_t)tile * HTILE2 + rh * 512;
    const u16* hb = hp + (size_t)z * H2;
    const u16* hbt = hb + (size_t)tile * HTILE2 + rh * 512;
    const float* bih = bihB + z * 768;
    const float* bhh = bhhB + z * 768;
    constexpr int NCX = 4, NC = 8;

    const u16* bx0 = Wih + (size_t)z * wz + (size_t)(colw + lx) * 256 + lg * 8;
    const u16* bx1 = bx0 + 65536;
    const u16* bx2 = bx0 + 131072;
    const u16* bh0 = Whh + (size_t)z * wzh + (size_t)(colw + lx) * 256 + lg * 8;
    const u16* bh1 = bh0 + 65536;
    const u16* bh2 = bh0 + 131072;

    const f32x4 zf = {0.f, 0.f, 0.f, 0.f};
    f32x4 aR[4], aZ[4], aNX[4], aNH[4];
#pragma unroll
    for (int rf = 0; rf < 4; rf++) { aR[rf] = zf; aZ[rf] = zf; aNX[rf] = zf; aNH[rf] = zf; }

    auto chunksrc = [&](int c) -> const u16* {
        return (c < NCX) ? xb + (size_t)c * 8192 : hbt + (size_t)(c - NCX) * 8192;
    };
    stage64T(lds[0], chunksrc(0), w, lane);

    for (int c = 0; c < NC; c++) {
        __syncthreads();
        if (c + 1 < NC) stage64T(lds[(c + 1) & 1], chunksrc(c + 1), w, lane);
        const u16* lb = lds[c & 1];
        const bool isX = (c < NCX);
        const int cl = isX ? c : c - NCX;
#pragma unroll
        for (int s = 0; s < 2; s++) {
            short8 axh[4];
            const u16* ph = lb + (size_t)(s * 4 + lg) * 512 + lx * 8;
#pragma unroll
            for (int rf = 0; rf < 4; rf++) axh[rf] = ldf(ph + rf * 128);
            const int ko = cl * 64 + s * 32;
            if (isX) {
                {
                    short8 bh_ = ldf(bx0 + ko);
#pragma unroll
                    for (int rf = 0; rf < 4; rf++) MFMA(axh[rf], bh_, aR[rf]);
                }
                {
                    short8 bh_ = ldf(bx1 + ko);
#pragma unroll
                    for (int rf = 0; rf < 4; rf++) MFMA(axh[rf], bh_, aZ[rf]);
                }
                {
                    short8 bh_ = ldf(bx2 + ko);
#pragma unroll
                    for (int rf = 0; rf < 4; rf++) MFMA(axh[rf], bh_, aNX[rf]);
                }
            } else {
                {
                    short8 bh_ = ldf(bh0 + ko);
#pragma unroll
                    for (int rf = 0; rf < 4; rf++) MFMA(axh[rf], bh_, aR[rf]);
                }
                {
                    short8 bh_ = ldf(bh1 + ko);
#pragma unroll
                    for (int rf = 0; rf < 4; rf++) MFMA(axh[rf], bh_, aZ[rf]);
                }
                {
                    short8 bh_ = ldf(bh2 + ko);
#pragma unroll
                    for (int rf = 0; rf < 4; rf++) MFMA(axh[rf], bh_, aNH[rf]);
                }
            }
        }
    }
    const int col = colw + lx;
    const float b_r = bih[col] + bhh[col];
    const float b_z = bih[256 + col] + bhh[256 + col];
    const float bx_n = bih[512 + col], bh_n = bhh[512 + col];
    const size_t colpart = (size_t)(col >> 3) * 1024 + (col & 7);
    u16* ob = op + (size_t)z * H2;
#pragma unroll
    for (int rf = 0; rf < 4; rf++) {
#pragma unroll
        for (int rr = 0; rr < 4; rr++) {
            int row = m0 + rf * 16 + lg * 4 + rr;
            if (row < NROWS) {
                float rg = fsig_(aR[rf][rr] + b_r);
                float zg = fsig_(aZ[rf][rr] + b_z);
                float ng = ftanh_(aNX[rf][rr] + bx_n + rg * (aNH[rf][rr] + bh_n));
                size_t addr = (size_t)(row >> 7) * HTILE2 + (size_t)(row & 127) * 8 + colpart;
                float hold = bf2f(hb[addr]);
                float hnew = (1.f - zg) * ng + zg * hold;
                ob[addr] = f2bf(hnew);
            }
        }
    }
}

// ---------------------------------------------------------------------------
// TreeLSTM step: internals unchanged (paired h); tiledOut writes hi-only feats.
// ---------------------------------------------------------------------------
__global__ __launch_bounds__(256, 3) void k_tree_step_mf(
    const float* __restrict__ treenext, u16* __restrict__ xtnext,
    const u16* __restrict__ txp,
    const u16* __restrict__ Wx, const u16* __restrict__ Wh,
    const u16* __restrict__ Wfx, const u16* __restrict__ Wfh,
    const float* __restrict__ bioux, const float* __restrict__ biouh,
    const float* __restrict__ bfx, const float* __restrict__ bfh,
    const u16* __restrict__ hp, float* __restrict__ cst,
    u16* __restrict__ op, int tiledOut) {
    __shared__ u16 lds[2][8192];
    const int tid = threadIdx.x, lane = tid & 63, w = tid >> 6;
    const int lx = lane & 15, lg = lane >> 4;
    int cbi, yy, zz;
    xcd_swz(cbi, yy, zz);
    const int colw = cbi * 64 + w * 16;
    const int m0 = yy * 64;
    constexpr int NCX = 2, NC = 6;

    const u16* bx0 = Wx + (size_t)(colw + lx) * 128 + lg * 8;
    const u16* bx1 = bx0 + 32768;
    const u16* bx2 = bx0 + 65536;
    const u16* bxf = Wfx + (size_t)(colw + lx) * 128 + lg * 8;
    const u16* bh0 = Wh + (size_t)(colw + lx) * 256 + lg * 8;
    const u16* bh1 = bh0 + 65536;
    const u16* bh2 = bh0 + 131072;
    const u16* bhf = Wfh + (size_t)(colw + lx) * 256 + lg * 8;

    const f32x4 zf = {0.f, 0.f, 0.f, 0.f};
    f32x4 aI[4], aO[4], aU[4], aF[4];
#pragma unroll
    for (int rf = 0; rf < 4; rf++) { aI[rf] = zf; aO[rf] = zf; aU[rf] = zf; aF[rf] = zf; }

    stage_chunk64(lds[0], txp, 256, 0, m0, w, lane);

    if (xtnext) {
        int row = m0 + (tid >> 2);
        if (row < NROWS) {
            int c0 = cbi * 32 + (tid & 3) * 8;
            const float* p = treenext + (size_t)row * (LTREE * FDIM) + c0;
            float v[8];
            *(float4*)v = *(const float4*)p;
            *(float4*)(v + 4) = *(const float4*)(p + 4);
            emit8(xtnext + (size_t)row * 256 + (size_t)(c0 >> 3) * 16, v);
        }
    }

    for (int c = 0; c < NC; c++) {
        __syncthreads();
        if (c + 1 < NC) {
            u16* nb = lds[(c + 1) & 1];
            if (c + 1 < NCX) stage_chunk64(nb, txp, 256, (c + 1) * 128, m0, w, lane);
            else stage_chunk64(nb, hp, 512, (c + 1 - NCX) * 128, m0, w, lane);
        }
        const u16* lb = lds[c & 1];
        const bool isX = (c < NCX);
        const int cl = isX ? c : c - NCX;
#pragma unroll
        for (int s = 0; s < 2; s++) {
            short8 axh[4], axl[4];
            const u16* ph = lb + (size_t)(2 * (s * 4 + lg)) * 512 + lx * 8;
#pragma unroll
            for (int rf = 0; rf < 4; rf++) {
                axh[rf] = ldf(ph + rf * 128);
                axl[rf] = ldf(ph + 512 + rf * 128);
            }
            const int ko = cl * 64 + s * 32;
            const u16* p0 = isX ? bx0 : bh0;
            const u16* p1 = isX ? bx1 : bh1;
            const u16* p2 = isX ? bx2 : bh2;
            const u16* p3 = isX ? bxf : bhf;
            {
                short8 bh_ = ldf(p0 + ko);
#pragma unroll
                for (int rf = 0; rf < 4; rf++) MF2(axh[rf], axl[rf], bh_, aI[rf]);
            }
            {
                short8 bh_ = ldf(p1 + ko);
#pragma unroll
                for (int rf = 0; rf < 4; rf++) MF2(axh[rf], axl[rf], bh_, aO[rf]);
            }
            {
                short8 bh_ = ldf(p2 + ko);
#pragma unroll
                for (int rf = 0; rf < 4; rf++) MF2(axh[rf], axl[rf], bh_, aU[rf]);
            }
            {
                short8 bh_ = ldf(p3 + ko);
#pragma unroll
                for (int rf = 0; rf < 4; rf++) MF2(axh[rf], axl[rf], bh_, aF[rf]);
            }
        }
    }
    const int col = colw + lx;
    const float b_i = bioux[col] + biouh[col];
    const float b_o = bioux[256 + col] + biouh[256 + col];
    const float b_u = bioux[512 + col] + biouh[512 + col];
    const float b_f = bfx[col] + bfh[col];
    const int cpo = ((col >> 3) << 4) + (col & 7);
    const size_t colpart2 = (size_t)(col >> 3) * 1024 + (col & 7);
#pragma unroll
    for (int rf = 0; rf < 4; rf++) {
#pragma unroll
        for (int rr = 0; rr < 4; rr++) {
            int row = m0 + rf * 16 + lg * 4 + rr;
            if (row < NROWS) {
                float ig = fsig_(aI[rf][rr] + b_i);
                float og = fsig_(aO[rf][rr] + b_o);
                float ug = ftanh_(aU[rf][rr] + b_u);
                float fg = fsig_(aF[rf][rr] + b_f);
                size_t ci = (size_t)row * H + col;
                float cnew = ig * ug + fg * cst[ci];
                cst[ci] = cnew;
                float hnew = og * ftanh_(cnew);
                if (tiledOut) {
                    size_t addr = (size_t)(row >> 7) * HTILE2 + (size_t)(row & 127) * 8 + colpart2;
                    op[addr] = f2bf(hnew);
                } else {
                    u16 hh = f2bf(hnew);
                    size_t oi = (size_t)row * 512 + cpo;
                    op[oi] = hh;
                    op[oi + 8] = f2bf(hnew - bf2f(hh));
                }
            }
        }
    }
}

// fv_z += h_z @ Wc-slice^T ; hi-only h. grid (4,79,2).
__global__ __launch_bounds__(256) void k_fv_acc_mf(
    float* __restrict__ fvbase, const u16* __restrict__ hq,
    const u16* __restrict__ Wc, int off_f, int off_b) {
    const int tid = threadIdx.x, lane = tid & 63, w = tid >> 6;
    const int lx = lane & 15, kl8 = (lane >> 4);
    int cbi, yy, z;
    xcd_swz(cbi, yy, z);
    const int wr = w >> 1, wc = w & 1;
    const int cb = cbi * 64 + wc * 32;
    const int m0 = yy * 128 + wr * 64;
    int arow[4];
#pragma unroll
    for (int rf = 0; rf < 4; rf++) {
        int r = m0 + rf * 16 + lx;
        arow[rf] = (r < NROWS) ? r : NROWS - 1;
    }
    const f32x4 zf = {0.f, 0.f, 0.f, 0.f};
    f32x4 acc[4][2] = {{zf, zf}, {zf, zf}, {zf, zf}, {zf, zf}};
    const u16* aB = hq + (size_t)z * H2;
    const int off = z ? off_b : off_f;
    const u16* a[4];
#pragma unroll
    for (int rf = 0; rf < 4; rf++) {
        a[rf] = aB + (size_t)(arow[rf] >> 7) * HTILE2 + (size_t)(arow[rf] & 127) * 8 +
                (size_t)kl8 * 1024;
    }
    const u16* bp0 = Wc + (size_t)(cb + lx) * 2560 + off + kl8 * 8;
    const u16* bp1 = bp0 + 16 * 2560;
#pragma unroll
    for (int it = 0; it < 8; it++) {
        short8 axh[4];
#pragma unroll
        for (int rf = 0; rf < 4; rf++) {
            axh[rf] = ldf(a[rf]);
            a[rf] += 4096;
        }
        const int kb = it * 32;
        {
            short8 bh = ldf(bp0 + kb);
#pragma unroll
            for (int rf = 0; rf < 4; rf++) MFMA(axh[rf], bh, acc[rf][0]);
        }
        {
            short8 bh = ldf(bp1 + kb);
#pragma unroll
            for (int rf = 0; rf < 4; rf++) MFMA(axh[rf], bh, acc[rf][1]);
        }
    }
    float* fv = fvbase + (size_t)z * (NROWS * H);
#pragma unroll
    for (int rf = 0; rf < 4; rf++) {
#pragma unroll
        for (int cf = 0; cf < 2; cf++) {
            int col = cb + cf * 16 + lx;
#pragma unroll
            for (int rr = 0; rr < 4; rr++) {
                int row = m0 + rf * 16 + (lane >> 4) * 4 + rr;
                if (row < NROWS) fv[(size_t)row * H + col] += acc[rf][cf][rr];
            }
        }
    }
}

// out = A @ W^T; RF=2, 128-row blocks, grid (4,80). (GCN path, paired A)
__global__ __launch_bounds__(256) void k_gcn_gemm(
    float* __restrict__ out, const u16* __restrict__ ap_, const u16* __restrict__ W) {
    const int tid = threadIdx.x, lane = tid & 63, w = tid >> 6;
    const int lx = lane & 15, kl = (lane >> 4) * 8;
    int cbi, yy, zz;
    xcd_swz(cbi, yy, zz);
    const int cb = cbi * 64, m0 = yy * 128 + w * 32;
    int arow[2];
#pragma unroll
    for (int rf = 0; rf < 2; rf++) {
        int r = m0 + rf * 16 + lx;
        arow[rf] = (r < NROWS) ? r : NROWS - 1;
    }
    const f32x4 zf = {0.f, 0.f, 0.f, 0.f};
    f32x4 acc[2][4] = {{zf, zf, zf, zf}, {zf, zf, zf, zf}};
    const u16* a0 = ap_ + (size_t)arow[0] * 512 + kl * 2;
    const u16* a1 = ap_ + (size_t)arow[1] * 512 + kl * 2;
    const u16* bp0 = W + (size_t)(cb + lx) * 256 + kl;
    const u16* bp1 = bp0 + 16 * 256;
    const u16* bp2 = bp0 + 32 * 256;
    const u16* bp3 = bp0 + 48 * 256;
#pragma unroll
    for (int kb = 0; kb < 256; kb += 32) {
        short8 axh[2], axl[2];
        axh[0] = ldf(a0 + kb * 2); axl[0] = ldf(a0 + kb * 2 + 8);
        axh[1] = ldf(a1 + kb * 2); axl[1] = ldf(a1 + kb * 2 + 8);
        {
            short8 bh = ldf(bp0 + kb);
#pragma unroll
            for (int rf = 0; rf < 2; rf++) MF2(axh[rf], axl[rf], bh, acc[rf][0]);
        }
        {
            short8 bh = ldf(bp1 + kb);
#pragma unroll
            for (int rf = 0; rf < 2; rf++) MF2(axh[rf], axl[rf], bh, acc[rf][1]);
        }
        {
            short8 bh = ldf(bp2 + kb);
#pragma unroll
            for (int rf = 0; rf < 2; rf++) MF2(axh[rf], axl[rf], bh, acc[rf][2]);
        }
        {
            short8 bh = ldf(bp3 + kb);
#pragma unroll
            for (int rf = 0; rf < 2; rf++) MF2(axh[rf], axl[rf], bh, acc[rf][3]);
        }
    }
#pragma unroll
    for (int rf = 0; rf < 2; rf++) {
#pragma unroll
        for (int cf = 0; cf < 4; cf++) {
            int col = cb + cf * 16 + lx;
#pragma unroll
            for (int rr = 0; rr < 4; rr++) {
                int row = m0 + rf * 16 + (lane >> 4) * 4 + rr;
                if (row < NROWS) out[(size_t)row * H + col] = acc[rf][cf][rr];
            }
        }
    }
}

// ---------------------------- GCN small kernels -----------------------------
__global__ void k_fv_init(float* fv, const float* __restrict__ b) {
    int idx = blockIdx.x * 256 + threadIdx.x;
    if (idx < NROWS * H) fv[idx] = b[idx & (H - 1)];
}
__global__ void k_cnt(int* __restrict__ cnt, const int* __restrict__ dst) {
    int i = blockIdx.x * 256 + threadIdx.x;
    if (i < NE) atomicAdd(&cnt[dst[i]], 1);
}
__global__ void k_scan(const int* __restrict__ cnt, int* __restrict__ rowptr) {
    __shared__ int part[256];
    int tid = threadIdx.x;
    int st = tid * 40, en = (st + 40 > NROWS) ? NROWS : st + 40;
    int s = 0;
    for (int i = st; i < en; i++) s += cnt[i];
    part[tid] = s;
    __syncthreads();
    if (tid == 0) {
        int run = 0;
        for (int i = 0; i < 256; i++) { int t = part[i]; part[i] = run; run += t; }
        rowptr[NROWS] = run;
    }
    __syncthreads();
    int run = part[tid];
    for (int i = st; i < en; i++) { rowptr[i] = run; run += cnt[i]; }
}
__global__ void k_dinv(float* __restrict__ dinv, const int* __restrict__ cnt) {
    int i = blockIdx.x * 256 + threadIdx.x;
    if (i < NROWS) dinv[i] = rsqrtf(1.0f + (float)cnt[i]);
}
__global__ void k_fill(int* __restrict__ csr, int* __restrict__ cursor,
                       const int* __restrict__ rowptr, const int* __restrict__ ei) {
    int e = blockIdx.x * 256 + threadIdx.x;
    if (e < NE) {
        int d = ei[NE + e];
        int p = atomicAdd(&cursor[d], 1);
        csr[rowptr[d] + p] = ei[e];
    }
}
__global__ __launch_bounds__(256) void k_gather(
    float* __restrict__ out, u16* __restrict__ xcp,
    const float* __restrict__ xw, const float* __restrict__ dinv,
    const int* __restrict__ rowptr, const int* __restrict__ csr, const float* __restrict__ b) {
    int node = blockIdx.x * 4 + (threadIdx.x >> 6);
    if (node >= NROWS) return;
    int lane = threadIdx.x & 63;
    float dn = dinv[node];
    float4 acc = *(const float4*)(xw + (size_t)node * H + lane * 4);
    float dn2 = dn * dn;
    acc.x *= dn2; acc.y *= dn2; acc.z *= dn2; acc.w *= dn2;
    int e0 = rowptr[node], e1 = rowptr[node + 1];
    for (int i = e0; i < e1; i++) {
        int s = csr[i];
        float wgt = dn * dinv[s];
        const float4 v = *(const float4*)(xw + (size_t)s * H + lane * 4);
        acc.x += v.x * wgt; acc.y += v.y * wgt; acc.z += v.z * wgt; acc.w += v.w * wgt;
    }
    const float4 bv = *(const float4*)(b + lane * 4);
    float o[4];
    o[0] = fmaxf(acc.x + bv.x, 0.f);
    o[1] = fmaxf(acc.y + bv.y, 0.f);
    o[2] = fmaxf(acc.z + bv.z, 0.f);
    o[3] = fmaxf(acc.w + bv.w, 0.f);
    *(float4*)(out + (size_t)node * H + lane * 4) = *(const float4*)o;
    u16 hs[4], ls[4];
#pragma unroll
    for (int j = 0; j < 4; j++) {
        hs[j] = f2bf(o[j]);
        ls[j] = f2bf(o[j] - bf2f(hs[j]));
    }
    size_t bidx = (size_t)node * 512 + (size_t)(lane >> 1) * 16 + (lane & 1) * 4;
    *(short4*)(xcp + bidx) = *(const short4*)hs;
    *(short4*)(xcp + bidx + 8) = *(const short4*)ls;
}
__global__ void k_colmax(float* __restrict__ out, const float* __restrict__ x) {
    int j = threadIdx.x;
    float m = 0.0f;
    for (int r = blockIdx.x; r < NROWS; r += gridDim.x)
        m = fmaxf(m, x[(size_t)r * H + j]);
    atomicMax((int*)&out[j], __float_as_int(m));
}

// ---------------------------------------------------------------------------
extern "C" void kernel_launch(void* const* d_in, const int* in_sizes, int n_in,
                              void* d_out, int out_size, void* d_ws, size_t ws_size,
                              hipStream_t stream) {
    const float* tree = (const float*)d_in[0];
    const float* s2 = (const float*)d_in[1];
    const float* s3 = (const float*)d_in[2];
    const float* s4 = (const float*)d_in[3];
    const float* s5 = (const float*)d_in[4];
    const int* edge = (const int*)d_in[5];
    const float* tl_Wioux = (const float*)d_in[6];
    const float* tl_bioux = (const float*)d_in[7];
    const float* tl_Wiouh = (const float*)d_in[8];
    const float* tl_biouh = (const float*)d_in[9];
    const float* tl_Wfx = (const float*)d_in[10];
    const float* tl_bfx = (const float*)d_in[11];
    const float* tl_Wfh = (const float*)d_in[12];
    const float* tl_bfh = (const float*)d_in[13];
    const float* gru_Wih = (const float*)d_in[14];
    const float* gru_Whh = (const float*)d_in[15];
    const float* gru_bih = (const float*)d_in[16];
    const float* gru_bhh = (const float*)d_in[17];
    const float* comb_Wih = (const float*)d_in[18];
    const float* comb_Whh = (const float*)d_in[19];
    const float* comb_bih = (const float*)d_in[20];
    const float* comb_bhh = (const float*)d_in[21];
    const float* connect_W = (const float*)d_in[22];
    const float* connect_b = (const float*)d_in[23];
    const float* gcn_W = (const float*)d_in[24];
    const float* gcn_b = (const float*)d_in[25];

    char* base = (char*)d_ws;
    size_t off = 0;
    auto aus = [&](size_t nu16) { u16* p = (u16*)(base + off); off += nu16 * sizeof(u16); return p; };
    u16* tx = aus(98304);
    u16* th = aus(196608);
    u16* tfx = aus(32768);
    u16* tfh = aus(65536);
    u16* gWih = aus(393216);
    u16* gWhh = aus(786432);
    u16* cWih = aus(393216);
    u16* cWhh = aus(393216);
    u16* cn = aus(655360);
    u16* gc = aus(196608);
    u16* feats = aus((size_t)5 * H2);     // hi-only slices
    u16* hA = aus((size_t)4 * H2);
    u16* hB = aus((size_t)4 * H2);
    u16* SA = aus((size_t)4 * XZS);
    u16* SB = aus((size_t)4 * XZS);

    const dim3 blk(256);

    hipMemsetAsync(d_out, 0, H * sizeof(float), stream);

    auto SPW = [&](const float* s, u16* d, int n) {
        k_splitWb<<<(n / 8 + 255) / 256, blk, 0, stream>>>(s, d, n / 8);
    };
    SPW(tl_Wioux, tx, 98304);
    SPW(tl_Wiouh, th, 196608);
    SPW(tl_Wfx, tfx, 32768);
    SPW(tl_Wfh, tfh, 65536);
    SPW(gru_Wih, gWih, 393216);
    SPW(gru_Whh, gWhh, 786432);
    SPW(comb_Wih, cWih, 393216);
    SPW(comb_Whh, cWhh, 393216);
    SPW(connect_W, cn, 655360);
    SPW(gcn_W, gc, 196608);

    // -------- TreeLSTM (8 steps); internals as before --------
    float* cbuf = (float*)SA;
    u16* xtA = SA + 5120000;
    u16* xtB = SA + 7680000;
    hipMemsetAsync(hA, 0, (size_t)NROWS * 512 * 2, stream);
    hipMemsetAsync(cbuf, 0, (size_t)NROWS * H * 4, stream);
    k_split_xtree<<<640, blk, 0, stream>>>(tree, 0, xtA);
    {
        u16 *p = hA, *q = hB;
        for (int t = 0; t < LTREE; ++t) {
            bool last = (t == LTREE - 1);
            u16* xin = (t & 1) ? xtB : xtA;
            u16* xnx = last ? (u16*)0 : ((t & 1) ? xtA : xtB);
            k_tree_step_mf<<<dim3(4, 160, 1), blk, 0, stream>>>(
                tree + (t + 1) * FDIM, xnx,
                xin, tx, th, tfx, tfh, tl_bioux, tl_biouh, tl_bfx, tl_bfh,
                p, cbuf, last ? feats : q, last ? 1 : 0);
            u16* tmp = p; p = q; q = tmp;
        }
    }

    // -------- 4 GRUs (16 steps, z=4); h hi-only --------
    u16* xsA = SA;
    u16* xsB = SB;
    hipMemsetAsync(hA, 0, (size_t)4 * H2 * 2, stream);
    k_split_xseq<<<2560, blk, 0, stream>>>(s2, s3, s4, s5, 0, xsA);
    {
        u16 *p = hA, *q = hB;
        for (int t = 0; t < TSEQ; ++t) {
            bool last = (t == TSEQ - 1);
            u16* xin = (t & 1) ? xsB : xsA;
            u16* xnx = last ? (u16*)0 : ((t & 1) ? xsA : xsB);
            k_rnn_step<128><<<dim3(4, 80, 4), blk, 0, stream>>>(
                s2, s3, s4, s5, (t + 1) * FDIM, xnx,
                xin,
                gWih, 98304LL, gWhh, 196608LL, gru_bih, gru_bhh,
                p,
                last ? feats + H2 : q);
            u16* tmp = p; p = q; q = tmp;
        }
    }

    // -------- combine bi-GRU (5 steps, z=2) + fused connect --------
    float* fvF = (float*)SA;
    float* fvB = fvF + (size_t)NROWS * H;
    hipMemsetAsync(hA, 0, (size_t)2 * H2 * 2, stream);
    k_fv_init<<<(NROWS * H + 255) / 256, blk, 0, stream>>>(fvF, connect_b);
    hipMemsetAsync(fvB, 0, (size_t)NROWS * H * 4, stream);
    {
        u16 *p = hA, *q = hB;
        for (int s = 0; s < 5; ++s) {
            k_rnn_step64<<<dim3(4, 160, 2), blk, 0, stream>>>(
                feats, (long long)s * H2, (long long)(4 - s) * H2,
                cWih, 196608LL, cWhh, 196608LL, comb_bih, comb_bhh,
                p, q);
            k_fv_acc_mf<<<dim3(4, 79, 2), blk, 0, stream>>>(
                fvF, q, cn, s * 512, (4 - s) * 512 + 256);
            u16* tmp = p; p = q; q = tmp;
        }
    }

    // -------- CSR build (tail of hB; xc occupies first 5.12M u16) --------
    int* cnt = (int*)(hB + 6000000);
    int* rowptr = cnt + 10016;
    int* cursor = rowptr + 10016;
    int* csr = cursor + 10016;
    float* dinv = (float*)(csr + NE);
    hipMemsetAsync(cnt, 0, NROWS * sizeof(int), stream);
    hipMemsetAsync(cursor, 0, NROWS * sizeof(int), stream);
    k_cnt<<<(NE + 255) / 256, blk, 0, stream>>>(cnt, edge + NE);
    k_scan<<<1, blk, 0, stream>>>(cnt, rowptr);
    k_dinv<<<(NROWS + 255) / 256, blk, 0, stream>>>(dinv, cnt);
    k_fill<<<(NE + 255) / 256, blk, 0, stream>>>(csr, cursor, rowptr, edge);

    // -------- 4 conv applications (last two share W2,b2) --------
    {
        u16* xc = hB;
        float* xw = (float*)SB;
        float* cur = fvF;
        float* nxt = (float*)hA;
        k_splitNH2<<<1250, blk, 0, stream>>>(fvF, fvB, xc);
        for (int i = 0; i < 4; ++i) {
            int wi = (i < 3) ? i : 2;
            k_gcn_gemm<<<dim3(4, 80, 1), blk, 0, stream>>>(xw, xc, gc + (size_t)wi * 65536);
            k_gather<<<(NROWS + 3) / 4, blk, 0, stream>>>(nxt, xc, xw, dinv, rowptr, csr,
                                                          gcn_b + wi * H);
            float* tmp = cur; cur = nxt; nxt = tmp;
        }
        k_colmax<<<256, blk, 0, stream>>>((float*)d_out, cur);
    }
}

// Round 18
// 1831.788 us; speedup vs baseline: 1.2592x; 1.0549x over previous
//
#include <hip/hip_runtime.h>
#include <math.h>

#define H 256
#define NROWS 10000
#define LTREE 8
#define TSEQ 16
#define FDIM 128
#define NE 160000
#define HTILE2 32768     // 128 rows * 256 cols hi-only (u16)
#define XT2 16384        // 128 rows * 128 cols hi-only (u16)
#define H2 2621440       // 80 tiles * HTILE2
#define XZ2 1310720      // 80 tiles * XT2

typedef __attribute__((ext_vector_type(8))) short short8;
typedef __attribute__((ext_vector_type(4))) float f32x4;
typedef unsigned short u16;

__device__ __forceinline__ u16 f2bf(float x) {
    unsigned int u = __float_as_uint(x);
    return (u16)((u + 0x7fffu + ((u >> 16) & 1u)) >> 16);
}
__device__ __forceinline__ float bf2f(u16 s) { return __uint_as_float(((unsigned int)s) << 16); }
__device__ __forceinline__ short8 ldf(const u16* __restrict__ p) { return *(const short8*)(p); }
__device__ __forceinline__ float fexp_(float x) { return __expf(fminf(x, 80.f)); }
__device__ __forceinline__ float fsig_(float x) { return 1.f / (1.f + fexp_(-x)); }
__device__ __forceinline__ float ftanh_(float x) {
    float e = fexp_(fmaxf(2.f * x, -80.f));
    return (e - 1.f) / (e + 1.f);
}
#define MFMA(A, B, C) C = __builtin_amdgcn_mfma_f32_16x16x32_bf16(A, B, C, 0, 0, 0)

__device__ __forceinline__ void async16(u16* l, const u16* g) {
    __builtin_amdgcn_global_load_lds((__attribute__((address_space(1))) const void*)g,
                                     (__attribute__((address_space(3))) void*)l, 16, 0, 0);
}

// XCD-aware remap, bijective when nwg%8==0.
__device__ __forceinline__ void xcd_swz(int& cbi, int& yy, int& zz) {
    const int gx = gridDim.x, gy = gridDim.y;
    int nwg8 = (gx * gy * gridDim.z) >> 3;
    int bid = blockIdx.x + gx * (blockIdx.y + gy * blockIdx.z);
    int wgid = (bid & 7) * nwg8 + (bid >> 3);
    cbi = wgid % gx;
    int rem = wgid / gx;
    yy = rem % gy;
    zz = rem / gy;
}

// hi-only tiled offsets
__device__ __forceinline__ size_t xpo(int row, int g) {   // 128-col x tile
    return (size_t)(row >> 7) * XT2 + (size_t)g * 1024 + (size_t)(row & 127) * 8;
}

// Stage one 16KB chunk (pre-tiled source == LDS image), 128-row tiles.
__device__ __forceinline__ void stageT(u16* ldsbuf, const u16* __restrict__ chunkbase,
                                       int w, int lane) {
#pragma unroll
    for (int cc = 0; cc < 4; cc++) {
        int eb = (w * 4 + cc) * 64;
        async16(ldsbuf + (size_t)eb * 8, chunkbase + (size_t)(eb + lane) * 8);
    }
}
// Stage an 8KB half-tile chunk (64 rows of a 128-row tile).
__device__ __forceinline__ void stage64T(u16* ldsbuf, const u16* __restrict__ chunkbase,
                                         int w, int lane) {
#pragma unroll
    for (int cc = 0; cc < 2; cc++) {
        int p = w * 2 + cc;
        async16(ldsbuf + (size_t)p * 512, chunkbase + (size_t)p * 1024 + (size_t)lane * 8);
    }
}
// hi-only row-major 64-row chunk (tree kernel): 16 planes x 8 u16 cols.
__device__ __forceinline__ void stage_chunk64h(u16* ldsbuf, const u16* __restrict__ src,
                                               int stride_u16, int kb_u16, int m0,
                                               int w, int lane) {
#pragma unroll
    for (int c = 0; c < 4; c++) {
        int e_base = (w * 4 + c) * 64;
        int e = e_base + lane;
        int p = e >> 6, rs = e & 63;
        int row = m0 + rs;
        if (row > NROWS - 1) row = NROWS - 1;
        const u16* g = src + (size_t)row * stride_u16 + kb_u16 + p * 8;
        async16(ldsbuf + (size_t)e_base * 8, g);
    }
}

// ---------------- split helpers (hi-only) ----------------
__device__ __forceinline__ void emit8h(u16* __restrict__ dst, const float* v8) {
    short8 h;
#pragma unroll
    for (int j = 0; j < 8; j++) h[j] = (short)f2bf(v8[j]);
    *(short8*)dst = h;
}
__global__ void k_splitWb(const float* __restrict__ src, u16* __restrict__ dst, int ngroups) {
    int g = blockIdx.x * 256 + threadIdx.x;
    if (g < ngroups) {
        float v[8];
        *(float4*)v = *(const float4*)(src + (size_t)g * 8);
        *(float4*)(v + 4) = *(const float4*)(src + (size_t)g * 8 + 4);
        emit8h(dst + (size_t)g * 8, v);
    }
}
// t=0 seed for GRU x: tiled hi-only [4][XZ2]
__global__ void k_split_xseq(const float* __restrict__ s2, const float* __restrict__ s3,
                             const float* __restrict__ s4, const float* __restrict__ s5,
                             int t, u16* __restrict__ dst) {
    int bid = blockIdx.x;
    int xcd = bid & 7, chunk = bid >> 3;
    int z = xcd >> 1, half = xcd & 1;
    int g = chunk * 256 + threadIdx.x;
    int row = half * 5120 + (g >> 4);
    if (row >= NROWS) return;
    int gg = g & 15;
    const float* s = (z == 0) ? s2 : (z == 1) ? s3 : (z == 2) ? s4 : s5;
    const float* p = s + (size_t)row * (TSEQ * FDIM) + t * FDIM + gg * 8;
    float v[8];
    *(float4*)v = *(const float4*)p;
    *(float4*)(v + 4) = *(const float4*)(p + 4);
    emit8h(dst + (size_t)z * XZ2 + xpo(row, gg), v);
}
// tree x seed: row-major hi-only [NROWS][128]
__global__ void k_split_xtree(const float* __restrict__ tree, int t, u16* __restrict__ dst) {
    int bid = blockIdx.x;
    int xcd = bid & 7, chunk = bid >> 3;
    int g = chunk * 256 + threadIdx.x;
    int row = xcd * 1280 + (g >> 4);
    if (row >= NROWS) return;
    int col = (g & 15) * 8;
    const float* p = tree + (size_t)row * (LTREE * FDIM) + t * FDIM + col;
    float v[8];
    *(float4*)v = *(const float4*)p;
    *(float4*)(v + 4) = *(const float4*)(p + 4);
    emit8h(dst + (size_t)row * 128 + col, v);
}
// (fvF + fvB) f32 -> hi-only [NROWS][256] (GCN conv input)
__global__ void k_splitNH2(const float* __restrict__ a, const float* __restrict__ b,
                           u16* __restrict__ dst) {
    int g = blockIdx.x * 256 + threadIdx.x;
    if (g < NROWS * 32) {
        float v[8];
        float4 x0 = *(const float4*)(a + (size_t)g * 8);
        float4 x1 = *(const float4*)(a + (size_t)g * 8 + 4);
        float4 y0 = *(const float4*)(b + (size_t)g * 8);
        float4 y1 = *(const float4*)(b + (size_t)g * 8 + 4);
        v[0] = x0.x + y0.x; v[1] = x0.y + y0.y; v[2] = x0.z + y0.z; v[3] = x0.w + y0.w;
        v[4] = x1.x + y1.x; v[5] = x1.y + y1.y; v[6] = x1.z + y1.z; v[7] = x1.w + y1.w;
        emit8h(dst + (size_t)g * 8, v);
    }
}

// ---------------------------------------------------------------------------
// GRU step: 128-row A-tile, RF=8, all operands hi-only bf16.
// NC = 2 x-chunks + 4 h-chunks (64 k each, 16KB). grid (4,80,4).
// ---------------------------------------------------------------------------
__global__ __launch_bounds__(256, 2) void k_rnn_step(
    const float* __restrict__ q0, const float* __restrict__ q1,
    const float* __restrict__ q2, const float* __restrict__ q3,
    int qoff4, u16* __restrict__ xnext,
    const u16* __restrict__ xp,
    const u16* __restrict__ Wih, long long wz,
    const u16* __restrict__ Whh, long long wzh,
    const float* __restrict__ bihB, const float* __restrict__ bhhB,
    const u16* __restrict__ hp,
    u16* __restrict__ op) {
    __shared__ u16 lds[2][8192];
    const int tid = threadIdx.x, lane = tid & 63, w = tid >> 6;
    const int lx = lane & 15, lg = lane >> 4;
    int cbi, yy, z;
    xcd_swz(cbi, yy, z);
    const int colw = cbi * 64 + w * 16;
    const int m0 = yy * 128;
    const u16* xb = xp + (size_t)z * XZ2 + (size_t)yy * XT2;
    const u16* hb = hp + (size_t)z * H2;
    const u16* hbt = hb + (size_t)yy * HTILE2;
    const float* bih = bihB + z * 768;
    const float* bhh = bhhB + z * 768;
    constexpr int NCX = 2, NC = 6;

    const u16* bx0 = Wih + (size_t)z * wz + (size_t)(colw + lx) * 128 + lg * 8;
    const u16* bx1 = bx0 + 32768;
    const u16* bx2 = bx0 + 65536;
    const u16* bh0 = Whh + (size_t)z * wzh + (size_t)(colw + lx) * 256 + lg * 8;
    const u16* bh1 = bh0 + 65536;
    const u16* bh2 = bh0 + 131072;

    const f32x4 zf = {0.f, 0.f, 0.f, 0.f};
    f32x4 aR[8], aZ[8], aNX[8], aNH[8];
#pragma unroll
    for (int rf = 0; rf < 8; rf++) { aR[rf] = zf; aZ[rf] = zf; aNX[rf] = zf; aNH[rf] = zf; }

    auto chunksrc = [&](int c) -> const u16* {
        return (c < NCX) ? xb + (size_t)c * 8192 : hbt + (size_t)(c - NCX) * 8192;
    };
    stageT(lds[0], chunksrc(0), w, lane);

    // fused next-timestep x split (hi-only tiled stores)
    if (xnext) {
        const float* qs = (z == 0) ? q0 : (z == 1) ? q1 : (z == 2) ? q2 : q3;
        int row = m0 + (tid >> 1);
        if (row < NROWS) {
            int g0 = (cbi * 32 + (tid & 1) * 16) >> 3;
            const float* p = qs + (size_t)row * (TSEQ * FDIM) + qoff4 + g0 * 8;
            u16* d = xnext + (size_t)z * XZ2;
            float v[8];
            *(float4*)v = *(const float4*)p;
            *(float4*)(v + 4) = *(const float4*)(p + 4);
            emit8h(d + xpo(row, g0), v);
            *(float4*)v = *(const float4*)(p + 8);
            *(float4*)(v + 4) = *(const float4*)(p + 12);
            emit8h(d + xpo(row, g0 + 1), v);
        }
    }

    for (int c = 0; c < NC; c++) {
        __syncthreads();  // drains DMA for lds[c&1]
        if (c + 1 < NC) stageT(lds[(c + 1) & 1], chunksrc(c + 1), w, lane);
        const u16* lb = lds[c & 1];
        const bool isX = (c < NCX);
        const int cl = isX ? c : c - NCX;
#pragma unroll
        for (int s = 0; s < 2; s++) {
            short8 axh[8];
            const u16* ph = lb + (size_t)(s * 4 + lg) * 1024 + lx * 8;
#pragma unroll
            for (int rf = 0; rf < 8; rf++) axh[rf] = ldf(ph + rf * 128);
            const int ko = cl * 64 + s * 32;
            if (isX) {
                {
                    short8 bh_ = ldf(bx0 + ko);
#pragma unroll
                    for (int rf = 0; rf < 8; rf++) MFMA(axh[rf], bh_, aR[rf]);
                }
                {
                    short8 bh_ = ldf(bx1 + ko);
#pragma unroll
                    for (int rf = 0; rf < 8; rf++) MFMA(axh[rf], bh_, aZ[rf]);
                }
                {
                    short8 bh_ = ldf(bx2 + ko);
#pragma unroll
                    for (int rf = 0; rf < 8; rf++) MFMA(axh[rf], bh_, aNX[rf]);
                }
            } else {
                {
                    short8 bh_ = ldf(bh0 + ko);
#pragma unroll
                    for (int rf = 0; rf < 8; rf++) MFMA(axh[rf], bh_, aR[rf]);
                }
                {
                    short8 bh_ = ldf(bh1 + ko);
#pragma unroll
                    for (int rf = 0; rf < 8; rf++) MFMA(axh[rf], bh_, aZ[rf]);
                }
                {
                    short8 bh_ = ldf(bh2 + ko);
#pragma unroll
                    for (int rf = 0; rf < 8; rf++) MFMA(axh[rf], bh_, aNH[rf]);
                }
            }
        }
    }
    const int col = colw + lx;
    const float b_r = bih[col] + bhh[col];
    const float b_z = bih[256 + col] + bhh[256 + col];
    const float bx_n = bih[512 + col], bh_n = bhh[512 + col];
    const size_t colpart = (size_t)(col >> 3) * 1024 + (col & 7);
    u16* ob = op + (size_t)z * H2;
#pragma unroll
    for (int rf = 0; rf < 8; rf++) {
#pragma unroll
        for (int rr = 0; rr < 4; rr++) {
            int row = m0 + rf * 16 + lg * 4 + rr;
            if (row < NROWS) {
                float rg = fsig_(aR[rf][rr] + b_r);
                float zg = fsig_(aZ[rf][rr] + b_z);
                float ng = ftanh_(aNX[rf][rr] + bx_n + rg * (aNH[rf][rr] + bh_n));
                size_t addr = (size_t)(row >> 7) * HTILE2 + (size_t)(row & 127) * 8 + colpart;
                float hold = bf2f(hb[addr]);
                float hnew = (1.f - zg) * ng + zg * hold;
                ob[addr] = f2bf(hnew);
            }
        }
    }
}

// ---------------------------------------------------------------------------
// comb GRU step: 64-row tile, RF=4, 3 waves/SIMD; hi-only. grid (4,160,2).
// ---------------------------------------------------------------------------
__global__ __launch_bounds__(256, 3) void k_rnn_step64(
    const u16* __restrict__ xp, long long xo0, long long xo1,
    const u16* __restrict__ Wih, long long wz,
    const u16* __restrict__ Whh, long long wzh,
    const float* __restrict__ bihB, const float* __restrict__ bhhB,
    const u16* __restrict__ hp,
    u16* __restrict__ op) {
    __shared__ u16 lds[2][4096];
    const int tid = threadIdx.x, lane = tid & 63, w = tid >> 6;
    const int lx = lane & 15, lg = lane >> 4;
    int cbi, yy, z;
    xcd_swz(cbi, yy, z);
    const int colw = cbi * 64 + w * 16;
    const int m0 = yy * 64;
    const int tile = yy >> 1, rh = yy & 1;
    const u16* xb = xp + (size_t)((z == 1) ? xo1 : xo0) + (size_t)tile * HTILE2 + rh * 512;
    const u16* hb = hp + (size_t)z * H2;
    const u16* hbt = hb + (size_t)tile * HTILE2 + rh * 512;
    const float* bih = bihB + z * 768;
    const float* bhh = bhhB + z * 768;
    constexpr int NCX = 4, NC = 8;

    const u16* bx0 = Wih + (size_t)z * wz + (size_t)(colw + lx) * 256 + lg * 8;
    const u16* bx1 = bx0 + 65536;
    const u16* bx2 = bx0 + 131072;
    const u16* bh0 = Whh + (size_t)z * wzh + (size_t)(colw + lx) * 256 + lg * 8;
    const u16* bh1 = bh0 + 65536;
    const u16* bh2 = bh0 + 131072;

    const f32x4 zf = {0.f, 0.f, 0.f, 0.f};
    f32x4 aR[4], aZ[4], aNX[4], aNH[4];
#pragma unroll
    for (int rf = 0; rf < 4; rf++) { aR[rf] = zf; aZ[rf] = zf; aNX[rf] = zf; aNH[rf] = zf; }

    auto chunksrc = [&](int c) -> const u16* {
        return (c < NCX) ? xb + (size_t)c * 8192 : hbt + (size_t)(c - NCX) * 8192;
    };
    stage64T(lds[0], chunksrc(0), w, lane);

    for (int c = 0; c < NC; c++) {
        __syncthreads();
        if (c + 1 < NC) stage64T(lds[(c + 1) & 1], chunksrc(c + 1), w, lane);
        const u16* lb = lds[c & 1];
        const bool isX = (c < NCX);
        const int cl = isX ? c : c - NCX;
#pragma unroll
        for (int s = 0; s < 2; s++) {
            short8 axh[4];
            const u16* ph = lb + (size_t)(s * 4 + lg) * 512 + lx * 8;
#pragma unroll
            for (int rf = 0; rf < 4; rf++) axh[rf] = ldf(ph + rf * 128);
            const int ko = cl * 64 + s * 32;
            if (isX) {
                {
                    short8 bh_ = ldf(bx0 + ko);
#pragma unroll
                    for (int rf = 0; rf < 4; rf++) MFMA(axh[rf], bh_, aR[rf]);
                }
                {
                    short8 bh_ = ldf(bx1 + ko);
#pragma unroll
                    for (int rf = 0; rf < 4; rf++) MFMA(axh[rf], bh_, aZ[rf]);
                }
                {
                    short8 bh_ = ldf(bx2 + ko);
#pragma unroll
                    for (int rf = 0; rf < 4; rf++) MFMA(axh[rf], bh_, aNX[rf]);
                }
            } else {
                {
                    short8 bh_ = ldf(bh0 + ko);
#pragma unroll
                    for (int rf = 0; rf < 4; rf++) MFMA(axh[rf], bh_, aR[rf]);
                }
                {
                    short8 bh_ = ldf(bh1 + ko);
#pragma unroll
                    for (int rf = 0; rf < 4; rf++) MFMA(axh[rf], bh_, aZ[rf]);
                }
                {
                    short8 bh_ = ldf(bh2 + ko);
#pragma unroll
                    for (int rf = 0; rf < 4; rf++) MFMA(axh[rf], bh_, aNH[rf]);
                }
            }
        }
    }
    const int col = colw + lx;
    const float b_r = bih[col] + bhh[col];
    const float b_z = bih[256 + col] + bhh[256 + col];
    const float bx_n = bih[512 + col], bh_n = bhh[512 + col];
    const size_t colpart = (size_t)(col >> 3) * 1024 + (col & 7);
    u16* ob = op + (size_t)z * H2;
#pragma unroll
    for (int rf = 0; rf < 4; rf++) {
#pragma unroll
        for (int rr = 0; rr < 4; rr++) {
            int row = m0 + rf * 16 + lg * 4 + rr;
            if (row < NROWS) {
                float rg = fsig_(aR[rf][rr] + b_r);
                float zg = fsig_(aZ[rf][rr] + b_z);
                float ng = ftanh_(aNX[rf][rr] + bx_n + rg * (aNH[rf][rr] + bh_n));
                size_t addr = (size_t)(row >> 7) * HTILE2 + (size_t)(row & 127) * 8 + colpart;
                float hold = bf2f(hb[addr]);
                float hnew = (1.f - zg) * ng + zg * hold;
                ob[addr] = f2bf(hnew);
            }
        }
    }
}

// ---------------------------------------------------------------------------
// TreeLSTM step: 64-row tile, RF=4, hi-only x [row][128] and h [row][256].
// NC = 1 x-chunk + 2 h-chunks (128 k each). grid (4, 160, 1).
// ---------------------------------------------------------------------------
__global__ __launch_bounds__(256, 3) void k_tree_step_mf(
    const float* __restrict__ treenext, u16* __restrict__ xtnext,
    const u16* __restrict__ txp,
    const u16* __restrict__ Wx, const u16* __restrict__ Wh,
    const u16* __restrict__ Wfx, const u16* __restrict__ Wfh,
    const float* __restrict__ bioux, const float* __restrict__ biouh,
    const float* __restrict__ bfx, const float* __restrict__ bfh,
    const u16* __restrict__ hp, float* __restrict__ cst,
    u16* __restrict__ op, int tiledOut) {
    __shared__ u16 lds[2][8192];
    const int tid = threadIdx.x, lane = tid & 63, w = tid >> 6;
    const int lx = lane & 15, lg = lane >> 4;
    int cbi, yy, zz;
    xcd_swz(cbi, yy, zz);
    const int colw = cbi * 64 + w * 16;
    const int m0 = yy * 64;
    constexpr int NC = 3;

    const u16* bx0 = Wx + (size_t)(colw + lx) * 128 + lg * 8;
    const u16* bx1 = bx0 + 32768;
    const u16* bx2 = bx0 + 65536;
    const u16* bxf = Wfx + (size_t)(colw + lx) * 128 + lg * 8;
    const u16* bh0 = Wh + (size_t)(colw + lx) * 256 + lg * 8;
    const u16* bh1 = bh0 + 65536;
    const u16* bh2 = bh0 + 131072;
    const u16* bhf = Wfh + (size_t)(colw + lx) * 256 + lg * 8;

    const f32x4 zf = {0.f, 0.f, 0.f, 0.f};
    f32x4 aI[4], aO[4], aU[4], aF[4];
#pragma unroll
    for (int rf = 0; rf < 4; rf++) { aI[rf] = zf; aO[rf] = zf; aU[rf] = zf; aF[rf] = zf; }

    stage_chunk64h(lds[0], txp, 128, 0, m0, w, lane);

    if (xtnext) {
        int row = m0 + (tid >> 2);
        if (row < NROWS) {
            int c0 = cbi * 32 + (tid & 3) * 8;
            const float* p = treenext + (size_t)row * (LTREE * FDIM) + c0;
            float v[8];
            *(float4*)v = *(const float4*)p;
            *(float4*)(v + 4) = *(const float4*)(p + 4);
            emit8h(xtnext + (size_t)row * 128 + c0, v);
        }
    }

    for (int c = 0; c < NC; c++) {
        __syncthreads();
        if (c + 1 < NC) stage_chunk64h(lds[(c + 1) & 1], hp, 256, c * 128, m0, w, lane);
        const u16* lb = lds[c & 1];
        const bool isX = (c == 0);
#pragma unroll
        for (int s = 0; s < 4; s++) {
            short8 axh[4];
            const u16* ph = lb + (size_t)(s * 4 + lg) * 512 + lx * 8;
#pragma unroll
            for (int rf = 0; rf < 4; rf++) axh[rf] = ldf(ph + rf * 128);
            const int ko = isX ? s * 32 : (c - 1) * 128 + s * 32;
            const u16* p0 = isX ? bx0 : bh0;
            const u16* p1 = isX ? bx1 : bh1;
            const u16* p2 = isX ? bx2 : bh2;
            const u16* p3 = isX ? bxf : bhf;
            {
                short8 bh_ = ldf(p0 + ko);
#pragma unroll
                for (int rf = 0; rf < 4; rf++) MFMA(axh[rf], bh_, aI[rf]);
            }
            {
                short8 bh_ = ldf(p1 + ko);
#pragma unroll
                for (int rf = 0; rf < 4; rf++) MFMA(axh[rf], bh_, aO[rf]);
            }
            {
                short8 bh_ = ldf(p2 + ko);
#pragma unroll
                for (int rf = 0; rf < 4; rf++) MFMA(axh[rf], bh_, aU[rf]);
            }
            {
                short8 bh_ = ldf(p3 + ko);
#pragma unroll
                for (int rf = 0; rf < 4; rf++) MFMA(axh[rf], bh_, aF[rf]);
            }
        }
    }
    const int col = colw + lx;
    const float b_i = bioux[col] + biouh[col];
    const float b_o = bioux[256 + col] + biouh[256 + col];
    const float b_u = bioux[512 + col] + biouh[512 + col];
    const float b_f = bfx[col] + bfh[col];
    const size_t colpart2 = (size_t)(col >> 3) * 1024 + (col & 7);
#pragma unroll
    for (int rf = 0; rf < 4; rf++) {
#pragma unroll
        for (int rr = 0; rr < 4; rr++) {
            int row = m0 + rf * 16 + lg * 4 + rr;
            if (row < NROWS) {
                float ig = fsig_(aI[rf][rr] + b_i);
                float og = fsig_(aO[rf][rr] + b_o);
                float ug = ftanh_(aU[rf][rr] + b_u);
                float fg = fsig_(aF[rf][rr] + b_f);
                size_t ci = (size_t)row * H + col;
                float cnew = ig * ug + fg * cst[ci];
                cst[ci] = cnew;
                float hnew = og * ftanh_(cnew);
                if (tiledOut) {
                    size_t addr = (size_t)(row >> 7) * HTILE2 + (size_t)(row & 127) * 8 + colpart2;
                    op[addr] = f2bf(hnew);
                } else {
                    op[(size_t)row * 256 + col] = f2bf(hnew);
                }
            }
        }
    }
}

// fv_z += h_z @ Wc-slice^T ; hi-only h. grid (4,79,2).
__global__ __launch_bounds__(256) void k_fv_acc_mf(
    float* __restrict__ fvbase, const u16* __restrict__ hq,
    const u16* __restrict__ Wc, int off_f, int off_b) {
    const int tid = threadIdx.x, lane = tid & 63, w = tid >> 6;
    const int lx = lane & 15, kl8 = (lane >> 4);
    int cbi, yy, z;
    xcd_swz(cbi, yy, z);
    const int wr = w >> 1, wc = w & 1;
    const int cb = cbi * 64 + wc * 32;
    const int m0 = yy * 128 + wr * 64;
    int arow[4];
#pragma unroll
    for (int rf = 0; rf < 4; rf++) {
        int r = m0 + rf * 16 + lx;
        arow[rf] = (r < NROWS) ? r : NROWS - 1;
    }
    const f32x4 zf = {0.f, 0.f, 0.f, 0.f};
    f32x4 acc[4][2] = {{zf, zf}, {zf, zf}, {zf, zf}, {zf, zf}};
    const u16* aB = hq + (size_t)z * H2;
    const int off = z ? off_b : off_f;
    const u16* a[4];
#pragma unroll
    for (int rf = 0; rf < 4; rf++) {
        a[rf] = aB + (size_t)(arow[rf] >> 7) * HTILE2 + (size_t)(arow[rf] & 127) * 8 +
                (size_t)kl8 * 1024;
    }
    const u16* bp0 = Wc + (size_t)(cb + lx) * 2560 + off + kl8 * 8;
    const u16* bp1 = bp0 + 16 * 2560;
#pragma unroll
    for (int it = 0; it < 8; it++) {
        short8 axh[4];
#pragma unroll
        for (int rf = 0; rf < 4; rf++) {
            axh[rf] = ldf(a[rf]);
            a[rf] += 4096;
        }
        const int kb = it * 32;
        {
            short8 bh = ldf(bp0 + kb);
#pragma unroll
            for (int rf = 0; rf < 4; rf++) MFMA(axh[rf], bh, acc[rf][0]);
        }
        {
            short8 bh = ldf(bp1 + kb);
#pragma unroll
            for (int rf = 0; rf < 4; rf++) MFMA(axh[rf], bh, acc[rf][1]);
        }
    }
    float* fv = fvbase + (size_t)z * (NROWS * H);
#pragma unroll
    for (int rf = 0; rf < 4; rf++) {
#pragma unroll
        for (int cf = 0; cf < 2; cf++) {
            int col = cb + cf * 16 + lx;
#pragma unroll
            for (int rr = 0; rr < 4; rr++) {
                int row = m0 + rf * 16 + (lane >> 4) * 4 + rr;
                if (row < NROWS) fv[(size_t)row * H + col] += acc[rf][cf][rr];
            }
        }
    }
}

// out = A @ W^T; A hi-only [row][256], W bf16. RF=2, grid (4,80).
__global__ __launch_bounds__(256) void k_gcn_gemm(
    float* __restrict__ out, const u16* __restrict__ ap_, const u16* __restrict__ W) {
    const int tid = threadIdx.x, lane = tid & 63, w = tid >> 6;
    const int lx = lane & 15, kl = (lane >> 4) * 8;
    int cbi, yy, zz;
    xcd_swz(cbi, yy, zz);
    const int cb = cbi * 64, m0 = yy * 128 + w * 32;
    int arow[2];
#pragma unroll
    for (int rf = 0; rf < 2; rf++) {
        int r = m0 + rf * 16 + lx;
        arow[rf] = (r < NROWS) ? r : NROWS - 1;
    }
    const f32x4 zf = {0.f, 0.f, 0.f, 0.f};
    f32x4 acc[2][4] = {{zf, zf, zf, zf}, {zf, zf, zf, zf}};
    const u16* a0 = ap_ + (size_t)arow[0] * 256 + kl;
    const u16* a1 = ap_ + (size_t)arow[1] * 256 + kl;
    const u16* bp0 = W + (size_t)(cb + lx) * 256 + kl;
    const u16* bp1 = bp0 + 16 * 256;
    const u16* bp2 = bp0 + 32 * 256;
    const u16* bp3 = bp0 + 48 * 256;
#pragma unroll
    for (int kb = 0; kb < 256; kb += 32) {
        short8 axh[2];
        axh[0] = ldf(a0 + kb);
        axh[1] = ldf(a1 + kb);
        {
            short8 bh = ldf(bp0 + kb);
#pragma unroll
            for (int rf = 0; rf < 2; rf++) MFMA(axh[rf], bh, acc[rf][0]);
        }
        {
            short8 bh = ldf(bp1 + kb);
#pragma unroll
            for (int rf = 0; rf < 2; rf++) MFMA(axh[rf], bh, acc[rf][1]);
        }
        {
            short8 bh = ldf(bp2 + kb);
#pragma unroll
            for (int rf = 0; rf < 2; rf++) MFMA(axh[rf], bh, acc[rf][2]);
        }
        {
            short8 bh = ldf(bp3 + kb);
#pragma unroll
            for (int rf = 0; rf < 2; rf++) MFMA(axh[rf], bh, acc[rf][3]);
        }
    }
#pragma unroll
    for (int rf = 0; rf < 2; rf++) {
#pragma unroll
        for (int cf = 0; cf < 4; cf++) {
            int col = cb + cf * 16 + lx;
#pragma unroll
            for (int rr = 0; rr < 4; rr++) {
                int row = m0 + rf * 16 + (lane >> 4) * 4 + rr;
                if (row < NROWS) out[(size_t)row * H + col] = acc[rf][cf][rr];
            }
        }
    }
}

// ---------------------------- GCN small kernels -----------------------------
__global__ void k_fv_init(float* fv, const float* __restrict__ b) {
    int idx = blockIdx.x * 256 + threadIdx.x;
    if (idx < NROWS * H) fv[idx] = b[idx & (H - 1)];
}
__global__ void k_cnt(int* __restrict__ cnt, const int* __restrict__ dst) {
    int i = blockIdx.x * 256 + threadIdx.x;
    if (i < NE) atomicAdd(&cnt[dst[i]], 1);
}
__global__ void k_scan(const int* __restrict__ cnt, int* __restrict__ rowptr) {
    __shared__ int part[256];
    int tid = threadIdx.x;
    int st = tid * 40, en = (st + 40 > NROWS) ? NROWS : st + 40;
    int s = 0;
    for (int i = st; i < en; i++) s += cnt[i];
    part[tid] = s;
    __syncthreads();
    if (tid == 0) {
        int run = 0;
        for (int i = 0; i < 256; i++) { int t = part[i]; part[i] = run; run += t; }
        rowptr[NROWS] = run;
    }
    __syncthreads();
    int run = part[tid];
    for (int i = st; i < en; i++) { rowptr[i] = run; run += cnt[i]; }
}
__global__ void k_dinv(float* __restrict__ dinv, const int* __restrict__ cnt) {
    int i = blockIdx.x * 256 + threadIdx.x;
    if (i < NROWS) dinv[i] = rsqrtf(1.0f + (float)cnt[i]);
}
__global__ void k_fill(int* __restrict__ csr, int* __restrict__ cursor,
                       const int* __restrict__ rowptr, const int* __restrict__ ei) {
    int e = blockIdx.x * 256 + threadIdx.x;
    if (e < NE) {
        int d = ei[NE + e];
        int p = atomicAdd(&cursor[d], 1);
        csr[rowptr[d] + p] = ei[e];
    }
}
__global__ __launch_bounds__(256) void k_gather(
    float* __restrict__ out, u16* __restrict__ xcp,
    const float* __restrict__ xw, const float* __restrict__ dinv,
    const int* __restrict__ rowptr, const int* __restrict__ csr, const float* __restrict__ b) {
    int node = blockIdx.x * 4 + (threadIdx.x >> 6);
    if (node >= NROWS) return;
    int lane = threadIdx.x & 63;
    float dn = dinv[node];
    float4 acc = *(const float4*)(xw + (size_t)node * H + lane * 4);
    float dn2 = dn * dn;
    acc.x *= dn2; acc.y *= dn2; acc.z *= dn2; acc.w *= dn2;
    int e0 = rowptr[node], e1 = rowptr[node + 1];
    for (int i = e0; i < e1; i++) {
        int s = csr[i];
        float wgt = dn * dinv[s];
        const float4 v = *(const float4*)(xw + (size_t)s * H + lane * 4);
        acc.x += v.x * wgt; acc.y += v.y * wgt; acc.z += v.z * wgt; acc.w += v.w * wgt;
    }
    const float4 bv = *(const float4*)(b + lane * 4);
    float o[4];
    o[0] = fmaxf(acc.x + bv.x, 0.f);
    o[1] = fmaxf(acc.y + bv.y, 0.f);
    o[2] = fmaxf(acc.z + bv.z, 0.f);
    o[3] = fmaxf(acc.w + bv.w, 0.f);
    *(float4*)(out + (size_t)node * H + lane * 4) = *(const float4*)o;
    u16 hs[4];
#pragma unroll
    for (int j = 0; j < 4; j++) hs[j] = f2bf(o[j]);
    *(short4*)(xcp + (size_t)node * 256 + lane * 4) = *(const short4*)hs;
}
__global__ void k_colmax(float* __restrict__ out, const float* __restrict__ x) {
    int j = threadIdx.x;
    float m = 0.0f;
    for (int r = blockIdx.x; r < NROWS; r += gridDim.x)
        m = fmaxf(m, x[(size_t)r * H + j]);
    atomicMax((int*)&out[j], __float_as_int(m));
}

// ---------------------------------------------------------------------------
extern "C" void kernel_launch(void* const* d_in, const int* in_sizes, int n_in,
                              void* d_out, int out_size, void* d_ws, size_t ws_size,
                              hipStream_t stream) {
    const float* tree = (const float*)d_in[0];
    const float* s2 = (const float*)d_in[1];
    const float* s3 = (const float*)d_in[2];
    const float* s4 = (const float*)d_in[3];
    const float* s5 = (const float*)d_in[4];
    const int* edge = (const int*)d_in[5];
    const float* tl_Wioux = (const float*)d_in[6];
    const float* tl_bioux = (const float*)d_in[7];
    const float* tl_Wiouh = (const float*)d_in[8];
    const float* tl_biouh = (const float*)d_in[9];
    const float* tl_Wfx = (const float*)d_in[10];
    const float* tl_bfx = (const float*)d_in[11];
    const float* tl_Wfh = (const float*)d_in[12];
    const float* tl_bfh = (const float*)d_in[13];
    const float* gru_Wih = (const float*)d_in[14];
    const float* gru_Whh = (const float*)d_in[15];
    const float* gru_bih = (const float*)d_in[16];
    const float* gru_bhh = (const float*)d_in[17];
    const float* comb_Wih = (const float*)d_in[18];
    const float* comb_Whh = (const float*)d_in[19];
    const float* comb_bih = (const float*)d_in[20];
    const float* comb_bhh = (const float*)d_in[21];
    const float* connect_W = (const float*)d_in[22];
    const float* connect_b = (const float*)d_in[23];
    const float* gcn_W = (const float*)d_in[24];
    const float* gcn_b = (const float*)d_in[25];

    char* base = (char*)d_ws;
    size_t off = 0;
    auto aus = [&](size_t nu16) { u16* p = (u16*)(base + off); off += nu16 * sizeof(u16); return p; };
    u16* tx = aus(98304);
    u16* th = aus(196608);
    u16* tfx = aus(32768);
    u16* tfh = aus(65536);
    u16* gWih = aus(393216);
    u16* gWhh = aus(786432);
    u16* cWih = aus(393216);
    u16* cWhh = aus(393216);
    u16* cn = aus(655360);
    u16* gc = aus(196608);
    u16* feats = aus((size_t)5 * H2);
    u16* hA = aus((size_t)4 * H2);
    u16* hB = aus((size_t)4 * H2);
    u16* SA = aus((size_t)8 * XZ2);   // 10.48M u16 scratch
    u16* SB = aus((size_t)8 * XZ2);

    const dim3 blk(256);

    hipMemsetAsync(d_out, 0, H * sizeof(float), stream);

    auto SPW = [&](const float* s, u16* d, int n) {
        k_splitWb<<<(n / 8 + 255) / 256, blk, 0, stream>>>(s, d, n / 8);
    };
    SPW(tl_Wioux, tx, 98304);
    SPW(tl_Wiouh, th, 196608);
    SPW(tl_Wfx, tfx, 32768);
    SPW(tl_Wfh, tfh, 65536);
    SPW(gru_Wih, gWih, 393216);
    SPW(gru_Whh, gWhh, 786432);
    SPW(comb_Wih, cWih, 393216);
    SPW(comb_Whh, cWhh, 393216);
    SPW(connect_W, cn, 655360);
    SPW(gcn_W, gc, 196608);

    // -------- TreeLSTM (8 steps); hi-only x/h --------
    float* cbuf = (float*)SA;                    // 10.24MB
    u16* xtA = SA + 5120000;                     // 1.28M u16
    u16* xtB = SA + 6400000;
    hipMemsetAsync(hA, 0, (size_t)NROWS * 256 * 2, stream);
    hipMemsetAsync(cbuf, 0, (size_t)NROWS * H * 4, stream);
    k_split_xtree<<<640, blk, 0, stream>>>(tree, 0, xtA);
    {
        u16 *p = hA, *q = hB;
        for (int t = 0; t < LTREE; ++t) {
            bool last = (t == LTREE - 1);
            u16* xin = (t & 1) ? xtB : xtA;
            u16* xnx = last ? (u16*)0 : ((t & 1) ? xtA : xtB);
            k_tree_step_mf<<<dim3(4, 160, 1), blk, 0, stream>>>(
                tree + (t + 1) * FDIM, xnx,
                xin, tx, th, tfx, tfh, tl_bioux, tl_biouh, tl_bfx, tl_bfh,
                p, cbuf, last ? feats : q, last ? 1 : 0);
            u16* tmp = p; p = q; q = tmp;
        }
    }

    // -------- 4 GRUs (16 steps, z=4); hi-only --------
    u16* xsA = SA;   // 4*XZ2 = 5.24M u16
    u16* xsB = SB;
    hipMemsetAsync(hA, 0, (size_t)4 * H2 * 2, stream);
    k_split_xseq<<<2560, blk, 0, stream>>>(s2, s3, s4, s5, 0, xsA);
    {
        u16 *p = hA, *q = hB;
        for (int t = 0; t < TSEQ; ++t) {
            bool last = (t == TSEQ - 1);
            u16* xin = (t & 1) ? xsB : xsA;
            u16* xnx = last ? (u16*)0 : ((t & 1) ? xsA : xsB);
            k_rnn_step<<<dim3(4, 80, 4), blk, 0, stream>>>(
                s2, s3, s4, s5, (t + 1) * FDIM, xnx,
                xin,
                gWih, 98304LL, gWhh, 196608LL, gru_bih, gru_bhh,
                p,
                last ? feats + H2 : q);
            u16* tmp = p; p = q; q = tmp;
        }
    }

    // -------- combine bi-GRU (5 steps, z=2) + fused connect --------
    float* fvF = (float*)SA;
    float* fvB = fvF + (size_t)NROWS * H;
    hipMemsetAsync(hA, 0, (size_t)2 * H2 * 2, stream);
    k_fv_init<<<(NROWS * H + 255) / 256, blk, 0, stream>>>(fvF, connect_b);
    hipMemsetAsync(fvB, 0, (size_t)NROWS * H * 4, stream);
    {
        u16 *p = hA, *q = hB;
        for (int s = 0; s < 5; ++s) {
            k_rnn_step64<<<dim3(4, 160, 2), blk, 0, stream>>>(
                feats, (long long)s * H2, (long long)(4 - s) * H2,
                cWih, 196608LL, cWhh, 196608LL, comb_bih, comb_bhh,
                p, q);
            k_fv_acc_mf<<<dim3(4, 79, 2), blk, 0, stream>>>(
                fvF, q, cn, s * 512, (4 - s) * 512 + 256);
            u16* tmp = p; p = q; q = tmp;
        }
    }

    // -------- CSR build (tail of hB; xc occupies first 2.56M u16) --------
    int* cnt = (int*)(hB + 6000000);
    int* rowptr = cnt + 10016;
    int* cursor = rowptr + 10016;
    int* csr = cursor + 10016;
    float* dinv = (float*)(csr + NE);
    hipMemsetAsync(cnt, 0, NROWS * sizeof(int), stream);
    hipMemsetAsync(cursor, 0, NROWS * sizeof(int), stream);
    k_cnt<<<(NE + 255) / 256, blk, 0, stream>>>(cnt, edge + NE);
    k_scan<<<1, blk, 0, stream>>>(cnt, rowptr);
    k_dinv<<<(NROWS + 255) / 256, blk, 0, stream>>>(dinv, cnt);
    k_fill<<<(NE + 255) / 256, blk, 0, stream>>>(csr, cursor, rowptr, edge);

    // -------- 4 conv applications (last two share W2,b2) --------
    {
        u16* xc = hB;                            // hi-only [NROWS][256]
        float* xw = (float*)SB;
        float* cur = fvF;
        float* nxt = (float*)hA;
        k_splitNH2<<<1250, blk, 0, stream>>>(fvF, fvB, xc);
        for (int i = 0; i < 4; ++i) {
            int wi = (i < 3) ? i : 2;
            k_gcn_gemm<<<dim3(4, 80, 1), blk, 0, stream>>>(xw, xc, gc + (size_t)wi * 65536);
            k_gather<<<(NROWS + 3) / 4, blk, 0, stream>>>(nxt, xc, xw, dinv, rowptr, csr,
                                                          gcn_b + wi * H);
            float* tmp = cur; cur = nxt; nxt = tmp;
        }
        k_colmax<<<256, blk, 0, stream>>>((float*)d_out, cur);
    }
}

// Round 19
// 1812.598 us; speedup vs baseline: 1.2726x; 1.0106x over previous
//
#include <hip/hip_runtime.h>
#include <math.h>

#define H 256
#define NROWS 10000
#define LTREE 8
#define TSEQ 16
#define FDIM 128
#define NE 160000
#define HTILE2 32768     // 128 rows * 256 cols hi-only (u16)
#define XT2 16384        // 128 rows * 128 cols hi-only (u16)
#define H2 2621440       // 80 tiles * HTILE2
#define XZ2 1310720      // 80 tiles * XT2

typedef __attribute__((ext_vector_type(8))) short short8;
typedef __attribute__((ext_vector_type(4))) float f32x4;
typedef unsigned short u16;

__device__ __forceinline__ u16 f2bf(float x) {
    unsigned int u = __float_as_uint(x);
    return (u16)((u + 0x7fffu + ((u >> 16) & 1u)) >> 16);
}
__device__ __forceinline__ float bf2f(u16 s) { return __uint_as_float(((unsigned int)s) << 16); }
__device__ __forceinline__ short8 ldf(const u16* __restrict__ p) { return *(const short8*)(p); }
__device__ __forceinline__ float fexp_(float x) { return __expf(fminf(x, 80.f)); }
__device__ __forceinline__ float fsig_(float x) { return 1.f / (1.f + fexp_(-x)); }
__device__ __forceinline__ float ftanh_(float x) {
    float e = fexp_(fmaxf(2.f * x, -80.f));
    return (e - 1.f) / (e + 1.f);
}
#define MFMA(A, B, C) C = __builtin_amdgcn_mfma_f32_16x16x32_bf16(A, B, C, 0, 0, 0)

__device__ __forceinline__ void async16(u16* l, const u16* g) {
    __builtin_amdgcn_global_load_lds((__attribute__((address_space(1))) const void*)g,
                                     (__attribute__((address_space(3))) void*)l, 16, 0, 0);
}

// XCD-aware remap, bijective when nwg%8==0.
__device__ __forceinline__ void xcd_swz(int& cbi, int& yy, int& zz) {
    const int gx = gridDim.x, gy = gridDim.y;
    int nwg8 = (gx * gy * gridDim.z) >> 3;
    int bid = blockIdx.x + gx * (blockIdx.y + gy * blockIdx.z);
    int wgid = (bid & 7) * nwg8 + (bid >> 3);
    cbi = wgid % gx;
    int rem = wgid / gx;
    yy = rem % gy;
    zz = rem / gy;
}

// hi-only tiled offsets
__device__ __forceinline__ size_t xpo(int row, int g) {   // 128-col x tile
    return (size_t)(row >> 7) * XT2 + (size_t)g * 1024 + (size_t)(row & 127) * 8;
}

// Stage one 32KB chunk (pre-tiled source == LDS image), 128-row tiles. 8 loads/wave.
__device__ __forceinline__ void stageT32(u16* ldsbuf, const u16* __restrict__ chunkbase,
                                         int w, int lane) {
#pragma unroll
    for (int cc = 0; cc < 8; cc++) {
        int eb = (w * 8 + cc) * 64;
        async16(ldsbuf + (size_t)eb * 8, chunkbase + (size_t)(eb + lane) * 8);
    }
}
// Stage a 16KB half-tile chunk (64 rows, 128 k). 4 loads/wave.
__device__ __forceinline__ void stage64T16(u16* ldsbuf, const u16* __restrict__ chunkbase,
                                           int w, int lane) {
#pragma unroll
    for (int cc = 0; cc < 4; cc++) {
        int p = w * 4 + cc;
        async16(ldsbuf + (size_t)p * 512, chunkbase + (size_t)p * 1024 + (size_t)lane * 8);
    }
}
// hi-only row-major 64-row chunk (tree kernel): 16 planes x 8 u16 cols.
__device__ __forceinline__ void stage_chunk64h(u16* ldsbuf, const u16* __restrict__ src,
                                               int stride_u16, int kb_u16, int m0,
                                               int w, int lane) {
#pragma unroll
    for (int c = 0; c < 4; c++) {
        int e_base = (w * 4 + c) * 64;
        int e = e_base + lane;
        int p = e >> 6, rs = e & 63;
        int row = m0 + rs;
        if (row > NROWS - 1) row = NROWS - 1;
        const u16* g = src + (size_t)row * stride_u16 + kb_u16 + p * 8;
        async16(ldsbuf + (size_t)e_base * 8, g);
    }
}

// ---------------- split helpers (hi-only) ----------------
__device__ __forceinline__ void emit8h(u16* __restrict__ dst, const float* v8) {
    short8 h;
#pragma unroll
    for (int j = 0; j < 8; j++) h[j] = (short)f2bf(v8[j]);
    *(short8*)dst = h;
}
__global__ void k_splitWb(const float* __restrict__ src, u16* __restrict__ dst, int ngroups) {
    int g = blockIdx.x * 256 + threadIdx.x;
    if (g < ngroups) {
        float v[8];
        *(float4*)v = *(const float4*)(src + (size_t)g * 8);
        *(float4*)(v + 4) = *(const float4*)(src + (size_t)g * 8 + 4);
        emit8h(dst + (size_t)g * 8, v);
    }
}
// t=0 seed for GRU x: tiled hi-only [4][XZ2]
__global__ void k_split_xseq(const float* __restrict__ s2, const float* __restrict__ s3,
                             const float* __restrict__ s4, const float* __restrict__ s5,
                             int t, u16* __restrict__ dst) {
    int bid = blockIdx.x;
    int xcd = bid & 7, chunk = bid >> 3;
    int z = xcd >> 1, half = xcd & 1;
    int g = chunk * 256 + threadIdx.x;
    int row = half * 5120 + (g >> 4);
    if (row >= NROWS) return;
    int gg = g & 15;
    const float* s = (z == 0) ? s2 : (z == 1) ? s3 : (z == 2) ? s4 : s5;
    const float* p = s + (size_t)row * (TSEQ * FDIM) + t * FDIM + gg * 8;
    float v[8];
    *(float4*)v = *(const float4*)p;
    *(float4*)(v + 4) = *(const float4*)(p + 4);
    emit8h(dst + (size_t)z * XZ2 + xpo(row, gg), v);
}
// tree x seed: row-major hi-only [NROWS][128]
__global__ void k_split_xtree(const float* __restrict__ tree, int t, u16* __restrict__ dst) {
    int bid = blockIdx.x;
    int xcd = bid & 7, chunk = bid >> 3;
    int g = chunk * 256 + threadIdx.x;
    int row = xcd * 1280 + (g >> 4);
    if (row >= NROWS) return;
    int col = (g & 15) * 8;
    const float* p = tree + (size_t)row * (LTREE * FDIM) + t * FDIM + col;
    float v[8];
    *(float4*)v = *(const float4*)p;
    *(float4*)(v + 4) = *(const float4*)(p + 4);
    emit8h(dst + (size_t)row * 128 + col, v);
}
// (fvF + fvB) f32 -> hi-only [NROWS][256] (GCN conv input)
__global__ void k_splitNH2(const float* __restrict__ a, const float* __restrict__ b,
                           u16* __restrict__ dst) {
    int g = blockIdx.x * 256 + threadIdx.x;
    if (g < NROWS * 32) {
        float v[8];
        float4 x0 = *(const float4*)(a + (size_t)g * 8);
        float4 x1 = *(const float4*)(a + (size_t)g * 8 + 4);
        float4 y0 = *(const float4*)(b + (size_t)g * 8);
        float4 y1 = *(const float4*)(b + (size_t)g * 8 + 4);
        v[0] = x0.x + y0.x; v[1] = x0.y + y0.y; v[2] = x0.z + y0.z; v[3] = x0.w + y0.w;
        v[4] = x1.x + y1.x; v[5] = x1.y + y1.y; v[6] = x1.z + y1.z; v[7] = x1.w + y1.w;
        emit8h(dst + (size_t)g * 8, v);
    }
}

// ---------------------------------------------------------------------------
// GRU step: 128-row A-tile, RF=8, hi-only. NC = 1 x-chunk (K=128) + 2 h-chunks
// (K=128 each), 32KB chunks -> 3 barriers. grid (4,80,4).
// ---------------------------------------------------------------------------
__global__ __launch_bounds__(256, 2) void k_rnn_step(
    const float* __restrict__ q0, const float* __restrict__ q1,
    const float* __restrict__ q2, const float* __restrict__ q3,
    int qoff4, u16* __restrict__ xnext,
    const u16* __restrict__ xp,
    const u16* __restrict__ Wih, long long wz,
    const u16* __restrict__ Whh, long long wzh,
    const float* __restrict__ bihB, const float* __restrict__ bhhB,
    const u16* __restrict__ hp,
    u16* __restrict__ op) {
    __shared__ u16 lds[2][16384];
    const int tid = threadIdx.x, lane = tid & 63, w = tid >> 6;
    const int lx = lane & 15, lg = lane >> 4;
    int cbi, yy, z;
    xcd_swz(cbi, yy, z);
    const int colw = cbi * 64 + w * 16;
    const int m0 = yy * 128;
    const u16* xb = xp + (size_t)z * XZ2 + (size_t)yy * XT2;
    const u16* hb = hp + (size_t)z * H2;
    const u16* hbt = hb + (size_t)yy * HTILE2;
    const float* bih = bihB + z * 768;
    const float* bhh = bhhB + z * 768;
    constexpr int NC = 3;

    const u16* bx0 = Wih + (size_t)z * wz + (size_t)(colw + lx) * 128 + lg * 8;
    const u16* bx1 = bx0 + 32768;
    const u16* bx2 = bx0 + 65536;
    const u16* bh0 = Whh + (size_t)z * wzh + (size_t)(colw + lx) * 256 + lg * 8;
    const u16* bh1 = bh0 + 65536;
    const u16* bh2 = bh0 + 131072;

    const f32x4 zf = {0.f, 0.f, 0.f, 0.f};
    f32x4 aR[8], aZ[8], aNX[8], aNH[8];
#pragma unroll
    for (int rf = 0; rf < 8; rf++) { aR[rf] = zf; aZ[rf] = zf; aNX[rf] = zf; aNH[rf] = zf; }

    auto chunksrc = [&](int c) -> const u16* {
        return (c == 0) ? xb : hbt + (size_t)(c - 1) * 16384;
    };
    stageT32(lds[0], chunksrc(0), w, lane);

    // fused next-timestep x split (hi-only tiled stores)
    if (xnext) {
        const float* qs = (z == 0) ? q0 : (z == 1) ? q1 : (z == 2) ? q2 : q3;
        int row = m0 + (tid >> 1);
        if (row < NROWS) {
            int g0 = (cbi * 32 + (tid & 1) * 16) >> 3;
            const float* p = qs + (size_t)row * (TSEQ * FDIM) + qoff4 + g0 * 8;
            u16* d = xnext + (size_t)z * XZ2;
            float v[8];
            *(float4*)v = *(const float4*)p;
            *(float4*)(v + 4) = *(const float4*)(p + 4);
            emit8h(d + xpo(row, g0), v);
            *(float4*)v = *(const float4*)(p + 8);
            *(float4*)(v + 4) = *(const float4*)(p + 12);
            emit8h(d + xpo(row, g0 + 1), v);
        }
    }

    for (int c = 0; c < NC; c++) {
        __syncthreads();  // drains DMA for lds[c&1]
        if (c + 1 < NC) stageT32(lds[(c + 1) & 1], chunksrc(c + 1), w, lane);
        const u16* lb = lds[c & 1];
        const bool isX = (c == 0);
#pragma unroll
        for (int s = 0; s < 4; s++) {
            short8 axh[8];
            const u16* ph = lb + (size_t)(s * 4 + lg) * 1024 + lx * 8;
#pragma unroll
            for (int rf = 0; rf < 8; rf++) axh[rf] = ldf(ph + rf * 128);
            const int ko = isX ? s * 32 : (c - 1) * 128 + s * 32;
            if (isX) {
                {
                    short8 bh_ = ldf(bx0 + ko);
#pragma unroll
                    for (int rf = 0; rf < 8; rf++) MFMA(axh[rf], bh_, aR[rf]);
                }
                {
                    short8 bh_ = ldf(bx1 + ko);
#pragma unroll
                    for (int rf = 0; rf < 8; rf++) MFMA(axh[rf], bh_, aZ[rf]);
                }
                {
                    short8 bh_ = ldf(bx2 + ko);
#pragma unroll
                    for (int rf = 0; rf < 8; rf++) MFMA(axh[rf], bh_, aNX[rf]);
                }
            } else {
                {
                    short8 bh_ = ldf(bh0 + ko);
#pragma unroll
                    for (int rf = 0; rf < 8; rf++) MFMA(axh[rf], bh_, aR[rf]);
                }
                {
                    short8 bh_ = ldf(bh1 + ko);
#pragma unroll
                    for (int rf = 0; rf < 8; rf++) MFMA(axh[rf], bh_, aZ[rf]);
                }
                {
                    short8 bh_ = ldf(bh2 + ko);
#pragma unroll
                    for (int rf = 0; rf < 8; rf++) MFMA(axh[rf], bh_, aNH[rf]);
                }
            }
        }
    }
    const int col = colw + lx;
    const float b_r = bih[col] + bhh[col];
    const float b_z = bih[256 + col] + bhh[256 + col];
    const float bx_n = bih[512 + col], bh_n = bhh[512 + col];
    const size_t colpart = (size_t)(col >> 3) * 1024 + (col & 7);
    u16* ob = op + (size_t)z * H2;
#pragma unroll
    for (int rf = 0; rf < 8; rf++) {
#pragma unroll
        for (int rr = 0; rr < 4; rr++) {
            int row = m0 + rf * 16 + lg * 4 + rr;
            if (row < NROWS) {
                float rg = fsig_(aR[rf][rr] + b_r);
                float zg = fsig_(aZ[rf][rr] + b_z);
                float ng = ftanh_(aNX[rf][rr] + bx_n + rg * (aNH[rf][rr] + bh_n));
                size_t addr = (size_t)(row >> 7) * HTILE2 + (size_t)(row & 127) * 8 + colpart;
                float hold = bf2f(hb[addr]);
                float hnew = (1.f - zg) * ng + zg * hold;
                ob[addr] = f2bf(hnew);
            }
        }
    }
}

// ---------------------------------------------------------------------------
// comb GRU step: 64-row tile, RF=4, 3 waves/SIMD; hi-only. NC = 2 x + 2 h
// chunks of 128 k (16KB). grid (4,160,2).
// ---------------------------------------------------------------------------
__global__ __launch_bounds__(256, 3) void k_rnn_step64(
    const u16* __restrict__ xp, long long xo0, long long xo1,
    const u16* __restrict__ Wih, long long wz,
    const u16* __restrict__ Whh, long long wzh,
    const float* __restrict__ bihB, const float* __restrict__ bhhB,
    const u16* __restrict__ hp,
    u16* __restrict__ op) {
    __shared__ u16 lds[2][8192];
    const int tid = threadIdx.x, lane = tid & 63, w = tid >> 6;
    const int lx = lane & 15, lg = lane >> 4;
    int cbi, yy, z;
    xcd_swz(cbi, yy, z);
    const int colw = cbi * 64 + w * 16;
    const int m0 = yy * 64;
    const int tile = yy >> 1, rh = yy & 1;
    const u16* xb = xp + (size_t)((z == 1) ? xo1 : xo0) + (size_t)tile * HTILE2 + rh * 512;
    const u16* hb = hp + (size_t)z * H2;
    const u16* hbt = hb + (size_t)tile * HTILE2 + rh * 512;
    const float* bih = bihB + z * 768;
    const float* bhh = bhhB + z * 768;
    constexpr int NCX = 2, NC = 4;

    const u16* bx0 = Wih + (size_t)z * wz + (size_t)(colw + lx) * 256 + lg * 8;
    const u16* bx1 = bx0 + 65536;
    const u16* bx2 = bx0 + 131072;
    const u16* bh0 = Whh + (size_t)z * wzh + (size_t)(colw + lx) * 256 + lg * 8;
    const u16* bh1 = bh0 + 65536;
    const u16* bh2 = bh0 + 131072;

    const f32x4 zf = {0.f, 0.f, 0.f, 0.f};
    f32x4 aR[4], aZ[4], aNX[4], aNH[4];
#pragma unroll
    for (int rf = 0; rf < 4; rf++) { aR[rf] = zf; aZ[rf] = zf; aNX[rf] = zf; aNH[rf] = zf; }

    auto chunksrc = [&](int c) -> const u16* {
        return (c < NCX) ? xb + (size_t)c * 16384 : hbt + (size_t)(c - NCX) * 16384;
    };
    stage64T16(lds[0], chunksrc(0), w, lane);

    for (int c = 0; c < NC; c++) {
        __syncthreads();
        if (c + 1 < NC) stage64T16(lds[(c + 1) & 1], chunksrc(c + 1), w, lane);
        const u16* lb = lds[c & 1];
        const bool isX = (c < NCX);
        const int cl = isX ? c : c - NCX;
#pragma unroll
        for (int s = 0; s < 4; s++) {
            short8 axh[4];
            const u16* ph = lb + (size_t)(s * 4 + lg) * 512 + lx * 8;
#pragma unroll
            for (int rf = 0; rf < 4; rf++) axh[rf] = ldf(ph + rf * 128);
            const int ko = cl * 128 + s * 32;
            if (isX) {
                {
                    short8 bh_ = ldf(bx0 + ko);
#pragma unroll
                    for (int rf = 0; rf < 4; rf++) MFMA(axh[rf], bh_, aR[rf]);
                }
                {
                    short8 bh_ = ldf(bx1 + ko);
#pragma unroll
                    for (int rf = 0; rf < 4; rf++) MFMA(axh[rf], bh_, aZ[rf]);
                }
                {
                    short8 bh_ = ldf(bx2 + ko);
#pragma unroll
                    for (int rf = 0; rf < 4; rf++) MFMA(axh[rf], bh_, aNX[rf]);
                }
            } else {
                {
                    short8 bh_ = ldf(bh0 + ko);
#pragma unroll
                    for (int rf = 0; rf < 4; rf++) MFMA(axh[rf], bh_, aR[rf]);
                }
                {
                    short8 bh_ = ldf(bh1 + ko);
#pragma unroll
                    for (int rf = 0; rf < 4; rf++) MFMA(axh[rf], bh_, aZ[rf]);
                }
                {
                    short8 bh_ = ldf(bh2 + ko);
#pragma unroll
                    for (int rf = 0; rf < 4; rf++) MFMA(axh[rf], bh_, aNH[rf]);
                }
            }
        }
    }
    const int col = colw + lx;
    const float b_r = bih[col] + bhh[col];
    const float b_z = bih[256 + col] + bhh[256 + col];
    const float bx_n = bih[512 + col], bh_n = bhh[512 + col];
    const size_t colpart = (size_t)(col >> 3) * 1024 + (col & 7);
    u16* ob = op + (size_t)z * H2;
#pragma unroll
    for (int rf = 0; rf < 4; rf++) {
#pragma unroll
        for (int rr = 0; rr < 4; rr++) {
            int row = m0 + rf * 16 + lg * 4 + rr;
            if (row < NROWS) {
                float rg = fsig_(aR[rf][rr] + b_r);
                float zg = fsig_(aZ[rf][rr] + b_z);
                float ng = ftanh_(aNX[rf][rr] + bx_n + rg * (aNH[rf][rr] + bh_n));
                size_t addr = (size_t)(row >> 7) * HTILE2 + (size_t)(row & 127) * 8 + colpart;
                float hold = bf2f(hb[addr]);
                float hnew = (1.f - zg) * ng + zg * hold;
                ob[addr] = f2bf(hnew);
            }
        }
    }
}

// ---------------------------------------------------------------------------
// TreeLSTM step: 64-row tile, RF=4, hi-only x [row][128] and h [row][256].
// NC = 1 x-chunk + 2 h-chunks (128 k each). grid (4, 160, 1).
// ---------------------------------------------------------------------------
__global__ __launch_bounds__(256, 3) void k_tree_step_mf(
    const float* __restrict__ treenext, u16* __restrict__ xtnext,
    const u16* __restrict__ txp,
    const u16* __restrict__ Wx, const u16* __restrict__ Wh,
    const u16* __restrict__ Wfx, const u16* __restrict__ Wfh,
    const float* __restrict__ bioux, const float* __restrict__ biouh,
    const float* __restrict__ bfx, const float* __restrict__ bfh,
    const u16* __restrict__ hp, float* __restrict__ cst,
    u16* __restrict__ op, int tiledOut) {
    __shared__ u16 lds[2][8192];
    const int tid = threadIdx.x, lane = tid & 63, w = tid >> 6;
    const int lx = lane & 15, lg = lane >> 4;
    int cbi, yy, zz;
    xcd_swz(cbi, yy, zz);
    const int colw = cbi * 64 + w * 16;
    const int m0 = yy * 64;
    constexpr int NC = 3;

    const u16* bx0 = Wx + (size_t)(colw + lx) * 128 + lg * 8;
    const u16* bx1 = bx0 + 32768;
    const u16* bx2 = bx0 + 65536;
    const u16* bxf = Wfx + (size_t)(colw + lx) * 128 + lg * 8;
    const u16* bh0 = Wh + (size_t)(colw + lx) * 256 + lg * 8;
    const u16* bh1 = bh0 + 65536;
    const u16* bh2 = bh0 + 131072;
    const u16* bhf = Wfh + (size_t)(colw + lx) * 256 + lg * 8;

    const f32x4 zf = {0.f, 0.f, 0.f, 0.f};
    f32x4 aI[4], aO[4], aU[4], aF[4];
#pragma unroll
    for (int rf = 0; rf < 4; rf++) { aI[rf] = zf; aO[rf] = zf; aU[rf] = zf; aF[rf] = zf; }

    stage_chunk64h(lds[0], txp, 128, 0, m0, w, lane);

    if (xtnext) {
        int row = m0 + (tid >> 2);
        if (row < NROWS) {
            int c0 = cbi * 32 + (tid & 3) * 8;
            const float* p = treenext + (size_t)row * (LTREE * FDIM) + c0;
            float v[8];
            *(float4*)v = *(const float4*)p;
            *(float4*)(v + 4) = *(const float4*)(p + 4);
            emit8h(xtnext + (size_t)row * 128 + c0, v);
        }
    }

    for (int c = 0; c < NC; c++) {
        __syncthreads();
        if (c + 1 < NC) stage_chunk64h(lds[(c + 1) & 1], hp, 256, c * 128, m0, w, lane);
        const u16* lb = lds[c & 1];
        const bool isX = (c == 0);
#pragma unroll
        for (int s = 0; s < 4; s++) {
            short8 axh[4];
            const u16* ph = lb + (size_t)(s * 4 + lg) * 512 + lx * 8;
#pragma unroll
            for (int rf = 0; rf < 4; rf++) axh[rf] = ldf(ph + rf * 128);
            const int ko = isX ? s * 32 : (c - 1) * 128 + s * 32;
            const u16* p0 = isX ? bx0 : bh0;
            const u16* p1 = isX ? bx1 : bh1;
            const u16* p2 = isX ? bx2 : bh2;
            const u16* p3 = isX ? bxf : bhf;
            {
                short8 bh_ = ldf(p0 + ko);
#pragma unroll
                for (int rf = 0; rf < 4; rf++) MFMA(axh[rf], bh_, aI[rf]);
            }
            {
                short8 bh_ = ldf(p1 + ko);
#pragma unroll
                for (int rf = 0; rf < 4; rf++) MFMA(axh[rf], bh_, aO[rf]);
            }
            {
                short8 bh_ = ldf(p2 + ko);
#pragma unroll
                for (int rf = 0; rf < 4; rf++) MFMA(axh[rf], bh_, aU[rf]);
            }
            {
                short8 bh_ = ldf(p3 + ko);
#pragma unroll
                for (int rf = 0; rf < 4; rf++) MFMA(axh[rf], bh_, aF[rf]);
            }
        }
    }
    const int col = colw + lx;
    const float b_i = bioux[col] + biouh[col];
    const float b_o = bioux[256 + col] + biouh[256 + col];
    const float b_u = bioux[512 + col] + biouh[512 + col];
    const float b_f = bfx[col] + bfh[col];
    const size_t colpart2 = (size_t)(col >> 3) * 1024 + (col & 7);
#pragma unroll
    for (int rf = 0; rf < 4; rf++) {
#pragma unroll
        for (int rr = 0; rr < 4; rr++) {
            int row = m0 + rf * 16 + lg * 4 + rr;
            if (row < NROWS) {
                float ig = fsig_(aI[rf][rr] + b_i);
                float og = fsig_(aO[rf][rr] + b_o);
                float ug = ftanh_(aU[rf][rr] + b_u);
                float fg = fsig_(aF[rf][rr] + b_f);
                size_t ci = (size_t)row * H + col;
                float cnew = ig * ug + fg * cst[ci];
                cst[ci] = cnew;
                float hnew = og * ftanh_(cnew);
                if (tiledOut) {
                    size_t addr = (size_t)(row >> 7) * HTILE2 + (size_t)(row & 127) * 8 + colpart2;
                    op[addr] = f2bf(hnew);
                } else {
                    op[(size_t)row * 256 + col] = f2bf(hnew);
                }
            }
        }
    }
}

// fv_z += h_z @ Wc-slice^T ; hi-only h. grid (4,79,2).
__global__ __launch_bounds__(256) void k_fv_acc_mf(
    float* __restrict__ fvbase, const u16* __restrict__ hq,
    const u16* __restrict__ Wc, int off_f, int off_b) {
    const int tid = threadIdx.x, lane = tid & 63, w = tid >> 6;
    const int lx = lane & 15, kl8 = (lane >> 4);
    int cbi, yy, z;
    xcd_swz(cbi, yy, z);
    const int wr = w >> 1, wc = w & 1;
    const int cb = cbi * 64 + wc * 32;
    const int m0 = yy * 128 + wr * 64;
    int arow[4];
#pragma unroll
    for (int rf = 0; rf < 4; rf++) {
        int r = m0 + rf * 16 + lx;
        arow[rf] = (r < NROWS) ? r : NROWS - 1;
    }
    const f32x4 zf = {0.f, 0.f, 0.f, 0.f};
    f32x4 acc[4][2] = {{zf, zf}, {zf, zf}, {zf, zf}, {zf, zf}};
    const u16* aB = hq + (size_t)z * H2;
    const int off = z ? off_b : off_f;
    const u16* a[4];
#pragma unroll
    for (int rf = 0; rf < 4; rf++) {
        a[rf] = aB + (size_t)(arow[rf] >> 7) * HTILE2 + (size_t)(arow[rf] & 127) * 8 +
                (size_t)kl8 * 1024;
    }
    const u16* bp0 = Wc + (size_t)(cb + lx) * 2560 + off + kl8 * 8;
    const u16* bp1 = bp0 + 16 * 2560;
#pragma unroll
    for (int it = 0; it < 8; it++) {
        short8 axh[4];
#pragma unroll
        for (int rf = 0; rf < 4; rf++) {
            axh[rf] = ldf(a[rf]);
            a[rf] += 4096;
        }
        const int kb = it * 32;
        {
            short8 bh = ldf(bp0 + kb);
#pragma unroll
            for (int rf = 0; rf < 4; rf++) MFMA(axh[rf], bh, acc[rf][0]);
        }
        {
            short8 bh = ldf(bp1 + kb);
#pragma unroll
            for (int rf = 0; rf < 4; rf++) MFMA(axh[rf], bh, acc[rf][1]);
        }
    }
    float* fv = fvbase + (size_t)z * (NROWS * H);
#pragma unroll
    for (int rf = 0; rf < 4; rf++) {
#pragma unroll
        for (int cf = 0; cf < 2; cf++) {
            int col = cb + cf * 16 + lx;
#pragma unroll
            for (int rr = 0; rr < 4; rr++) {
                int row = m0 + rf * 16 + (lane >> 4) * 4 + rr;
                if (row < NROWS) fv[(size_t)row * H + col] += acc[rf][cf][rr];
            }
        }
    }
}

// out = A @ W^T; A hi-only [row][256], W bf16. RF=2, grid (4,80).
__global__ __launch_bounds__(256) void k_gcn_gemm(
    float* __restrict__ out, const u16* __restrict__ ap_, const u16* __restrict__ W) {
    const int tid = threadIdx.x, lane = tid & 63, w = tid >> 6;
    const int lx = lane & 15, kl = (lane >> 4) * 8;
    int cbi, yy, zz;
    xcd_swz(cbi, yy, zz);
    const int cb = cbi * 64, m0 = yy * 128 + w * 32;
    int arow[2];
#pragma unroll
    for (int rf = 0; rf < 2; rf++) {
        int r = m0 + rf * 16 + lx;
        arow[rf] = (r < NROWS) ? r : NROWS - 1;
    }
    const f32x4 zf = {0.f, 0.f, 0.f, 0.f};
    f32x4 acc[2][4] = {{zf, zf, zf, zf}, {zf, zf, zf, zf}};
    const u16* a0 = ap_ + (size_t)arow[0] * 256 + kl;
    const u16* a1 = ap_ + (size_t)arow[1] * 256 + kl;
    const u16* bp0 = W + (size_t)(cb + lx) * 256 + kl;
    const u16* bp1 = bp0 + 16 * 256;
    const u16* bp2 = bp0 + 32 * 256;
    const u16* bp3 = bp0 + 48 * 256;
#pragma unroll
    for (int kb = 0; kb < 256; kb += 32) {
        short8 axh[2];
        axh[0] = ldf(a0 + kb);
        axh[1] = ldf(a1 + kb);
        {
            short8 bh = ldf(bp0 + kb);
#pragma unroll
            for (int rf = 0; rf < 2; rf++) MFMA(axh[rf], bh, acc[rf][0]);
        }
        {
            short8 bh = ldf(bp1 + kb);
#pragma unroll
            for (int rf = 0; rf < 2; rf++) MFMA(axh[rf], bh, acc[rf][1]);
        }
        {
            short8 bh = ldf(bp2 + kb);
#pragma unroll
            for (int rf = 0; rf < 2; rf++) MFMA(axh[rf], bh, acc[rf][2]);
        }
        {
            short8 bh = ldf(bp3 + kb);
#pragma unroll
            for (int rf = 0; rf < 2; rf++) MFMA(axh[rf], bh, acc[rf][3]);
        }
    }
#pragma unroll
    for (int rf = 0; rf < 2; rf++) {
#pragma unroll
        for (int cf = 0; cf < 4; cf++) {
            int col = cb + cf * 16 + lx;
#pragma unroll
            for (int rr = 0; rr < 4; rr++) {
                int row = m0 + rf * 16 + (lane >> 4) * 4 + rr;
                if (row < NROWS) out[(size_t)row * H + col] = acc[rf][cf][rr];
            }
        }
    }
}

// ---------------------------- GCN small kernels -----------------------------
__global__ void k_fv_init(float* fv, const float* __restrict__ b) {
    int idx = blockIdx.x * 256 + threadIdx.x;
    if (idx < NROWS * H) fv[idx] = b[idx & (H - 1)];
}
__global__ void k_cnt(int* __restrict__ cnt, const int* __restrict__ dst) {
    int i = blockIdx.x * 256 + threadIdx.x;
    if (i < NE) atomicAdd(&cnt[dst[i]], 1);
}
__global__ void k_scan(const int* __restrict__ cnt, int* __restrict__ rowptr) {
    __shared__ int part[256];
    int tid = threadIdx.x;
    int st = tid * 40, en = (st + 40 > NROWS) ? NROWS : st + 40;
    int s = 0;
    for (int i = st; i < en; i++) s += cnt[i];
    part[tid] = s;
    __syncthreads();
    if (tid == 0) {
        int run = 0;
        for (int i = 0; i < 256; i++) { int t = part[i]; part[i] = run; run += t; }
        rowptr[NROWS] = run;
    }
    __syncthreads();
    int run = part[tid];
    for (int i = st; i < en; i++) { rowptr[i] = run; run += cnt[i]; }
}
__global__ void k_dinv(float* __restrict__ dinv, const int* __restrict__ cnt) {
    int i = blockIdx.x * 256 + threadIdx.x;
    if (i < NROWS) dinv[i] = rsqrtf(1.0f + (float)cnt[i]);
}
__global__ void k_fill(int* __restrict__ csr, int* __restrict__ cursor,
                       const int* __restrict__ rowptr, const int* __restrict__ ei) {
    int e = blockIdx.x * 256 + threadIdx.x;
    if (e < NE) {
        int d = ei[NE + e];
        int p = atomicAdd(&cursor[d], 1);
        csr[rowptr[d] + p] = ei[e];
    }
}
__global__ __launch_bounds__(256) void k_gather(
    float* __restrict__ out, u16* __restrict__ xcp,
    const float* __restrict__ xw, const float* __restrict__ dinv,
    const int* __restrict__ rowptr, const int* __restrict__ csr, const float* __restrict__ b) {
    int node = blockIdx.x * 4 + (threadIdx.x >> 6);
    if (node >= NROWS) return;
    int lane = threadIdx.x & 63;
    float dn = dinv[node];
    float4 acc = *(const float4*)(xw + (size_t)node * H + lane * 4);
    float dn2 = dn * dn;
    acc.x *= dn2; acc.y *= dn2; acc.z *= dn2; acc.w *= dn2;
    int e0 = rowptr[node], e1 = rowptr[node + 1];
    for (int i = e0; i < e1; i++) {
        int s = csr[i];
        float wgt = dn * dinv[s];
        const float4 v = *(const float4*)(xw + (size_t)s * H + lane * 4);
        acc.x += v.x * wgt; acc.y += v.y * wgt; acc.z += v.z * wgt; acc.w += v.w * wgt;
    }
    const float4 bv = *(const float4*)(b + lane * 4);
    float o[4];
    o[0] = fmaxf(acc.x + bv.x, 0.f);
    o[1] = fmaxf(acc.y + bv.y, 0.f);
    o[2] = fmaxf(acc.z + bv.z, 0.f);
    o[3] = fmaxf(acc.w + bv.w, 0.f);
    *(float4*)(out + (size_t)node * H + lane * 4) = *(const float4*)o;
    u16 hs[4];
#pragma unroll
    for (int j = 0; j < 4; j++) hs[j] = f2bf(o[j]);
    *(short4*)(xcp + (size_t)node * 256 + lane * 4) = *(const short4*)hs;
}
__global__ void k_colmax(float* __restrict__ out, const float* __restrict__ x) {
    int j = threadIdx.x;
    float m = 0.0f;
    for (int r = blockIdx.x; r < NROWS; r += gridDim.x)
        m = fmaxf(m, x[(size_t)r * H + j]);
    atomicMax((int*)&out[j], __float_as_int(m));
}

// ---------------------------------------------------------------------------
extern "C" void kernel_launch(void* const* d_in, const int* in_sizes, int n_in,
                              void* d_out, int out_size, void* d_ws, size_t ws_size,
                              hipStream_t stream) {
    const float* tree = (const float*)d_in[0];
    const float* s2 = (const float*)d_in[1];
    const float* s3 = (const float*)d_in[2];
    const float* s4 = (const float*)d_in[3];
    const float* s5 = (const float*)d_in[4];
    const int* edge = (const int*)d_in[5];
    const float* tl_Wioux = (const float*)d_in[6];
    const float* tl_bioux = (const float*)d_in[7];
    const float* tl_Wiouh = (const float*)d_in[8];
    const float* tl_biouh = (const float*)d_in[9];
    const float* tl_Wfx = (const float*)d_in[10];
    const float* tl_bfx = (const float*)d_in[11];
    const float* tl_Wfh = (const float*)d_in[12];
    const float* tl_bfh = (const float*)d_in[13];
    const float* gru_Wih = (const float*)d_in[14];
    const float* gru_Whh = (const float*)d_in[15];
    const float* gru_bih = (const float*)d_in[16];
    const float* gru_bhh = (const float*)d_in[17];
    const float* comb_Wih = (const float*)d_in[18];
    const float* comb_Whh = (const float*)d_in[19];
    const float* comb_bih = (const float*)d_in[20];
    const float* comb_bhh = (const float*)d_in[21];
    const float* connect_W = (const float*)d_in[22];
    const float* connect_b = (const float*)d_in[23];
    const float* gcn_W = (const float*)d_in[24];
    const float* gcn_b = (const float*)d_in[25];

    char* base = (char*)d_ws;
    size_t off = 0;
    auto aus = [&](size_t nu16) { u16* p = (u16*)(base + off); off += nu16 * sizeof(u16); return p; };
    u16* tx = aus(98304);
    u16* th = aus(196608);
    u16* tfx = aus(32768);
    u16* tfh = aus(65536);
    u16* gWih = aus(393216);
    u16* gWhh = aus(786432);
    u16* cWih = aus(393216);
    u16* cWhh = aus(393216);
    u16* cn = aus(655360);
    u16* gc = aus(196608);
    u16* feats = aus((size_t)5 * H2);
    u16* hA = aus((size_t)4 * H2);
    u16* hB = aus((size_t)4 * H2);
    u16* SA = aus((size_t)8 * XZ2);   // 10.48M u16 scratch
    u16* SB = aus((size_t)8 * XZ2);

    const dim3 blk(256);

    hipMemsetAsync(d_out, 0, H * sizeof(float), stream);

    auto SPW = [&](const float* s, u16* d, int n) {
        k_splitWb<<<(n / 8 + 255) / 256, blk, 0, stream>>>(s, d, n / 8);
    };
    SPW(tl_Wioux, tx, 98304);
    SPW(tl_Wiouh, th, 196608);
    SPW(tl_Wfx, tfx, 32768);
    SPW(tl_Wfh, tfh, 65536);
    SPW(gru_Wih, gWih, 393216);
    SPW(gru_Whh, gWhh, 786432);
    SPW(comb_Wih, cWih, 393216);
    SPW(comb_Whh, cWhh, 393216);
    SPW(connect_W, cn, 655360);
    SPW(gcn_W, gc, 196608);

    // -------- TreeLSTM (8 steps); hi-only x/h --------
    float* cbuf = (float*)SA;
    u16* xtA = SA + 5120000;
    u16* xtB = SA + 6400000;
    hipMemsetAsync(hA, 0, (size_t)NROWS * 256 * 2, stream);
    hipMemsetAsync(cbuf, 0, (size_t)NROWS * H * 4, stream);
    k_split_xtree<<<640, blk, 0, stream>>>(tree, 0, xtA);
    {
        u16 *p = hA, *q = hB;
        for (int t = 0; t < LTREE; ++t) {
            bool last = (t == LTREE - 1);
            u16* xin = (t & 1) ? xtB : xtA;
            u16* xnx = last ? (u16*)0 : ((t & 1) ? xtA : xtB);
            k_tree_step_mf<<<dim3(4, 160, 1), blk, 0, stream>>>(
                tree + (t + 1) * FDIM, xnx,
                xin, tx, th, tfx, tfh, tl_bioux, tl_biouh, tl_bfx, tl_bfh,
                p, cbuf, last ? feats : q, last ? 1 : 0);
            u16* tmp = p; p = q; q = tmp;
        }
    }

    // -------- 4 GRUs (16 steps, z=4); hi-only --------
    u16* xsA = SA;
    u16* xsB = SB;
    hipMemsetAsync(hA, 0, (size_t)4 * H2 * 2, stream);
    k_split_xseq<<<2560, blk, 0, stream>>>(s2, s3, s4, s5, 0, xsA);
    {
        u16 *p = hA, *q = hB;
        for (int t = 0; t < TSEQ; ++t) {
            bool last = (t == TSEQ - 1);
            u16* xin = (t & 1) ? xsB : xsA;
            u16* xnx = last ? (u16*)0 : ((t & 1) ? xsA : xsB);
            k_rnn_step<<<dim3(4, 80, 4), blk, 0, stream>>>(
                s2, s3, s4, s5, (t + 1) * FDIM, xnx,
                xin,
                gWih, 98304LL, gWhh, 196608LL, gru_bih, gru_bhh,
                p,
                last ? feats + H2 : q);
            u16* tmp = p; p = q; q = tmp;
        }
    }

    // -------- combine bi-GRU (5 steps, z=2) + fused connect --------
    float* fvF = (float*)SA;
    float* fvB = fvF + (size_t)NROWS * H;
    hipMemsetAsync(hA, 0, (size_t)2 * H2 * 2, stream);
    k_fv_init<<<(NROWS * H + 255) / 256, blk, 0, stream>>>(fvF, connect_b);
    hipMemsetAsync(fvB, 0, (size_t)NROWS * H * 4, stream);
    {
        u16 *p = hA, *q = hB;
        for (int s = 0; s < 5; ++s) {
            k_rnn_step64<<<dim3(4, 160, 2), blk, 0, stream>>>(
                feats, (long long)s * H2, (long long)(4 - s) * H2,
                cWih, 196608LL, cWhh, 196608LL, comb_bih, comb_bhh,
                p, q);
            k_fv_acc_mf<<<dim3(4, 79, 2), blk, 0, stream>>>(
                fvF, q, cn, s * 512, (4 - s) * 512 + 256);
            u16* tmp = p; p = q; q = tmp;
        }
    }

    // -------- CSR build (tail of hB; xc occupies first 2.56M u16) --------
    int* cnt = (int*)(hB + 6000000);
    int* rowptr = cnt + 10016;
    int* cursor = rowptr + 10016;
    int* csr = cursor + 10016;
    float* dinv = (float*)(csr + NE);
    hipMemsetAsync(cnt, 0, NROWS * sizeof(int), stream);
    hipMemsetAsync(cursor, 0, NROWS * sizeof(int), stream);
    k_cnt<<<(NE + 255) / 256, blk, 0, stream>>>(cnt, edge + NE);
    k_scan<<<1, blk, 0, stream>>>(cnt, rowptr);
    k_dinv<<<(NROWS + 255) / 256, blk, 0, stream>>>(dinv, cnt);
    k_fill<<<(NE + 255) / 256, blk, 0, stream>>>(csr, cursor, rowptr, edge);

    // -------- 4 conv applications (last two share W2,b2) --------
    {
        u16* xc = hB;                            // hi-only [NROWS][256]
        float* xw = (float*)SB;
        float* cur = fvF;
        float* nxt = (float*)hA;
        k_splitNH2<<<1250, blk, 0, stream>>>(fvF, fvB, xc);
        for (int i = 0; i < 4; ++i) {
            int wi = (i < 3) ? i : 2;
            k_gcn_gemm<<<dim3(4, 80, 1), blk, 0, stream>>>(xw, xc, gc + (size_t)wi * 65536);
            k_gather<<<(NROWS + 3) / 4, blk, 0, stream>>>(nxt, xc, xw, dinv, rowptr, csr,
                                                          gcn_b + wi * H);
            float* tmp = cur; cur = nxt; nxt = tmp;
        }
        k_colmax<<<256, blk, 0, stream>>>((float*)d_out, cur);
    }
}

// Round 20
// 1549.979 us; speedup vs baseline: 1.4882x; 1.1694x over previous
//
#include <hip/hip_runtime.h>
#include <math.h>

#define H 256
#define NROWS 10000
#define LTREE 8
#define TSEQ 16
#define FDIM 128
#define NE 160000
#define HTILE2 32768     // 128 rows * 256 cols hi-only (u16)
#define XT2 16384        // 128 rows * 128 cols hi-only (u16)
#define H2 2621440       // 80 tiles * HTILE2
#define XZ2 1310720      // 80 tiles * XT2

typedef __attribute__((ext_vector_type(8))) short short8;
typedef __attribute__((ext_vector_type(4))) float f32x4;
typedef unsigned short u16;

__device__ __forceinline__ u16 f2bf(float x) {
    unsigned int u = __float_as_uint(x);
    return (u16)((u + 0x7fffu + ((u >> 16) & 1u)) >> 16);
}
__device__ __forceinline__ float bf2f(u16 s) { return __uint_as_float(((unsigned int)s) << 16); }
__device__ __forceinline__ short8 ldf(const u16* __restrict__ p) { return *(const short8*)(p); }
__device__ __forceinline__ float frcp_(float x) { return __builtin_amdgcn_rcpf(x); }
__device__ __forceinline__ float fsig_(float x) { return frcp_(1.f + __expf(-x)); }
__device__ __forceinline__ float ftanh_(float x) {
    return 1.f - 2.f * frcp_(__expf(2.f * x) + 1.f);
}
// packed f32x2 -> bf16x2 (RNE), single instruction
__device__ __forceinline__ unsigned cvtpk(float lo, float hi) {
    unsigned r;
    asm volatile("v_cvt_pk_bf16_f32 %0, %1, %2" : "=v"(r) : "v"(lo), "v"(hi));
    return r;
}
#define MFMA(A, B, C) C = __builtin_amdgcn_mfma_f32_16x16x32_bf16(A, B, C, 0, 0, 0)

__device__ __forceinline__ void async16(u16* l, const u16* g) {
    __builtin_amdgcn_global_load_lds((__attribute__((address_space(1))) const void*)g,
                                     (__attribute__((address_space(3))) void*)l, 16, 0, 0);
}

// XCD-aware remap, bijective when nwg%8==0.
__device__ __forceinline__ void xcd_swz(int& cbi, int& yy, int& zz) {
    const int gx = gridDim.x, gy = gridDim.y;
    int nwg8 = (gx * gy * gridDim.z) >> 3;
    int bid = blockIdx.x + gx * (blockIdx.y + gy * blockIdx.z);
    int wgid = (bid & 7) * nwg8 + (bid >> 3);
    cbi = wgid % gx;
    int rem = wgid / gx;
    yy = rem % gy;
    zz = rem / gy;
}

// hi-only tiled offsets
__device__ __forceinline__ size_t xpo(int row, int g) {   // 128-col x tile
    return (size_t)(row >> 7) * XT2 + (size_t)g * 1024 + (size_t)(row & 127) * 8;
}

// Stage one 32KB chunk (pre-tiled source == LDS image), 128-row tiles. 8 loads/wave.
__device__ __forceinline__ void stageT32(u16* ldsbuf, const u16* __restrict__ chunkbase,
                                         int w, int lane) {
#pragma unroll
    for (int cc = 0; cc < 8; cc++) {
        int eb = (w * 8 + cc) * 64;
        async16(ldsbuf + (size_t)eb * 8, chunkbase + (size_t)(eb + lane) * 8);
    }
}
// Stage a 16KB half-tile chunk (64 rows, 128 k). 4 loads/wave.
__device__ __forceinline__ void stage64T16(u16* ldsbuf, const u16* __restrict__ chunkbase,
                                           int w, int lane) {
#pragma unroll
    for (int cc = 0; cc < 4; cc++) {
        int p = w * 4 + cc;
        async16(ldsbuf + (size_t)p * 512, chunkbase + (size_t)p * 1024 + (size_t)lane * 8);
    }
}
// hi-only row-major 64-row chunk (tree kernel): 16 planes x 8 u16 cols.
__device__ __forceinline__ void stage_chunk64h(u16* ldsbuf, const u16* __restrict__ src,
                                               int stride_u16, int kb_u16, int m0,
                                               int w, int lane) {
#pragma unroll
    for (int c = 0; c < 4; c++) {
        int e_base = (w * 4 + c) * 64;
        int e = e_base + lane;
        int p = e >> 6, rs = e & 63;
        int row = m0 + rs;
        if (row > NROWS - 1) row = NROWS - 1;
        const u16* g = src + (size_t)row * stride_u16 + kb_u16 + p * 8;
        async16(ldsbuf + (size_t)e_base * 8, g);
    }
}

// ---------------- split helpers (hi-only, packed cvt) ----------------
__device__ __forceinline__ void emit8h(u16* __restrict__ dst, const float* v8) {
    int4 o;
    o.x = (int)cvtpk(v8[0], v8[1]);
    o.y = (int)cvtpk(v8[2], v8[3]);
    o.z = (int)cvtpk(v8[4], v8[5]);
    o.w = (int)cvtpk(v8[6], v8[7]);
    *(int4*)dst = o;
}
__global__ void k_splitWb(const float* __restrict__ src, u16* __restrict__ dst, int ngroups) {
    int g = blockIdx.x * 256 + threadIdx.x;
    if (g < ngroups) {
        float v[8];
        *(float4*)v = *(const float4*)(src + (size_t)g * 8);
        *(float4*)(v + 4) = *(const float4*)(src + (size_t)g * 8 + 4);
        emit8h(dst + (size_t)g * 8, v);
    }
}
// t=0 seed for GRU x: tiled hi-only [4][XZ2]
__global__ void k_split_xseq(const float* __restrict__ s2, const float* __restrict__ s3,
                             const float* __restrict__ s4, const float* __restrict__ s5,
                             int t, u16* __restrict__ dst) {
    int bid = blockIdx.x;
    int xcd = bid & 7, chunk = bid >> 3;
    int z = xcd >> 1, half = xcd & 1;
    int g = chunk * 256 + threadIdx.x;
    int row = half * 5120 + (g >> 4);
    if (row >= NROWS) return;
    int gg = g & 15;
    const float* s = (z == 0) ? s2 : (z == 1) ? s3 : (z == 2) ? s4 : s5;
    const float* p = s + (size_t)row * (TSEQ * FDIM) + t * FDIM + gg * 8;
    float v[8];
    *(float4*)v = *(const float4*)p;
    *(float4*)(v + 4) = *(const float4*)(p + 4);
    emit8h(dst + (size_t)z * XZ2 + xpo(row, gg), v);
}
// tree x seed: row-major hi-only [NROWS][128]
__global__ void k_split_xtree(const float* __restrict__ tree, int t, u16* __restrict__ dst) {
    int bid = blockIdx.x;
    int xcd = bid & 7, chunk = bid >> 3;
    int g = chunk * 256 + threadIdx.x;
    int row = xcd * 1280 + (g >> 4);
    if (row >= NROWS) return;
    int col = (g & 15) * 8;
    const float* p = tree + (size_t)row * (LTREE * FDIM) + t * FDIM + col;
    float v[8];
    *(float4*)v = *(const float4*)p;
    *(float4*)(v + 4) = *(const float4*)(p + 4);
    emit8h(dst + (size_t)row * 128 + col, v);
}
// (fvF + fvB) f32 -> hi-only [NROWS][256] (GCN conv input)
__global__ void k_splitNH2(const float* __restrict__ a, const float* __restrict__ b,
                           u16* __restrict__ dst) {
    int g = blockIdx.x * 256 + threadIdx.x;
    if (g < NROWS * 32) {
        float v[8];
        float4 x0 = *(const float4*)(a + (size_t)g * 8);
        float4 x1 = *(const float4*)(a + (size_t)g * 8 + 4);
        float4 y0 = *(const float4*)(b + (size_t)g * 8);
        float4 y1 = *(const float4*)(b + (size_t)g * 8 + 4);
        v[0] = x0.x + y0.x; v[1] = x0.y + y0.y; v[2] = x0.z + y0.z; v[3] = x0.w + y0.w;
        v[4] = x1.x + y1.x; v[5] = x1.y + y1.y; v[6] = x1.z + y1.z; v[7] = x1.w + y1.w;
        emit8h(dst + (size_t)g * 8, v);
    }
}

// ---------------------------------------------------------------------------
// GRU step: 128-row A-tile, RF=8, hi-only. NC = 1 x-chunk (K=128) + 2 h-chunks
// (K=128 each), 32KB chunks -> 3 barriers. grid (4,80,4).
// Epilogue: hold from LDS, packed bf16 stores.
// ---------------------------------------------------------------------------
__global__ __launch_bounds__(256, 2) void k_rnn_step(
    const float* __restrict__ q0, const float* __restrict__ q1,
    const float* __restrict__ q2, const float* __restrict__ q3,
    int qoff4, u16* __restrict__ xnext,
    const u16* __restrict__ xp,
    const u16* __restrict__ Wih, long long wz,
    const u16* __restrict__ Whh, long long wzh,
    const float* __restrict__ bihB, const float* __restrict__ bhhB,
    const u16* __restrict__ hp,
    u16* __restrict__ op) {
    __shared__ u16 lds[2][16384];
    const int tid = threadIdx.x, lane = tid & 63, w = tid >> 6;
    const int lx = lane & 15, lg = lane >> 4;
    int cbi, yy, z;
    xcd_swz(cbi, yy, z);
    const int colw = cbi * 64 + w * 16;
    const int m0 = yy * 128;
    const u16* xb = xp + (size_t)z * XZ2 + (size_t)yy * XT2;
    const u16* hb = hp + (size_t)z * H2;
    const u16* hbt = hb + (size_t)yy * HTILE2;
    const float* bih = bihB + z * 768;
    const float* bhh = bhhB + z * 768;
    constexpr int NC = 3;

    const u16* bx0 = Wih + (size_t)z * wz + (size_t)(colw + lx) * 128 + lg * 8;
    const u16* bx1 = bx0 + 32768;
    const u16* bx2 = bx0 + 65536;
    const u16* bh0 = Whh + (size_t)z * wzh + (size_t)(colw + lx) * 256 + lg * 8;
    const u16* bh1 = bh0 + 65536;
    const u16* bh2 = bh0 + 131072;

    const f32x4 zf = {0.f, 0.f, 0.f, 0.f};
    f32x4 aR[8], aZ[8], aNX[8], aNH[8];
#pragma unroll
    for (int rf = 0; rf < 8; rf++) { aR[rf] = zf; aZ[rf] = zf; aNX[rf] = zf; aNH[rf] = zf; }

    auto chunksrc = [&](int c) -> const u16* {
        return (c == 0) ? xb : hbt + (size_t)(c - 1) * 16384;
    };
    stageT32(lds[0], chunksrc(0), w, lane);

    // fused next-timestep x split (hi-only tiled stores)
    if (xnext) {
        const float* qs = (z == 0) ? q0 : (z == 1) ? q1 : (z == 2) ? q2 : q3;
        int row = m0 + (tid >> 1);
        if (row < NROWS) {
            int g0 = (cbi * 32 + (tid & 1) * 16) >> 3;
            const float* p = qs + (size_t)row * (TSEQ * FDIM) + qoff4 + g0 * 8;
            u16* d = xnext + (size_t)z * XZ2;
            float v[8];
            *(float4*)v = *(const float4*)p;
            *(float4*)(v + 4) = *(const float4*)(p + 4);
            emit8h(d + xpo(row, g0), v);
            *(float4*)v = *(const float4*)(p + 8);
            *(float4*)(v + 4) = *(const float4*)(p + 12);
            emit8h(d + xpo(row, g0 + 1), v);
        }
    }

    for (int c = 0; c < NC; c++) {
        __syncthreads();  // drains DMA for lds[c&1]
        if (c + 1 < NC) stageT32(lds[(c + 1) & 1], chunksrc(c + 1), w, lane);
        const u16* lb = lds[c & 1];
        const bool isX = (c == 0);
#pragma unroll
        for (int s = 0; s < 4; s++) {
            short8 axh[8];
            const u16* ph = lb + (size_t)(s * 4 + lg) * 1024 + lx * 8;
#pragma unroll
            for (int rf = 0; rf < 8; rf++) axh[rf] = ldf(ph + rf * 128);
            const int ko = isX ? s * 32 : (c - 1) * 128 + s * 32;
            if (isX) {
                {
                    short8 bh_ = ldf(bx0 + ko);
#pragma unroll
                    for (int rf = 0; rf < 8; rf++) MFMA(axh[rf], bh_, aR[rf]);
                }
                {
                    short8 bh_ = ldf(bx1 + ko);
#pragma unroll
                    for (int rf = 0; rf < 8; rf++) MFMA(axh[rf], bh_, aZ[rf]);
                }
                {
                    short8 bh_ = ldf(bx2 + ko);
#pragma unroll
                    for (int rf = 0; rf < 8; rf++) MFMA(axh[rf], bh_, aNX[rf]);
                }
            } else {
                {
                    short8 bh_ = ldf(bh0 + ko);
#pragma unroll
                    for (int rf = 0; rf < 8; rf++) MFMA(axh[rf], bh_, aR[rf]);
                }
                {
                    short8 bh_ = ldf(bh1 + ko);
#pragma unroll
                    for (int rf = 0; rf < 8; rf++) MFMA(axh[rf], bh_, aZ[rf]);
                }
                {
                    short8 bh_ = ldf(bh2 + ko);
#pragma unroll
                    for (int rf = 0; rf < 8; rf++) MFMA(axh[rf], bh_, aNH[rf]);
                }
            }
        }
    }
    const int col = colw + lx;
    const float b_r = bih[col] + bhh[col];
    const float b_z = bih[256 + col] + bhh[256 + col];
    const float bx_n = bih[512 + col], bh_n = bhh[512 + col];
    const size_t colpart = (size_t)(col >> 3) * 1024 + (col & 7);
    u16* ob = op + (size_t)z * H2 + (size_t)yy * HTILE2;
    // h chunk for cols 0..127 is in lds[1] (chunk1), cols 128..255 in lds[0] (chunk2)
    const u16* hl = lds[1 - (cbi >> 1)];
    const size_t hoff = (size_t)((col & 127) >> 3) * 1024 + (col & 7);
#pragma unroll
    for (int rf = 0; rf < 8; rf++) {
#pragma unroll
        for (int rr = 0; rr < 4; rr += 2) {
            int rl0 = rf * 16 + lg * 4 + rr;
            int row0 = m0 + rl0;
            float hold0 = bf2f(hl[hoff + (size_t)rl0 * 8]);
            float hold1 = bf2f(hl[hoff + (size_t)(rl0 + 1) * 8]);
            float rg0 = fsig_(aR[rf][rr] + b_r);
            float zg0 = fsig_(aZ[rf][rr] + b_z);
            float ng0 = ftanh_(aNX[rf][rr] + bx_n + rg0 * (aNH[rf][rr] + bh_n));
            float h0 = (1.f - zg0) * ng0 + zg0 * hold0;
            float rg1 = fsig_(aR[rf][rr + 1] + b_r);
            float zg1 = fsig_(aZ[rf][rr + 1] + b_z);
            float ng1 = ftanh_(aNX[rf][rr + 1] + bx_n + rg1 * (aNH[rf][rr + 1] + bh_n));
            float h1 = (1.f - zg1) * ng1 + zg1 * hold1;
            unsigned pk = cvtpk(h0, h1);
            if (row0 < NROWS) ob[colpart + (size_t)rl0 * 8] = (u16)pk;
            if (row0 + 1 < NROWS) ob[colpart + (size_t)(rl0 + 1) * 8] = (u16)(pk >> 16);
        }
    }
}

// ---------------------------------------------------------------------------
// comb GRU step: 64-row tile, RF=4, 3 waves/SIMD; hi-only. NC = 2 x + 2 h
// chunks of 128 k (16KB). grid (4,160,2). Epilogue hold from LDS + cvt_pk.
// ---------------------------------------------------------------------------
__global__ __launch_bounds__(256, 3) void k_rnn_step64(
    const u16* __restrict__ xp, long long xo0, long long xo1,
    const u16* __restrict__ Wih, long long wz,
    const u16* __restrict__ Whh, long long wzh,
    const float* __restrict__ bihB, const float* __restrict__ bhhB,
    const u16* __restrict__ hp,
    u16* __restrict__ op) {
    __shared__ u16 lds[2][8192];
    const int tid = threadIdx.x, lane = tid & 63, w = tid >> 6;
    const int lx = lane & 15, lg = lane >> 4;
    int cbi, yy, z;
    xcd_swz(cbi, yy, z);
    const int colw = cbi * 64 + w * 16;
    const int m0 = yy * 64;
    const int tile = yy >> 1, rh = yy & 1;
    const u16* xb = xp + (size_t)((z == 1) ? xo1 : xo0) + (size_t)tile * HTILE2 + rh * 512;
    const u16* hb = hp + (size_t)z * H2;
    const u16* hbt = hb + (size_t)tile * HTILE2 + rh * 512;
    const float* bih = bihB + z * 768;
    const float* bhh = bhhB + z * 768;
    constexpr int NCX = 2, NC = 4;

    const u16* bx0 = Wih + (size_t)z * wz + (size_t)(colw + lx) * 256 + lg * 8;
    const u16* bx1 = bx0 + 65536;
    const u16* bx2 = bx0 + 131072;
    const u16* bh0 = Whh + (size_t)z * wzh + (size_t)(colw + lx) * 256 + lg * 8;
    const u16* bh1 = bh0 + 65536;
    const u16* bh2 = bh0 + 131072;

    const f32x4 zf = {0.f, 0.f, 0.f, 0.f};
    f32x4 aR[4], aZ[4], aNX[4], aNH[4];
#pragma unroll
    for (int rf = 0; rf < 4; rf++) { aR[rf] = zf; aZ[rf] = zf; aNX[rf] = zf; aNH[rf] = zf; }

    auto chunksrc = [&](int c) -> const u16* {
        return (c < NCX) ? xb + (size_t)c * 16384 : hbt + (size_t)(c - NCX) * 16384;
    };
    stage64T16(lds[0], chunksrc(0), w, lane);

    for (int c = 0; c < NC; c++) {
        __syncthreads();
        if (c + 1 < NC) stage64T16(lds[(c + 1) & 1], chunksrc(c + 1), w, lane);
        const u16* lb = lds[c & 1];
        const bool isX = (c < NCX);
        const int cl = isX ? c : c - NCX;
#pragma unroll
        for (int s = 0; s < 4; s++) {
            short8 axh[4];
            const u16* ph = lb + (size_t)(s * 4 + lg) * 512 + lx * 8;
#pragma unroll
            for (int rf = 0; rf < 4; rf++) axh[rf] = ldf(ph + rf * 128);
            const int ko = cl * 128 + s * 32;
            if (isX) {
                {
                    short8 bh_ = ldf(bx0 + ko);
#pragma unroll
                    for (int rf = 0; rf < 4; rf++) MFMA(axh[rf], bh_, aR[rf]);
                }
                {
                    short8 bh_ = ldf(bx1 + ko);
#pragma unroll
                    for (int rf = 0; rf < 4; rf++) MFMA(axh[rf], bh_, aZ[rf]);
                }
                {
                    short8 bh_ = ldf(bx2 + ko);
#pragma unroll
                    for (int rf = 0; rf < 4; rf++) MFMA(axh[rf], bh_, aNX[rf]);
                }
            } else {
                {
                    short8 bh_ = ldf(bh0 + ko);
#pragma unroll
                    for (int rf = 0; rf < 4; rf++) MFMA(axh[rf], bh_, aR[rf]);
                }
                {
                    short8 bh_ = ldf(bh1 + ko);
#pragma unroll
                    for (int rf = 0; rf < 4; rf++) MFMA(axh[rf], bh_, aZ[rf]);
                }
                {
                    short8 bh_ = ldf(bh2 + ko);
#pragma unroll
                    for (int rf = 0; rf < 4; rf++) MFMA(axh[rf], bh_, aNH[rf]);
                }
            }
        }
    }
    const int col = colw + lx;
    const float b_r = bih[col] + bhh[col];
    const float b_z = bih[256 + col] + bhh[256 + col];
    const float bx_n = bih[512 + col], bh_n = bhh[512 + col];
    const size_t colpart = (size_t)(col >> 3) * 1024 + (col & 7);
    u16* ob = op + (size_t)z * H2 + (size_t)tile * HTILE2 + rh * 512;
    // h chunk for cols 0..127 in lds[0] (chunk2), cols 128..255 in lds[1] (chunk3)
    const u16* hl = lds[cbi >> 1];
    const size_t hoff = (size_t)((col & 127) >> 3) * 512 + (col & 7);
#pragma unroll
    for (int rf = 0; rf < 4; rf++) {
#pragma unroll
        for (int rr = 0; rr < 4; rr += 2) {
            int rl0 = rf * 16 + lg * 4 + rr;
            int row0 = m0 + rl0;
            float hold0 = bf2f(hl[hoff + (size_t)rl0 * 8]);
            float hold1 = bf2f(hl[hoff + (size_t)(rl0 + 1) * 8]);
            float rg0 = fsig_(aR[rf][rr] + b_r);
            float zg0 = fsig_(aZ[rf][rr] + b_z);
            float ng0 = ftanh_(aNX[rf][rr] + bx_n + rg0 * (aNH[rf][rr] + bh_n));
            float h0 = (1.f - zg0) * ng0 + zg0 * hold0;
            float rg1 = fsig_(aR[rf][rr + 1] + b_r);
            float zg1 = fsig_(aZ[rf][rr + 1] + b_z);
            float ng1 = ftanh_(aNX[rf][rr + 1] + bx_n + rg1 * (aNH[rf][rr + 1] + bh_n));
            float h1 = (1.f - zg1) * ng1 + zg1 * hold1;
            unsigned pk = cvtpk(h0, h1);
            if (row0 < NROWS) ob[colpart + (size_t)rl0 * 8] = (u16)pk;
            if (row0 + 1 < NROWS) ob[colpart + (size_t)(rl0 + 1) * 8] = (u16)(pk >> 16);
        }
    }
}

// ---------------------------------------------------------------------------
// TreeLSTM step: 64-row tile, RF=4, hi-only x [row][128] and h [row][256].
// NC = 1 x-chunk + 2 h-chunks (128 k each). grid (4, 160, 1).
// ---------------------------------------------------------------------------
__global__ __launch_bounds__(256, 3) void k_tree_step_mf(
    const float* __restrict__ treenext, u16* __restrict__ xtnext,
    const u16* __restrict__ txp,
    const u16* __restrict__ Wx, const u16* __restrict__ Wh,
    const u16* __restrict__ Wfx, const u16* __restrict__ Wfh,
    const float* __restrict__ bioux, const float* __restrict__ biouh,
    const float* __restrict__ bfx, const float* __restrict__ bfh,
    const u16* __restrict__ hp, float* __restrict__ cst,
    u16* __restrict__ op, int tiledOut) {
    __shared__ u16 lds[2][8192];
    const int tid = threadIdx.x, lane = tid & 63, w = tid >> 6;
    const int lx = lane & 15, lg = lane >> 4;
    int cbi, yy, zz;
    xcd_swz(cbi, yy, zz);
    const int colw = cbi * 64 + w * 16;
    const int m0 = yy * 64;
    constexpr int NC = 3;

    const u16* bx0 = Wx + (size_t)(colw + lx) * 128 + lg * 8;
    const u16* bx1 = bx0 + 32768;
    const u16* bx2 = bx0 + 65536;
    const u16* bxf = Wfx + (size_t)(colw + lx) * 128 + lg * 8;
    const u16* bh0 = Wh + (size_t)(colw + lx) * 256 + lg * 8;
    const u16* bh1 = bh0 + 65536;
    const u16* bh2 = bh0 + 131072;
    const u16* bhf = Wfh + (size_t)(colw + lx) * 256 + lg * 8;

    const f32x4 zf = {0.f, 0.f, 0.f, 0.f};
    f32x4 aI[4], aO[4], aU[4], aF[4];
#pragma unroll
    for (int rf = 0; rf < 4; rf++) { aI[rf] = zf; aO[rf] = zf; aU[rf] = zf; aF[rf] = zf; }

    stage_chunk64h(lds[0], txp, 128, 0, m0, w, lane);

    if (xtnext) {
        int row = m0 + (tid >> 2);
        if (row < NROWS) {
            int c0 = cbi * 32 + (tid & 3) * 8;
            const float* p = treenext + (size_t)row * (LTREE * FDIM) + c0;
            float v[8];
            *(float4*)v = *(const float4*)p;
            *(float4*)(v + 4) = *(const float4*)(p + 4);
            emit8h(xtnext + (size_t)row * 128 + c0, v);
        }
    }

    for (int c = 0; c < NC; c++) {
        __syncthreads();
        if (c + 1 < NC) stage_chunk64h(lds[(c + 1) & 1], hp, 256, c * 128, m0, w, lane);
        const u16* lb = lds[c & 1];
        const bool isX = (c == 0);
#pragma unroll
        for (int s = 0; s < 4; s++) {
            short8 axh[4];
            const u16* ph = lb + (size_t)(s * 4 + lg) * 512 + lx * 8;
#pragma unroll
            for (int rf = 0; rf < 4; rf++) axh[rf] = ldf(ph + rf * 128);
            const int ko = isX ? s * 32 : (c - 1) * 128 + s * 32;
            const u16* p0 = isX ? bx0 : bh0;
            const u16* p1 = isX ? bx1 : bh1;
            const u16* p2 = isX ? bx2 : bh2;
            const u16* p3 = isX ? bxf : bhf;
            {
                short8 bh_ = ldf(p0 + ko);
#pragma unroll
                for (int rf = 0; rf < 4; rf++) MFMA(axh[rf], bh_, aI[rf]);
            }
            {
                short8 bh_ = ldf(p1 + ko);
#pragma unroll
                for (int rf = 0; rf < 4; rf++) MFMA(axh[rf], bh_, aO[rf]);
            }
            {
                short8 bh_ = ldf(p2 + ko);
#pragma unroll
                for (int rf = 0; rf < 4; rf++) MFMA(axh[rf], bh_, aU[rf]);
            }
            {
                short8 bh_ = ldf(p3 + ko);
#pragma unroll
                for (int rf = 0; rf < 4; rf++) MFMA(axh[rf], bh_, aF[rf]);
            }
        }
    }
    const int col = colw + lx;
    const float b_i = bioux[col] + biouh[col];
    const float b_o = bioux[256 + col] + biouh[256 + col];
    const float b_u = bioux[512 + col] + biouh[512 + col];
    const float b_f = bfx[col] + bfh[col];
    const size_t colpart2 = (size_t)(col >> 3) * 1024 + (col & 7);
#pragma unroll
    for (int rf = 0; rf < 4; rf++) {
#pragma unroll
        for (int rr = 0; rr < 4; rr += 2) {
            int rl0 = rf * 16 + lg * 4 + rr;
            int row0 = m0 + rl0;
            float h0 = 0.f, h1 = 0.f;
            {
                float ig = fsig_(aI[rf][rr] + b_i);
                float og = fsig_(aO[rf][rr] + b_o);
                float ug = ftanh_(aU[rf][rr] + b_u);
                float fg = fsig_(aF[rf][rr] + b_f);
                if (row0 < NROWS) {
                    size_t ci = (size_t)row0 * H + col;
                    float cnew = ig * ug + fg * cst[ci];
                    cst[ci] = cnew;
                    h0 = og * ftanh_(cnew);
                }
            }
            {
                float ig = fsig_(aI[rf][rr + 1] + b_i);
                float og = fsig_(aO[rf][rr + 1] + b_o);
                float ug = ftanh_(aU[rf][rr + 1] + b_u);
                float fg = fsig_(aF[rf][rr + 1] + b_f);
                if (row0 + 1 < NROWS) {
                    size_t ci = (size_t)(row0 + 1) * H + col;
                    float cnew = ig * ug + fg * cst[ci];
                    cst[ci] = cnew;
                    h1 = og * ftanh_(cnew);
                }
            }
            unsigned pk = cvtpk(h0, h1);
            if (tiledOut) {
                size_t a0 = (size_t)(row0 >> 7) * HTILE2 + (size_t)(row0 & 127) * 8 + colpart2;
                size_t a1 = (size_t)((row0 + 1) >> 7) * HTILE2 + (size_t)((row0 + 1) & 127) * 8 + colpart2;
                if (row0 < NROWS) op[a0] = (u16)pk;
                if (row0 + 1 < NROWS) op[a1] = (u16)(pk >> 16);
            } else {
                if (row0 < NROWS) op[(size_t)row0 * 256 + col] = (u16)pk;
                if (row0 + 1 < NROWS) op[(size_t)(row0 + 1) * 256 + col] = (u16)(pk >> 16);
            }
        }
    }
}

// fv_z += h_z @ Wc-slice^T ; hi-only h. grid (4,79,2).
__global__ __launch_bounds__(256) void k_fv_acc_mf(
    float* __restrict__ fvbase, const u16* __restrict__ hq,
    const u16* __restrict__ Wc, int off_f, int off_b) {
    const int tid = threadIdx.x, lane = tid & 63, w = tid >> 6;
    const int lx = lane & 15, kl8 = (lane >> 4);
    int cbi, yy, z;
    xcd_swz(cbi, yy, z);
    const int wr = w >> 1, wc = w & 1;
    const int cb = cbi * 64 + wc * 32;
    const int m0 = yy * 128 + wr * 64;
    int arow[4];
#pragma unroll
    for (int rf = 0; rf < 4; rf++) {
        int r = m0 + rf * 16 + lx;
        arow[rf] = (r < NROWS) ? r : NROWS - 1;
    }
    const f32x4 zf = {0.f, 0.f, 0.f, 0.f};
    f32x4 acc[4][2] = {{zf, zf}, {zf, zf}, {zf, zf}, {zf, zf}};
    const u16* aB = hq + (size_t)z * H2;
    const int off = z ? off_b : off_f;
    const u16* a[4];
#pragma unroll
    for (int rf = 0; rf < 4; rf++) {
        a[rf] = aB + (size_t)(arow[rf] >> 7) * HTILE2 + (size_t)(arow[rf] & 127) * 8 +
                (size_t)kl8 * 1024;
    }
    const u16* bp0 = Wc + (size_t)(cb + lx) * 2560 + off + kl8 * 8;
    const u16* bp1 = bp0 + 16 * 2560;
#pragma unroll
    for (int it = 0; it < 8; it++) {
        short8 axh[4];
#pragma unroll
        for (int rf = 0; rf < 4; rf++) {
            axh[rf] = ldf(a[rf]);
            a[rf] += 4096;
        }
        const int kb = it * 32;
        {
            short8 bh = ldf(bp0 + kb);
#pragma unroll
            for (int rf = 0; rf < 4; rf++) MFMA(axh[rf], bh, acc[rf][0]);
        }
        {
            short8 bh = ldf(bp1 + kb);
#pragma unroll
            for (int rf = 0; rf < 4; rf++) MFMA(axh[rf], bh, acc[rf][1]);
        }
    }
    float* fv = fvbase + (size_t)z * (NROWS * H);
#pragma unroll
    for (int rf = 0; rf < 4; rf++) {
#pragma unroll
        for (int cf = 0; cf < 2; cf++) {
            int col = cb + cf * 16 + lx;
#pragma unroll
            for (int rr = 0; rr < 4; rr++) {
                int row = m0 + rf * 16 + (lane >> 4) * 4 + rr;
                if (row < NROWS) fv[(size_t)row * H + col] += acc[rf][cf][rr];
            }
        }
    }
}

// out = A @ W^T; A hi-only [row][256], W bf16. RF=2, grid (4,80).
__global__ __launch_bounds__(256) void k_gcn_gemm(
    float* __restrict__ out, const u16* __restrict__ ap_, const u16* __restrict__ W) {
    const int tid = threadIdx.x, lane = tid & 63, w = tid >> 6;
    const int lx = lane & 15, kl = (lane >> 4) * 8;
    int cbi, yy, zz;
    xcd_swz(cbi, yy, zz);
    const int cb = cbi * 64, m0 = yy * 128 + w * 32;
    int arow[2];
#pragma unroll
    for (int rf = 0; rf < 2; rf++) {
        int r = m0 + rf * 16 + lx;
        arow[rf] = (r < NROWS) ? r : NROWS - 1;
    }
    const f32x4 zf = {0.f, 0.f, 0.f, 0.f};
    f32x4 acc[2][4] = {{zf, zf, zf, zf}, {zf, zf, zf, zf}};
    const u16* a0 = ap_ + (size_t)arow[0] * 256 + kl;
    const u16* a1 = ap_ + (size_t)arow[1] * 256 + kl;
    const u16* bp0 = W + (size_t)(cb + lx) * 256 + kl;
    const u16* bp1 = bp0 + 16 * 256;
    const u16* bp2 = bp0 + 32 * 256;
    const u16* bp3 = bp0 + 48 * 256;
#pragma unroll
    for (int kb = 0; kb < 256; kb += 32) {
        short8 axh[2];
        axh[0] = ldf(a0 + kb);
        axh[1] = ldf(a1 + kb);
        {
            short8 bh = ldf(bp0 + kb);
#pragma unroll
            for (int rf = 0; rf < 2; rf++) MFMA(axh[rf], bh, acc[rf][0]);
        }
        {
            short8 bh = ldf(bp1 + kb);
#pragma unroll
            for (int rf = 0; rf < 2; rf++) MFMA(axh[rf], bh, acc[rf][1]);
        }
        {
            short8 bh = ldf(bp2 + kb);
#pragma unroll
            for (int rf = 0; rf < 2; rf++) MFMA(axh[rf], bh, acc[rf][2]);
        }
        {
            short8 bh = ldf(bp3 + kb);
#pragma unroll
            for (int rf = 0; rf < 2; rf++) MFMA(axh[rf], bh, acc[rf][3]);
        }
    }
#pragma unroll
    for (int rf = 0; rf < 2; rf++) {
#pragma unroll
        for (int cf = 0; cf < 4; cf++) {
            int col = cb + cf * 16 + lx;
#pragma unroll
            for (int rr = 0; rr < 4; rr++) {
                int row = m0 + rf * 16 + (lane >> 4) * 4 + rr;
                if (row < NROWS) out[(size_t)row * H + col] = acc[rf][cf][rr];
            }
        }
    }
}

// ---------------------------- GCN small kernels -----------------------------
__global__ void k_fv_init(float* fv, const float* __restrict__ b) {
    int idx = blockIdx.x * 256 + threadIdx.x;
    if (idx < NROWS * H) fv[idx] = b[idx & (H - 1)];
}
__global__ void k_cnt(int* __restrict__ cnt, const int* __restrict__ dst) {
    int i = blockIdx.x * 256 + threadIdx.x;
    if (i < NE) atomicAdd(&cnt[dst[i]], 1);
}
__global__ void k_scan(const int* __restrict__ cnt, int* __restrict__ rowptr) {
    __shared__ int part[256];
    int tid = threadIdx.x;
    int st = tid * 40, en = (st + 40 > NROWS) ? NROWS : st + 40;
    int s = 0;
    for (int i = st; i < en; i++) s += cnt[i];
    part[tid] = s;
    __syncthreads();
    if (tid == 0) {
        int run = 0;
        for (int i = 0; i < 256; i++) { int t = part[i]; part[i] = run; run += t; }
        rowptr[NROWS] = run;
    }
    __syncthreads();
    int run = part[tid];
    for (int i = st; i < en; i++) { rowptr[i] = run; run += cnt[i]; }
}
__global__ void k_dinv(float* __restrict__ dinv, const int* __restrict__ cnt) {
    int i = blockIdx.x * 256 + threadIdx.x;
    if (i < NROWS) dinv[i] = rsqrtf(1.0f + (float)cnt[i]);
}
__global__ void k_fill(int* __restrict__ csr, int* __restrict__ cursor,
                       const int* __restrict__ rowptr, const int* __restrict__ ei) {
    int e = blockIdx.x * 256 + threadIdx.x;
    if (e < NE) {
        int d = ei[NE + e];
        int p = atomicAdd(&cursor[d], 1);
        csr[rowptr[d] + p] = ei[e];
    }
}
__global__ __launch_bounds__(256) void k_gather(
    float* __restrict__ out, u16* __restrict__ xcp,
    const float* __restrict__ xw, const float* __restrict__ dinv,
    const int* __restrict__ rowptr, const int* __restrict__ csr, const float* __restrict__ b) {
    int node = blockIdx.x * 4 + (threadIdx.x >> 6);
    if (node >= NROWS) return;
    int lane = threadIdx.x & 63;
    float dn = dinv[node];
    float4 acc = *(const float4*)(xw + (size_t)node * H + lane * 4);
    float dn2 = dn * dn;
    acc.x *= dn2; acc.y *= dn2; acc.z *= dn2; acc.w *= dn2;
    int e0 = rowptr[node], e1 = rowptr[node + 1];
    for (int i = e0; i < e1; i++) {
        int s = csr[i];
        float wgt = dn * dinv[s];
        const float4 v = *(const float4*)(xw + (size_t)s * H + lane * 4);
        acc.x += v.x * wgt; acc.y += v.y * wgt; acc.z += v.z * wgt; acc.w += v.w * wgt;
    }
    const float4 bv = *(const float4*)(b + lane * 4);
    float o0 = fmaxf(acc.x + bv.x, 0.f);
    float o1 = fmaxf(acc.y + bv.y, 0.f);
    float o2 = fmaxf(acc.z + bv.z, 0.f);
    float o3 = fmaxf(acc.w + bv.w, 0.f);
    float4 of = {o0, o1, o2, o3};
    *(float4*)(out + (size_t)node * H + lane * 4) = of;
    int2 pk;
    pk.x = (int)cvtpk(o0, o1);
    pk.y = (int)cvtpk(o2, o3);
    *(int2*)(xcp + (size_t)node * 256 + lane * 4) = pk;
}
__global__ void k_colmax(float* __restrict__ out, const float* __restrict__ x) {
    int j = threadIdx.x;
    float m = 0.0f;
    for (int r = blockIdx.x; r < NROWS; r += gridDim.x)
        m = fmaxf(m, x[(size_t)r * H + j]);
    atomicMax((int*)&out[j], __float_as_int(m));
}

// ---------------------------------------------------------------------------
extern "C" void kernel_launch(void* const* d_in, const int* in_sizes, int n_in,
                              void* d_out, int out_size, void* d_ws, size_t ws_size,
                              hipStream_t stream) {
    const float* tree = (const float*)d_in[0];
    const float* s2 = (const float*)d_in[1];
    const float* s3 = (const float*)d_in[2];
    const float* s4 = (const float*)d_in[3];
    const float* s5 = (const float*)d_in[4];
    const int* edge = (const int*)d_in[5];
    const float* tl_Wioux = (const float*)d_in[6];
    const float* tl_bioux = (const float*)d_in[7];
    const float* tl_Wiouh = (const float*)d_in[8];
    const float* tl_biouh = (const float*)d_in[9];
    const float* tl_Wfx = (const float*)d_in[10];
    const float* tl_bfx = (const float*)d_in[11];
    const float* tl_Wfh = (const float*)d_in[12];
    const float* tl_bfh = (const float*)d_in[13];
    const float* gru_Wih = (const float*)d_in[14];
    const float* gru_Whh = (const float*)d_in[15];
    const float* gru_bih = (const float*)d_in[16];
    const float* gru_bhh = (const float*)d_in[17];
    const float* comb_Wih = (const float*)d_in[18];
    const float* comb_Whh = (const float*)d_in[19];
    const float* comb_bih = (const float*)d_in[20];
    const float* comb_bhh = (const float*)d_in[21];
    const float* connect_W = (const float*)d_in[22];
    const float* connect_b = (const float*)d_in[23];
    const float* gcn_W = (const float*)d_in[24];
    const float* gcn_b = (const float*)d_in[25];

    char* base = (char*)d_ws;
    size_t off = 0;
    auto aus = [&](size_t nu16) { u16* p = (u16*)(base + off); off += nu16 * sizeof(u16); return p; };
    u16* tx = aus(98304);
    u16* th = aus(196608);
    u16* tfx = aus(32768);
    u16* tfh = aus(65536);
    u16* gWih = aus(393216);
    u16* gWhh = aus(786432);
    u16* cWih = aus(393216);
    u16* cWhh = aus(393216);
    u16* cn = aus(655360);
    u16* gc = aus(196608);
    u16* feats = aus((size_t)5 * H2);
    u16* hA = aus((size_t)4 * H2);
    u16* hB = aus((size_t)4 * H2);
    u16* SA = aus((size_t)8 * XZ2);   // 10.48M u16 scratch
    u16* SB = aus((size_t)8 * XZ2);

    const dim3 blk(256);

    hipMemsetAsync(d_out, 0, H * sizeof(float), stream);

    auto SPW = [&](const float* s, u16* d, int n) {
        k_splitWb<<<(n / 8 + 255) / 256, blk, 0, stream>>>(s, d, n / 8);
    };
    SPW(tl_Wioux, tx, 98304);
    SPW(tl_Wiouh, th, 196608);
    SPW(tl_Wfx, tfx, 32768);
    SPW(tl_Wfh, tfh, 65536);
    SPW(gru_Wih, gWih, 393216);
    SPW(gru_Whh, gWhh, 786432);
    SPW(comb_Wih, cWih, 393216);
    SPW(comb_Whh, cWhh, 393216);
    SPW(connect_W, cn, 655360);
    SPW(gcn_W, gc, 196608);

    // -------- TreeLSTM (8 steps); hi-only x/h --------
    float* cbuf = (float*)SA;
    u16* xtA = SA + 5120000;
    u16* xtB = SA + 6400000;
    hipMemsetAsync(hA, 0, (size_t)NROWS * 256 * 2, stream);
    hipMemsetAsync(cbuf, 0, (size_t)NROWS * H * 4, stream);
    k_split_xtree<<<640, blk, 0, stream>>>(tree, 0, xtA);
    {
        u16 *p = hA, *q = hB;
        for (int t = 0; t < LTREE; ++t) {
            bool last = (t == LTREE - 1);
            u16* xin = (t & 1) ? xtB : xtA;
            u16* xnx = last ? (u16*)0 : ((t & 1) ? xtA : xtB);
            k_tree_step_mf<<<dim3(4, 160, 1), blk, 0, stream>>>(
                tree + (t + 1) * FDIM, xnx,
                xin, tx, th, tfx, tfh, tl_bioux, tl_biouh, tl_bfx, tl_bfh,
                p, cbuf, last ? feats : q, last ? 1 : 0);
            u16* tmp = p; p = q; q = tmp;
        }
    }

    // -------- 4 GRUs (16 steps, z=4); hi-only --------
    u16* xsA = SA;
    u16* xsB = SB;
    hipMemsetAsync(hA, 0, (size_t)4 * H2 * 2, stream);
    k_split_xseq<<<2560, blk, 0, stream>>>(s2, s3, s4, s5, 0, xsA);
    {
        u16 *p = hA, *q = hB;
        for (int t = 0; t < TSEQ; ++t) {
            bool last = (t == TSEQ - 1);
            u16* xin = (t & 1) ? xsB : xsA;
            u16* xnx = last ? (u16*)0 : ((t & 1) ? xsA : xsB);
            k_rnn_step<<<dim3(4, 80, 4), blk, 0, stream>>>(
                s2, s3, s4, s5, (t + 1) * FDIM, xnx,
                xin,
                gWih, 98304LL, gWhh, 196608LL, gru_bih, gru_bhh,
                p,
                last ? feats + H2 : q);
            u16* tmp = p; p = q; q = tmp;
        }
    }

    // -------- combine bi-GRU (5 steps, z=2) + fused connect --------
    float* fvF = (float*)SA;
    float* fvB = fvF + (size_t)NROWS * H;
    hipMemsetAsync(hA, 0, (size_t)2 * H2 * 2, stream);
    k_fv_init<<<(NROWS * H + 255) / 256, blk, 0, stream>>>(fvF, connect_b);
    hipMemsetAsync(fvB, 0, (size_t)NROWS * H * 4, stream);
    {
        u16 *p = hA, *q = hB;
        for (int s = 0; s < 5; ++s) {
            k_rnn_step64<<<dim3(4, 160, 2), blk, 0, stream>>>(
                feats, (long long)s * H2, (long long)(4 - s) * H2,
                cWih, 196608LL, cWhh, 196608LL, comb_bih, comb_bhh,
                p, q);
            k_fv_acc_mf<<<dim3(4, 79, 2), blk, 0, stream>>>(
                fvF, q, cn, s * 512, (4 - s) * 512 + 256);
            u16* tmp = p; p = q; q = tmp;
        }
    }

    // -------- CSR build (tail of hB; xc occupies first 2.56M u16) --------
    int* cnt = (int*)(hB + 6000000);
    int* rowptr = cnt + 10016;
    int* cursor = rowptr + 10016;
    int* csr = cursor + 10016;
    float* dinv = (float*)(csr + NE);
    hipMemsetAsync(cnt, 0, NROWS * sizeof(int), stream);
    hipMemsetAsync(cursor, 0, NROWS * sizeof(int), stream);
    k_cnt<<<(NE + 255) / 256, blk, 0, stream>>>(cnt, edge + NE);
    k_scan<<<1, blk, 0, stream>>>(cnt, rowptr);
    k_dinv<<<(NROWS + 255) / 256, blk, 0, stream>>>(dinv, cnt);
    k_fill<<<(NE + 255) / 256, blk, 0, stream>>>(csr, cursor, rowptr, edge);

    // -------- 4 conv applications (last two share W2,b2) --------
    {
        u16* xc = hB;                            // hi-only [NROWS][256]
        float* xw = (float*)SB;
        float* cur = fvF;
        float* nxt = (float*)hA;
        k_splitNH2<<<1250, blk, 0, stream>>>(fvF, fvB, xc);
        for (int i = 0; i < 4; ++i) {
            int wi = (i < 3) ? i : 2;
            k_gcn_gemm<<<dim3(4, 80, 1), blk, 0, stream>>>(xw, xc, gc + (size_t)wi * 65536);
            k_gather<<<(NROWS + 3) / 4, blk, 0, stream>>>(nxt, xc, xw, dinv, rowptr, csr,
                                                          gcn_b + wi * H);
            float* tmp = cur; cur = nxt; nxt = tmp;
        }
        k_colmax<<<256, blk, 0, stream>>>((float*)d_out, cur);
    }
}